// Round 1
// baseline (380.272 us; speedup 1.0000x reference)
//
#include <hip/hip_runtime.h>

// (B,E,K,C) = (64,32,128,512), fp32.
#define BB 64
#define EE 32
#define KK 128
#define CC 512
#define V0EPS 1e-7f

#define LPA 34    // [128][34] padded stride (postAB kernel)
#define LTR 132   // [32][132] padded stride
#define L33 33    // [32][33] padded stride
#define PTS 132   // scan: P^T row stride
// segment-padded K-vector layout: element i lives at (i/16)*20 + (i%16)
// -> per-q float4 quads start at banks {0,20,8,28,16,4,24,12}+4u: conflict-free
#define SEG(i) ((((i) >> 4) * 20) + ((i) & 15))

// scan sScal slots
#define SC_S2  0
#define SC_SIG 1
#define SC_KL  2
#define SC_B1  3
#define SC_B2  4
#define SC_R11 5
#define SC_R12 6
#define SC_R22 7

__device__ __forceinline__ float wsum64(float v) {
#pragma unroll
  for (int m = 32; m >= 1; m >>= 1) v += __shfl_xor(v, m, 64);
  return v;
}

// ---------------- Kernel 1: A0 = M0 M0^T + I (shared across batches) ----------------
__global__ __launch_bounds__(256) void a0_kernel(const float* __restrict__ M0,
                                                 float* __restrict__ wsA0) {
  __shared__ __align__(16) float sRow[CC];
  const int k = blockIdx.x;
  for (int c = threadIdx.x; c < CC; c += 256) sRow[c] = M0[k * CC + c];
  __syncthreads();
  const int wv = threadIdx.x >> 6, ln = threadIdx.x & 63;
  const float4* zr = (const float4*)(sRow + 8 * ln);
  const float4 z0 = zr[0], z1 = zr[1];
  for (int li = 0; li < 32; ++li) {
    const int l = wv * 32 + li;
    const float4* rp = (const float4*)(M0 + l * CC + 8 * ln);
    const float4 a = rp[0], b = rp[1];
    float s = a.x * z0.x + a.y * z0.y + a.z * z0.z + a.w * z0.w +
              b.x * z1.x + b.y * z1.y + b.z * z1.z + b.w * z1.w;
    s = wsum64(s);
    if (ln == 0) wsA0[k * KK + l] = s + (l == k ? 1.0f : 0.0f);
  }
}

// ------- Kernel 2 (fused): WGs 0..63 -> P = M0 Z^T, S = Z Z^T ; WG 64 -> inv(A0) -------
__global__ __launch_bounds__(1024) void psinv_kernel(const float* __restrict__ x,
                                                     const float* __restrict__ M0,
                                                     float* __restrict__ wsP,
                                                     float* __restrict__ wsS,
                                                     const float* __restrict__ A0g,
                                                     float* __restrict__ Ainv0) {
  __shared__ __align__(16) float zAll[32][520];
  __shared__ __align__(16) float Mch[2][16][520];
  __shared__ float sFb[2][128];
  __shared__ __align__(16) float sPv[2][256];
  __shared__ float sScal[2];
  const int tid = threadIdx.x;

  if (blockIdx.x < 64) {
    // ================= ps body =================
    const int b = blockIdx.x;
    {
      const float4* x4 = (const float4*)(x + (size_t)b * EE * CC);
#pragma unroll
      for (int i = 0; i < 4; i++) {
        const int F = tid + 1024 * i, e = F >> 7, c4 = F & 127;
        ((float4*)zAll[e])[c4] = x4[F];
      }
    }
    const float4* M4 = (const float4*)M0;
    const int srow = tid >> 7, sc4 = tid & 127;
    float4 st0 = M4[srow * 128 + sc4];
    float4 st1 = M4[(8 + srow) * 128 + sc4];
    int buf = 0;
    const int p = tid & 7;           // 8 threads per dot
    const int ep = (tid >> 3) & 15;  // episodes 2*ep, 2*ep+1  (0..31)
    const int kp = tid >> 7;         // k rows kp, kp+8
#pragma unroll 1
    for (int kc = 0; kc < 8; ++kc) {
      ((float4*)Mch[buf][srow])[sc4] = st0;
      ((float4*)Mch[buf][8 + srow])[sc4] = st1;
      __syncthreads();
      if (kc + 1 < 8) {
        st0 = M4[((kc + 1) * 16 + srow) * 128 + sc4];
        st1 = M4[((kc + 1) * 16 + 8 + srow) * 128 + sc4];
      }
      float s00 = 0, s01 = 0, s10 = 0, s11 = 0;
      const float* m0 = Mch[buf][kp];
      const float* m1 = Mch[buf][kp + 8];
      const float* z0 = zAll[2 * ep];
      const float* z1 = zAll[2 * ep + 1];
#pragma unroll
      for (int u = 0; u < 16; u++) {
        const int c = 4 * p + 32 * u;
        const float4 a0 = *(const float4*)(m0 + c);
        const float4 a1 = *(const float4*)(m1 + c);
        const float4 b0 = *(const float4*)(z0 + c);
        const float4 b1 = *(const float4*)(z1 + c);
        s00 += a0.x * b0.x + a0.y * b0.y + a0.z * b0.z + a0.w * b0.w;
        s01 += a0.x * b1.x + a0.y * b1.y + a0.z * b1.z + a0.w * b1.w;
        s10 += a1.x * b0.x + a1.y * b0.y + a1.z * b0.z + a1.w * b0.w;
        s11 += a1.x * b1.x + a1.y * b1.y + a1.z * b1.z + a1.w * b1.w;
      }
#pragma unroll
      for (int m = 1; m <= 4; m <<= 1) {
        s00 += __shfl_xor(s00, m, 64); s01 += __shfl_xor(s01, m, 64);
        s10 += __shfl_xor(s10, m, 64); s11 += __shfl_xor(s11, m, 64);
      }
      if (p == 0) {
        float* Pb = wsP + (size_t)b * KK * EE;
        Pb[(kc * 16 + kp) * EE + 2 * ep] = s00;
        Pb[(kc * 16 + kp) * EE + 2 * ep + 1] = s01;
        Pb[(kc * 16 + kp + 8) * EE + 2 * ep] = s10;
        Pb[(kc * 16 + kp + 8) * EE + 2 * ep + 1] = s11;
      }
      buf ^= 1;
    }
    // S = Z Z^T
    {
      const int e = tid >> 5, f = tid & 31;
      const float4* ze = (const float4*)zAll[e];
      const float4* zf = (const float4*)zAll[f];
      float a0 = 0, a1 = 0, a2 = 0, a3 = 0;
#pragma unroll 4
      for (int u = 0; u < 128; u++) {
        const float4 A = ze[u], Bq = zf[u];
        a0 += A.x * Bq.x; a1 += A.y * Bq.y; a2 += A.z * Bq.z; a3 += A.w * Bq.w;
      }
      wsS[(size_t)b * EE * EE + e * EE + f] = (a0 + a1) + (a2 + a3);
    }
  } else {
    // ================= inv0 body (WG 64): register GJ, conditional pivot loads =================
    const int r = tid >> 3, q = tid & 7;
    float wreg[16], vreg[16];
    {
      const float4* a4 = (const float4*)(A0g + r * KK + 16 * q);
#pragma unroll
      for (int u = 0; u < 4; u++) {
        const float4 t4 = a4[u];
        wreg[4 * u] = t4.x; wreg[4 * u + 1] = t4.y; wreg[4 * u + 2] = t4.z; wreg[4 * u + 3] = t4.w;
      }
#pragma unroll
      for (int c = 0; c < 16; c++) vreg[c] = (16 * q + c == r) ? 1.0f : 0.0f;
    }
    if (q == 0) sFb[0][r] = wreg[0];
    if (r == 0) {
#pragma unroll
      for (int c = 0; c < 16; c++) { sPv[0][16 * q + c] = wreg[c]; sPv[0][128 + 16 * q + c] = vreg[c]; }
    }
    if (tid == 0) sScal[0] = 1.0f / wreg[0];
    __syncthreads();
#pragma unroll 1
    for (int j = 0; j < KK; ++j) {
      const int sl = j & 1, sn = sl ^ 1;
      const float f = sFb[sl][r] * sScal[sl];
      if (r != j) {
        if (16 * q + 15 >= j) {
          const float4* w4 = (const float4*)(sPv[sl] + 16 * q);
#pragma unroll
          for (int u = 0; u < 4; u++) {
            const float4 aa = w4[u];
            wreg[4 * u] -= f * aa.x; wreg[4 * u + 1] -= f * aa.y;
            wreg[4 * u + 2] -= f * aa.z; wreg[4 * u + 3] -= f * aa.w;
          }
        }
        if (16 * q <= j) {
          const float4* v4 = (const float4*)(sPv[sl] + 128 + 16 * q);
#pragma unroll
          for (int u = 0; u < 4; u++) {
            const float4 bb = v4[u];
            vreg[4 * u] -= f * bb.x; vreg[4 * u + 1] -= f * bb.y;
            vreg[4 * u + 2] -= f * bb.z; vreg[4 * u + 3] -= f * bb.w;
          }
        }
      }
      if (j + 1 < KK) {
        const int jn = j + 1;
        float wval = 0.0f;
#pragma unroll
        for (int c = 0; c < 16; c++) if (c == (jn & 15)) wval = wreg[c];
        if (q == (jn >> 4)) sFb[sn][r] = wval;
        if (r == jn) {
#pragma unroll
          for (int c = 0; c < 16; c++) { sPv[sn][16 * q + c] = wreg[c]; sPv[sn][128 + 16 * q + c] = vreg[c]; }
        }
        if (r == jn && q == (jn >> 4)) sScal[sn] = 1.0f / wval;
      }
      __syncthreads();
    }
    {
      float dval = 0.0f;
#pragma unroll
      for (int c = 0; c < 16; c++) if (c == (r & 15)) dval = wreg[c];
      if (q == (r >> 4)) sFb[0][r] = dval;
    }
    __syncthreads();
    {
      const float sc = 1.0f / sFb[0][r];
      float4* o4 = (float4*)(Ainv0 + r * KK + 16 * q);
#pragma unroll
      for (int u = 0; u < 4; u++) {
        float4 o;
        o.x = vreg[4 * u] * sc; o.y = vreg[4 * u + 1] * sc;
        o.z = vreg[4 * u + 2] * sc; o.w = vreg[4 * u + 3] * sc;
        o4[u] = o;
      }
    }
  }
}

// ---------------- Kernel 3: scan in (K,E)-coordinates, one WG per batch ----------------
// Conflict-free LDS round: P transposed (column reads -> stride-1), segment-padded
// K-vectors (stride 20 per 16), stride-8 k-slicing in dgw/qt, h-rotated j in wU,
// single transposed copies of G / Egg (row copies dropped).
__global__ __launch_bounds__(1024) void scan_kernel(
    const float* __restrict__ Pg, const float* __restrict__ Sg,
    const float* __restrict__ scaleP, const float* __restrict__ Ainv0,
    float* __restrict__ wsAinvP, float* __restrict__ wsG,
    float* __restrict__ wsEggT, float* __restrict__ wsD,
    float* __restrict__ wsKL) {
  __shared__ float sPT[EE * PTS];    // P^T : [e][k]
  __shared__ float sGT[EE * LTR];    // G^T : [t][k]
  __shared__ float sEggT[EE * LTR];  // Egg^T : [t][k]
  __shared__ float sYT[EE * LTR];    // Y^T : [t][k]
  __shared__ float sS[EE * L33];
  __shared__ float sD[EE * L33];
  __shared__ float sW[160], sWU[160], sPu[160], sPm[160], sQ[160];
  __shared__ float sDz[EE], sDgw[EE], sQt[EE], sScal[16];

  const int tid = threadIdx.x, wv = tid >> 6, ln = tid & 63;
  const int r = tid >> 3, q = tid & 7;
  const int b = blockIdx.x;

  float areg[16];
  {
    const float4* a4 = (const float4*)(Ainv0 + r * KK + 16 * q);
#pragma unroll
    for (int u = 0; u < 4; u++) {
      const float4 t4 = a4[u];
      areg[4 * u] = t4.x; areg[4 * u + 1] = t4.y; areg[4 * u + 2] = t4.z; areg[4 * u + 3] = t4.w;
    }
  }
  {
    const float* Pb = Pg + (size_t)b * KK * EE;
#pragma unroll
    for (int i = 0; i < 4; i++) {
      const int idx = tid + 1024 * i;
      sPT[(idx & 31) * PTS + (idx >> 5)] = Pb[idx];  // transpose into [e][k]
    }
    sS[(tid >> 5) * L33 + (tid & 31)] = Sg[(size_t)b * EE * EE + tid];
  }
  if (tid < 16) sScal[tid] = 0.0f;
  const float v0 = scaleP[0] + V0EPS;
  __syncthreads();
  {  // w0 = Ainv0 * P[:,0]
    float s = 0;
#pragma unroll
    for (int c = 0; c < 16; c++) s += areg[c] * sPT[16 * q + c];
    s += __shfl_xor(s, 1, 64); s += __shfl_xor(s, 2, 64); s += __shfl_xor(s, 4, 64);
    if (q == 0) sW[SEG(r)] = s;
  }
  __syncthreads();

#pragma unroll 1
  for (int t = 0; t < EE; ++t) {
    const bool hn = (t + 1 < EE);
    // ---- PH1: Pm = Ainv w ; dgw = G^T w ; qt = Y^T w ; S2 ----
    {
      float s = 0;
#pragma unroll
      for (int c = 0; c < 16; c++) s += areg[c] * sW[20 * q + c];
      s += __shfl_xor(s, 1, 64); s += __shfl_xor(s, 2, 64); s += __shfl_xor(s, 4, 64);
      if (q == 0) sPm[SEG(r)] = s;
    }
    if (tid < 256) {
      const int s8 = tid >> 3, p3 = tid & 7;
      if (s8 < t) {
        float s = 0;
#pragma unroll
        for (int kk = 0; kk < 16; kk++) {
          const int kx = p3 + 8 * kk;  // stride-8 slice: <=2-way banks
          s += sGT[s8 * LTR + kx] * sW[SEG(kx)];
        }
        s += __shfl_xor(s, 1, 64); s += __shfl_xor(s, 2, 64); s += __shfl_xor(s, 4, 64);
        if (p3 == 0) sDgw[s8] = s;
      }
    } else if (tid < 512) {
      const int j = (tid - 256) >> 3, p3 = tid & 7;
      if (j < t) {
        float s = 0;
#pragma unroll
        for (int kk = 0; kk < 16; kk++) {
          const int kx = p3 + 8 * kk;
          s += sYT[j * LTR + kx] * sW[SEG(kx)];
        }
        s += __shfl_xor(s, 1, 64); s += __shfl_xor(s, 2, 64); s += __shfl_xor(s, 4, 64);
        if (p3 == 0) sQt[j] = s;
      }
    } else if (wv == 8) {
      const float w0v = sW[SEG(ln)], w1v = sW[SEG(ln + 64)];
      float s = w0v * w0v + w1v * w1v;
      s = wsum64(s);
      if (ln == 0) sScal[SC_S2] = s;
    }
    __syncthreads();
    // ---- PH2: wU = v0 w - Y qt ; D_t ; e_t ; sigma ; KL ----
    if (tid < 512) {
      const int r4 = tid >> 2, h = tid & 3;
      float s = 0;
#pragma unroll
      for (int kk = 0; kk < 8; kk++) {
        const int jj = 8 * h + ((kk + 2 * h) & 7);  // h-rotation: distinct banks per h
        if (jj < t) s += sYT[jj * LTR + r4] * sQt[jj];
      }
      s += __shfl_xor(s, 1, 64); s += __shfl_xor(s, 2, 64);
      if (h == 0) sWU[SEG(r4)] = v0 * sW[SEG(r4)] - s;
    } else if (tid < 544) {
      const int r2 = tid - 512;
      float s = (r2 == t) ? 1.0f : 0.0f;
      for (int s2 = 0; s2 < t; ++s2) s -= sDgw[s2] * sD[s2 * L33 + r2];
      sD[t * L33 + r2] = s;
    } else if (tid >= 576 && tid < 704) {
      const int r3 = tid - 576;
      float s = sW[SEG(r3)];
      for (int s2 = 0; s2 < t; ++s2) s -= sEggT[s2 * LTR + r3] * sDgw[s2];
      sEggT[t * LTR + r3] = s;
    } else if (wv == 12) {
      float s = (ln < t) ? sQt[ln] * sQt[ln] : 0.0f;
      s = wsum64(s);
      if (ln == 0) sScal[SC_SIG] = v0 * sScal[SC_S2] - s + 1.0f;
    } else if (tid == 896) {
      sScal[SC_KL] += sScal[SC_S2];
    }
    __syncthreads();
    // ---- PH3: Pu = Ainv wU ; dz[s<=t] ; beta parts ----
    {
      float s = 0;
#pragma unroll
      for (int c = 0; c < 16; c++) s += areg[c] * sWU[20 * q + c];
      s += __shfl_xor(s, 1, 64); s += __shfl_xor(s, 2, 64); s += __shfl_xor(s, 4, 64);
      if (q == 0) sPu[SEG(r)] = s;
    }
    if (tid < 512) {
      const int s4 = tid >> 4, p4 = tid & 15;
      if (hn && s4 <= t) {
        float s = sD[s4 * L33 + p4] * sS[p4 * L33 + (t + 1)] +
                  sD[s4 * L33 + p4 + 16] * sS[(p4 + 16) * L33 + (t + 1)];
#pragma unroll
        for (int kk = 0; kk < 8; kk++) {
          const int rr = p4 + 16 * kk;  // lanes consecutive -> conflict-free
          s -= sEggT[s4 * LTR + rr] * sPT[(t + 1) * PTS + rr];
        }
        s += __shfl_xor(s, 1, 64); s += __shfl_xor(s, 2, 64);
        s += __shfl_xor(s, 4, 64); s += __shfl_xor(s, 8, 64);
        if (p4 == 0) sDz[s4] = s;
      }
    } else if (tid >= 544 && tid < 560) {
      const int p4 = tid & 15;
      float s = sD[t * L33 + p4] * sS[p4 * L33 + t] +
                sD[t * L33 + p4 + 16] * sS[(p4 + 16) * L33 + t];
      s += __shfl_xor(s, 1, 64); s += __shfl_xor(s, 2, 64);
      s += __shfl_xor(s, 4, 64); s += __shfl_xor(s, 8, 64);
      if (p4 == 0) sScal[SC_B1] = s;
    } else if (tid >= 576 && tid < 608) {
      const int l5 = tid - 576;
      float s = 0;
#pragma unroll
      for (int u = 0; u < 4; u++) {
        const int rr = 4 * l5 + u;
        s += sEggT[t * LTR + rr] * sPT[t * PTS + rr];
      }
      s += __shfl_xor(s, 1, 64); s += __shfl_xor(s, 2, 64);
      s += __shfl_xor(s, 4, 64); s += __shfl_xor(s, 8, 64); s += __shfl_xor(s, 16, 64);
      if (l5 == 0) sScal[SC_B2] = s;
    }
    __syncthreads();
    // ---- PH4: raw 2x2 dots ; appends (g, y) ; q_next ----
    if (wv == 0) {
      float s = sWU[SEG(ln)] * sPu[SEG(ln)] + sWU[SEG(ln + 64)] * sPu[SEG(ln + 64)];
      s = wsum64(s);
      if (ln == 0) sScal[SC_R11] = s;
    } else if (wv == 1) {
      float s = sWU[SEG(ln)] * sPm[SEG(ln)] + sWU[SEG(ln + 64)] * sPm[SEG(ln + 64)];
      s = wsum64(s);
      if (ln == 0) sScal[SC_R12] = s;
    } else if (wv == 2) {
      float s = sW[SEG(ln)] * sPm[SEG(ln)] + sW[SEG(ln + 64)] * sPm[SEG(ln + 64)];
      s = wsum64(s);
      if (ln == 0) sScal[SC_R22] = s;
    } else if (tid >= 192 && tid < 320) {
      const int rr = tid - 192;
      const float sig = sScal[SC_SIG];
      const float wu = sWU[SEG(rr)];
      const float gv = wu / sig;
      sGT[t * LTR + rr] = gv;
      sYT[t * LTR + rr] = wu * rsqrtf(sig);
    }
    if (hn) {
      float s = 0;
#pragma unroll
      for (int u = 0; u < 4; u++) {
        const int s2 = q + 8 * u;
        if (s2 < t) s += sGT[s2 * LTR + r] * sDz[s2];
      }
      s += __shfl_xor(s, 1, 64); s += __shfl_xor(s, 2, 64); s += __shfl_xor(s, 4, 64);
      if (q == 0)
        sQ[SEG(r)] = sPT[(t + 1) * PTS + r] + s + (sWU[SEG(r)] / sScal[SC_SIG]) * sDz[t];
    }
    __syncthreads();
    // ---- PH5: Ainv rank-2 update (registers) ; w_next ----
    {
      const float rs = 1.0f / sScal[SC_SIG];
      const float beta = sScal[SC_B1] - sScal[SC_B2] - sScal[SC_S2];
      const float e11 = sScal[SC_R11] * rs * rs;
      const float e12 = sScal[SC_R12] * rs + 1.0f;
      const float e22 = sScal[SC_R22] - beta;
      const float rd = 1.0f / (e11 * e22 - e12 * e12);
      const float t11 = e22 * rd, t12 = -e12 * rd, t22 = e11 * rd;
      const float u1r = sPu[SEG(r)] * rs, u2r = sPm[SEG(r)];
#pragma unroll
      for (int c = 0; c < 16; c++) {
        const float u1c = sPu[20 * q + c] * rs;
        const float u2c = sPm[20 * q + c];
        areg[c] -= u1r * (t11 * u1c + t12 * u2c) + u2r * (t12 * u1c + t22 * u2c);
      }
    }
    if (hn) {
      float s = 0;
#pragma unroll
      for (int c = 0; c < 16; c++) s += areg[c] * sQ[20 * q + c];
      s += __shfl_xor(s, 1, 64); s += __shfl_xor(s, 2, 64); s += __shfl_xor(s, 4, 64);
      if (q == 0) sW[SEG(r)] = s;
    }
    __syncthreads();
  }

  // ---- epilogue ----
  {
    float* aout = wsAinvP + (size_t)b * KK * KK + r * KK + 16 * q;
#pragma unroll
    for (int u = 0; u < 4; u++) {
      float4 o;
      o.x = areg[4 * u]; o.y = areg[4 * u + 1]; o.z = areg[4 * u + 2]; o.w = areg[4 * u + 3];
      ((float4*)aout)[u] = o;
    }
  }
#pragma unroll
  for (int i = 0; i < 4; i++) {
    const int idx = tid + 1024 * i;  // idx = k*32 + e (global layout unchanged)
    wsG[(size_t)b * 4096 + idx] = sGT[(idx & 31) * LTR + (idx >> 5)];
    wsEggT[(size_t)b * 4096 + idx] = sEggT[(idx >> 7) * LTR + (idx & 127)];
  }
  wsD[(size_t)b * 1024 + tid] = sD[(tid >> 5) * L33 + (tid & 31)];
  if (tid == 0) wsKL[b] = sScal[SC_KL];
}

// ---------------- Kernel 4 (fused postA+postB), one WG per batch ----------------
__global__ __launch_bounds__(1024) void postAB_kernel(
    const float* __restrict__ Pg, const float* __restrict__ Sg,
    const float* __restrict__ wsAinvP, const float* __restrict__ wsG,
    const float* __restrict__ wsEggT, const float* __restrict__ wsD,
    const float* __restrict__ x, const float* __restrict__ M0,
    const float* __restrict__ znoise,
    float* __restrict__ wsKLr, float* __restrict__ out) {
  __shared__ __align__(16) float SM[25856];  // 103.4 KB, lifetime-aliased
  float* sP    = SM;            // 4352  [128][34]
  float* sG    = SM + 4352;     // 4352
  float* sRhs  = SM + 8704;     // 4352
  float* sWr   = SM + 13056;    // 4352
  float* sEggT = SM + 17408;    // 4224  [32][132]
  float* sD    = SM + 21632;    // 1056  [32][33]
  float* sS    = SM + 22688;    // 1056
  float* sR1   = SM + 23744;    // 1056
  float* sGam  = SM + 24800;    // 1056
  float* sWt   = SM;            // 5440 floats: overlays dead sP + head of sG (postB)
  float* Mch   = SM + 8704;     // 8320 floats: overlays dead sRhs + sWr (postB)

  const int tid = threadIdx.x, b = blockIdx.x;
  const int r = tid >> 3, q = tid & 7;
#pragma unroll
  for (int i = 0; i < 4; i++) {
    const int idx = tid + 1024 * i;
    sP[(idx >> 5) * LPA + (idx & 31)] = Pg[(size_t)b * 4096 + idx];
    sG[(idx >> 5) * LPA + (idx & 31)] = wsG[(size_t)b * 4096 + idx];
    sEggT[(idx >> 7) * LTR + (idx & 127)] = wsEggT[(size_t)b * 4096 + idx];
  }
  sD[(tid >> 5) * L33 + (tid & 31)] = wsD[(size_t)b * 1024 + tid];
  sS[(tid >> 5) * L33 + (tid & 31)] = Sg[(size_t)b * 1024 + tid];
  __syncthreads();
  // R1 = D S - Egg^T P
  {
    const int s = tid >> 5, e = tid & 31;
    float acc = 0;
#pragma unroll 4
    for (int f = 0; f < 32; f++) acc += sD[s * L33 + f] * sS[f * L33 + e];
#pragma unroll 4
    for (int rr = 0; rr < 128; rr++) acc -= sEggT[s * LTR + rr] * sP[rr * LPA + e];
    sR1[s * L33 + e] = acc;
  }
  __syncthreads();
  // rhs = P + G R1
  {
#pragma unroll
    for (int u = 0; u < 4; u++) {
      const int e = q + 8 * u;
      float acc = sP[r * LPA + e];
#pragma unroll 4
      for (int s = 0; s < 32; s++) acc += sG[r * LPA + s] * sR1[s * L33 + e];
      sRhs[r * LPA + e] = acc;
    }
  }
  __syncthreads();
  // w_read = Ainv_post rhs
  {
    float areg[16];
    const float4* a4 = (const float4*)(wsAinvP + (size_t)b * KK * KK + r * KK + 16 * q);
#pragma unroll
    for (int u = 0; u < 4; u++) {
      const float4 t4 = a4[u];
      areg[4 * u] = t4.x; areg[4 * u + 1] = t4.y; areg[4 * u + 2] = t4.z; areg[4 * u + 3] = t4.w;
    }
#pragma unroll 1
    for (int e = 0; e < 32; ++e) {
      float s = 0;
#pragma unroll
      for (int c = 0; c < 16; c++) s += areg[c] * sRhs[(16 * q + c) * LPA + e];
      s += __shfl_xor(s, 1, 64); s += __shfl_xor(s, 2, 64); s += __shfl_xor(s, 4, 64);
      if (q == 0) sWr[r * LPA + e] = s;
    }
  }
  __syncthreads();
  // Gam = G^T w
  {
    const int s = tid >> 5, e = tid & 31;
    float acc = 0;
#pragma unroll 4
    for (int rr = 0; rr < 128; rr++) acc += sG[rr * LPA + s] * sWr[rr * LPA + e];
    sGam[s * L33 + e] = acc;
  }
  __syncthreads();
  // Wc = w - Egg Gam -> sWt[0..127] ; Vc = D^T Gam -> sWt[128..159] ; KLr
  // (sWt overlays sP and head of sG — both dead now)
  {
#pragma unroll
    for (int u = 0; u < 4; u++) {
      const int e = q + 8 * u;
      float acc = sWr[r * LPA + e];
#pragma unroll 4
      for (int s = 0; s < 32; s++) acc -= sEggT[s * LTR + r] * sGam[s * L33 + e];
      sWt[r * 34 + e] = acc;
    }
    const int s7 = tid >> 5, e7 = tid & 31;
    float acc2 = 0;
#pragma unroll 4
    for (int f = 0; f < 32; f++) acc2 += sD[f * L33 + s7] * sGam[f * L33 + e7];
    sWt[(128 + s7) * 34 + e7] = acc2;
    if (tid < 512) {
      const int e6 = tid >> 4, p6 = tid & 15;
      float s = 0;
#pragma unroll
      for (int u = 0; u < 8; u++) {
        const float w_ = sWr[(8 * p6 + u) * LPA + e6];
        s += w_ * w_;
      }
      s += __shfl_xor(s, 1, 64); s += __shfl_xor(s, 2, 64);
      s += __shfl_xor(s, 4, 64); s += __shfl_xor(s, 8, 64);
      if (p6 == 0) wsKLr[b * EE + e6] = s;
    }
  }
  __syncthreads();

  // ===== postB: z_mean = [M0; Z]^T [Wc; Vc] + noise (Mch overlays dead sRhs+sWr) =====
  {
    const int srow = tid >> 7, sc4 = tid & 127;
    const float4* M4 = (const float4*)M0;
    const float4* X4 = (const float4*)(x + (size_t)b * EE * CC);
    float4 st = M4[srow * 128 + sc4];
    int buf = 0;
    const int e = tid & 31, cseg = tid >> 5;
    float acc[16];
#pragma unroll
    for (int u = 0; u < 16; u++) acc[u] = 0;
#pragma unroll 1
    for (int ch = 0; ch < 20; ++ch) {
      ((float4*)(Mch + buf * 4160 + srow * 520))[sc4] = st;
      __syncthreads();
      if (ch + 1 < 20) {
        st = (ch + 1 < 16) ? M4[((ch + 1) * 8 + srow) * 128 + sc4]
                           : X4[((ch + 1 - 16) * 8 + srow) * 128 + sc4];
      }
#pragma unroll
      for (int kk = 0; kk < 8; kk++) {
        const float wk = sWt[(ch * 8 + kk) * 34 + e];
        const float* mr = Mch + buf * 4160 + kk * 520 + 16 * cseg;
        const float4 m0 = *(const float4*)(mr);
        const float4 m1 = *(const float4*)(mr + 4);
        const float4 m2 = *(const float4*)(mr + 8);
        const float4 m3 = *(const float4*)(mr + 12);
        acc[0] += wk * m0.x;  acc[1] += wk * m0.y;  acc[2] += wk * m0.z;  acc[3] += wk * m0.w;
        acc[4] += wk * m1.x;  acc[5] += wk * m1.y;  acc[6] += wk * m1.z;  acc[7] += wk * m1.w;
        acc[8] += wk * m2.x;  acc[9] += wk * m2.y;  acc[10] += wk * m2.z; acc[11] += wk * m2.w;
        acc[12] += wk * m3.x; acc[13] += wk * m3.y; acc[14] += wk * m3.z; acc[15] += wk * m3.w;
      }
      buf ^= 1;
    }
    {
      const size_t ob = ((size_t)b * EE + e) * CC + 16 * cseg;
      const size_t nb = ((size_t)e * BB + b) * CC + 16 * cseg;
#pragma unroll
      for (int u = 0; u < 4; u++) {
        const float4 nz = *(const float4*)(znoise + nb + 4 * u);
        float4 o;
        o.x = acc[4 * u] + nz.x;     o.y = acc[4 * u + 1] + nz.y;
        o.z = acc[4 * u + 2] + nz.z; o.w = acc[4 * u + 3] + nz.w;
        *(float4*)(out + ob + 4 * u) = o;
      }
    }
  }
}

// ---------------- Kernel 5: total divergence ----------------
__global__ __launch_bounds__(256) void final_kernel(const float* __restrict__ wsKL,
                                                    const float* __restrict__ wsKLr,
                                                    const float* __restrict__ lwsP,
                                                    float* __restrict__ out) {
  __shared__ float sPp[256];
  const int tid = threadIdx.x;
  float s = 0.0f;
  if (tid < 64) s += wsKL[tid];
  for (int i = tid; i < 2048; i += 256) s += wsKLr[i];
  sPp[tid] = s;
  __syncthreads();
  for (int off = 128; off > 0; off >>= 1) {
    if (tid < off) sPp[tid] += sPp[tid + off];
    __syncthreads();
  }
  if (tid == 0) {
    const float lws = lwsP[0];
    const float sw2 = expf(2.0f * lws);
    out[(size_t)BB * EE * CC] =
        0.5f * sPp[0] / (float)(EE * BB) + (float)KK * (sw2 - 1.0f - 2.0f * lws);
  }
}

extern "C" void kernel_launch(void* const* d_in, const int* in_sizes, int n_in,
                              void* d_out, int out_size, void* d_ws, size_t ws_size,
                              hipStream_t stream) {
  (void)in_sizes; (void)n_in; (void)out_size; (void)ws_size;
  const float* x = (const float*)d_in[0];        // [B,E,C]
  const float* M0 = (const float*)d_in[1];       // [K,C]
  const float* scaleP = (const float*)d_in[2];   // scalar
  const float* lwsP = (const float*)d_in[3];     // scalar
  const float* znoise = (const float*)d_in[4];   // [E,B,C]
  float* out = (float*)d_out;

  float* ws = (float*)d_ws;
  float* wsP = ws;                        // 64*128*32 = 262144
  float* wsS = wsP + 262144;              // 64*32*32  = 65536
  float* wsA0 = wsS + 65536;              // 16384
  float* wsAinv0 = wsA0 + 16384;          // 16384
  float* wsAinvP = wsAinv0 + 16384;       // 64*16384 = 1048576
  float* wsG = wsAinvP + 1048576;         // 64*4096 = 262144
  float* wsEggT = wsG + 262144;           // 262144
  float* wsD = wsEggT + 262144;           // 65536
  float* wsKL = wsD + 65536;              // 64
  float* wsKLr = wsKL + 64;               // 2048

  a0_kernel<<<KK, 256, 0, stream>>>(M0, wsA0);
  psinv_kernel<<<65, 1024, 0, stream>>>(x, M0, wsP, wsS, wsA0, wsAinv0);
  scan_kernel<<<BB, 1024, 0, stream>>>(wsP, wsS, scaleP, wsAinv0,
                                       wsAinvP, wsG, wsEggT, wsD, wsKL);
  postAB_kernel<<<BB, 1024, 0, stream>>>(wsP, wsS, wsAinvP, wsG, wsEggT, wsD,
                                         x, M0, znoise, wsKLr, out);
  final_kernel<<<1, 256, 0, stream>>>(wsKL, wsKLr, lwsP, out);
}

// Round 2
// 375.132 us; speedup vs baseline: 1.0137x; 1.0137x over previous
//
#include <hip/hip_runtime.h>

// (B,E,K,C) = (64,32,128,512), fp32.
#define BB 64
#define EE 32
#define KK 128
#define CC 512
#define V0EPS 1e-7f

#define LPA 34    // [128][34] padded stride (postAB kernel)
#define LTR 132   // [32][132] padded stride
#define L33 33    // [32][33] padded stride (postAB kernel)
#define PTS 132   // scan: P^T row stride
#define LKM 36    // scan: k-major row stride (G/Y/Egg), 144B = 16B-aligned
#define L36 36    // scan: S/D row stride (b128-aligned rows)
// segment-padded K-vector layout: element i lives at (i/16)*20 + (i%16)
#define SEG(i) ((((i) >> 4) * 20) + ((i) & 15))

// scan sScal slots (order matters: read as two float4s in PH5)
#define SC_S2  0
#define SC_SIG 1
#define SC_KL  2
#define SC_B1  3
#define SC_B2  4
#define SC_R11 5
#define SC_R12 6
#define SC_R22 7

__device__ __forceinline__ float wsum64(float v) {
#pragma unroll
  for (int m = 32; m >= 1; m >>= 1) v += __shfl_xor(v, m, 64);
  return v;
}

__device__ __forceinline__ float wsum32(float v) {  // reduce within aligned 32-lane half
#pragma unroll
  for (int m = 16; m >= 1; m >>= 1) v += __shfl_xor(v, m, 64);
  return v;
}

// ---------------- Kernel 1: A0 = M0 M0^T + I (shared across batches) ----------------
__global__ __launch_bounds__(256) void a0_kernel(const float* __restrict__ M0,
                                                 float* __restrict__ wsA0) {
  __shared__ __align__(16) float sRow[CC];
  const int k = blockIdx.x;
  for (int c = threadIdx.x; c < CC; c += 256) sRow[c] = M0[k * CC + c];
  __syncthreads();
  const int wv = threadIdx.x >> 6, ln = threadIdx.x & 63;
  const float4* zr = (const float4*)(sRow + 8 * ln);
  const float4 z0 = zr[0], z1 = zr[1];
  for (int li = 0; li < 32; ++li) {
    const int l = wv * 32 + li;
    const float4* rp = (const float4*)(M0 + l * CC + 8 * ln);
    const float4 a = rp[0], b = rp[1];
    float s = a.x * z0.x + a.y * z0.y + a.z * z0.z + a.w * z0.w +
              b.x * z1.x + b.y * z1.y + b.z * z1.z + b.w * z1.w;
    s = wsum64(s);
    if (ln == 0) wsA0[k * KK + l] = s + (l == k ? 1.0f : 0.0f);
  }
}

// ------- Kernel 2 (fused): WGs 0..63 -> P = M0 Z^T, S = Z Z^T ; WG 64 -> inv(A0) -------
__global__ __launch_bounds__(1024) void psinv_kernel(const float* __restrict__ x,
                                                     const float* __restrict__ M0,
                                                     float* __restrict__ wsP,
                                                     float* __restrict__ wsS,
                                                     const float* __restrict__ A0g,
                                                     float* __restrict__ Ainv0) {
  __shared__ __align__(16) float zAll[32][520];
  __shared__ __align__(16) float Mch[2][16][520];
  __shared__ float sFb[2][128];
  __shared__ __align__(16) float sPv[2][256];
  __shared__ float sScal[2];
  const int tid = threadIdx.x;

  if (blockIdx.x < 64) {
    // ================= ps body =================
    const int b = blockIdx.x;
    {
      const float4* x4 = (const float4*)(x + (size_t)b * EE * CC);
#pragma unroll
      for (int i = 0; i < 4; i++) {
        const int F = tid + 1024 * i, e = F >> 7, c4 = F & 127;
        ((float4*)zAll[e])[c4] = x4[F];
      }
    }
    const float4* M4 = (const float4*)M0;
    const int srow = tid >> 7, sc4 = tid & 127;
    float4 st0 = M4[srow * 128 + sc4];
    float4 st1 = M4[(8 + srow) * 128 + sc4];
    int buf = 0;
    const int p = tid & 7;           // 8 threads per dot
    const int ep = (tid >> 3) & 15;  // episodes 2*ep, 2*ep+1  (0..31)
    const int kp = tid >> 7;         // k rows kp, kp+8
#pragma unroll 1
    for (int kc = 0; kc < 8; ++kc) {
      ((float4*)Mch[buf][srow])[sc4] = st0;
      ((float4*)Mch[buf][8 + srow])[sc4] = st1;
      __syncthreads();
      if (kc + 1 < 8) {
        st0 = M4[((kc + 1) * 16 + srow) * 128 + sc4];
        st1 = M4[((kc + 1) * 16 + 8 + srow) * 128 + sc4];
      }
      float s00 = 0, s01 = 0, s10 = 0, s11 = 0;
      const float* m0 = Mch[buf][kp];
      const float* m1 = Mch[buf][kp + 8];
      const float* z0 = zAll[2 * ep];
      const float* z1 = zAll[2 * ep + 1];
#pragma unroll
      for (int u = 0; u < 16; u++) {
        const int c = 4 * p + 32 * u;
        const float4 a0 = *(const float4*)(m0 + c);
        const float4 a1 = *(const float4*)(m1 + c);
        const float4 b0 = *(const float4*)(z0 + c);
        const float4 b1 = *(const float4*)(z1 + c);
        s00 += a0.x * b0.x + a0.y * b0.y + a0.z * b0.z + a0.w * b0.w;
        s01 += a0.x * b1.x + a0.y * b1.y + a0.z * b1.z + a0.w * b1.w;
        s10 += a1.x * b0.x + a1.y * b0.y + a1.z * b0.z + a1.w * b0.w;
        s11 += a1.x * b1.x + a1.y * b1.y + a1.z * b1.z + a1.w * b1.w;
      }
#pragma unroll
      for (int m = 1; m <= 4; m <<= 1) {
        s00 += __shfl_xor(s00, m, 64); s01 += __shfl_xor(s01, m, 64);
        s10 += __shfl_xor(s10, m, 64); s11 += __shfl_xor(s11, m, 64);
      }
      if (p == 0) {
        float* Pb = wsP + (size_t)b * KK * EE;
        Pb[(kc * 16 + kp) * EE + 2 * ep] = s00;
        Pb[(kc * 16 + kp) * EE + 2 * ep + 1] = s01;
        Pb[(kc * 16 + kp + 8) * EE + 2 * ep] = s10;
        Pb[(kc * 16 + kp + 8) * EE + 2 * ep + 1] = s11;
      }
      buf ^= 1;
    }
    // S = Z Z^T
    {
      const int e = tid >> 5, f = tid & 31;
      const float4* ze = (const float4*)zAll[e];
      const float4* zf = (const float4*)zAll[f];
      float a0 = 0, a1 = 0, a2 = 0, a3 = 0;
#pragma unroll 4
      for (int u = 0; u < 128; u++) {
        const float4 A = ze[u], Bq = zf[u];
        a0 += A.x * Bq.x; a1 += A.y * Bq.y; a2 += A.z * Bq.z; a3 += A.w * Bq.w;
      }
      wsS[(size_t)b * EE * EE + e * EE + f] = (a0 + a1) + (a2 + a3);
    }
  } else {
    // ================= inv0 body (WG 64): register GJ, conditional pivot loads =================
    const int r = tid >> 3, q = tid & 7;
    float wreg[16], vreg[16];
    {
      const float4* a4 = (const float4*)(A0g + r * KK + 16 * q);
#pragma unroll
      for (int u = 0; u < 4; u++) {
        const float4 t4 = a4[u];
        wreg[4 * u] = t4.x; wreg[4 * u + 1] = t4.y; wreg[4 * u + 2] = t4.z; wreg[4 * u + 3] = t4.w;
      }
#pragma unroll
      for (int c = 0; c < 16; c++) vreg[c] = (16 * q + c == r) ? 1.0f : 0.0f;
    }
    if (q == 0) sFb[0][r] = wreg[0];
    if (r == 0) {
#pragma unroll
      for (int c = 0; c < 16; c++) { sPv[0][16 * q + c] = wreg[c]; sPv[0][128 + 16 * q + c] = vreg[c]; }
    }
    if (tid == 0) sScal[0] = 1.0f / wreg[0];
    __syncthreads();
#pragma unroll 1
    for (int j = 0; j < KK; ++j) {
      const int sl = j & 1, sn = sl ^ 1;
      const float f = sFb[sl][r] * sScal[sl];
      if (r != j) {
        if (16 * q + 15 >= j) {
          const float4* w4 = (const float4*)(sPv[sl] + 16 * q);
#pragma unroll
          for (int u = 0; u < 4; u++) {
            const float4 aa = w4[u];
            wreg[4 * u] -= f * aa.x; wreg[4 * u + 1] -= f * aa.y;
            wreg[4 * u + 2] -= f * aa.z; wreg[4 * u + 3] -= f * aa.w;
          }
        }
        if (16 * q <= j) {
          const float4* v4 = (const float4*)(sPv[sl] + 128 + 16 * q);
#pragma unroll
          for (int u = 0; u < 4; u++) {
            const float4 bb = v4[u];
            vreg[4 * u] -= f * bb.x; vreg[4 * u + 1] -= f * bb.y;
            vreg[4 * u + 2] -= f * bb.z; vreg[4 * u + 3] -= f * bb.w;
          }
        }
      }
      if (j + 1 < KK) {
        const int jn = j + 1;
        float wval = 0.0f;
#pragma unroll
        for (int c = 0; c < 16; c++) if (c == (jn & 15)) wval = wreg[c];
        if (q == (jn >> 4)) sFb[sn][r] = wval;
        if (r == jn) {
#pragma unroll
          for (int c = 0; c < 16; c++) { sPv[sn][16 * q + c] = wreg[c]; sPv[sn][128 + 16 * q + c] = vreg[c]; }
        }
        if (r == jn && q == (jn >> 4)) sScal[sn] = 1.0f / wval;
      }
      __syncthreads();
    }
    {
      float dval = 0.0f;
#pragma unroll
      for (int c = 0; c < 16; c++) if (c == (r & 15)) dval = wreg[c];
      if (q == (r >> 4)) sFb[0][r] = dval;
    }
    __syncthreads();
    {
      const float sc = 1.0f / sFb[0][r];
      float4* o4 = (float4*)(Ainv0 + r * KK + 16 * q);
#pragma unroll
      for (int u = 0; u < 4; u++) {
        float4 o;
        o.x = vreg[4 * u] * sc; o.y = vreg[4 * u + 1] * sc;
        o.z = vreg[4 * u + 2] * sc; o.w = vreg[4 * u + 3] * sc;
        o4[u] = o;
      }
    }
  }
}

// ---------------- Kernel 3: scan, 512 threads, one WG per batch ----------------
// DS-instruction-count round: 8 waves (not 16) behind each barrier; areg[32]/thread;
// k-major mirrors (sYk/sGk/sEk) turn the wU / Egg-append / q_next column walks into
// b128 row reads; S accessed via its exact symmetry; reduction dots placed on
// otherwise-idle wave halves at earliest-legal phase; scalars finalized per-thread.
__global__ __launch_bounds__(512) void scan_kernel(
    const float* __restrict__ Pg, const float* __restrict__ Sg,
    const float* __restrict__ scaleP, const float* __restrict__ Ainv0,
    float* __restrict__ wsAinvP, float* __restrict__ wsG,
    float* __restrict__ wsEggT, float* __restrict__ wsD,
    float* __restrict__ wsKL) {
  __shared__ __align__(16) float sPT[EE * PTS];    // P^T : [e][k]
  __shared__ __align__(16) float sGT[EE * LTR];    // G^T : [t][k]
  __shared__ __align__(16) float sYT[EE * LTR];    // Y^T : [t][k]
  __shared__ __align__(16) float sEggT[EE * LTR];  // Egg^T : [t][k]
  __shared__ __align__(16) float sGk[KK * LKM];    // G  : [k][t]
  __shared__ __align__(16) float sYk[KK * LKM];    // Y  : [k][j]
  __shared__ __align__(16) float sEk[KK * LKM];    // Egg: [k][s]
  __shared__ __align__(16) float sS[EE * L36];     // S (symmetric)
  __shared__ __align__(16) float sD[EE * L36];     // D : [s][r2]
  __shared__ __align__(16) float sW[160];
  __shared__ __align__(16) float sWU[160];
  __shared__ __align__(16) float sPu[160];
  __shared__ __align__(16) float sPm[160];
  __shared__ __align__(16) float sQ[160];
  __shared__ __align__(16) float sDz[EE];
  __shared__ __align__(16) float sDgw[EE];
  __shared__ __align__(16) float sQt[EE];
  __shared__ __align__(16) float sScal[16];

  const int tid = threadIdx.x, wv = tid >> 6, ln = tid & 63;
  const int mr = tid >> 2, mq = tid & 3;  // matvec: row mr, col-quarter mq (cols 32mq..32mq+31)
  const int b = blockIdx.x;

  float areg[32];
  {
    const float4* a4 = (const float4*)(Ainv0 + mr * KK + 32 * mq);
#pragma unroll
    for (int u = 0; u < 8; u++) {
      const float4 t4 = a4[u];
      areg[4 * u] = t4.x; areg[4 * u + 1] = t4.y; areg[4 * u + 2] = t4.z; areg[4 * u + 3] = t4.w;
    }
  }
  {
    const float* Pb = Pg + (size_t)b * KK * EE;
#pragma unroll
    for (int i = 0; i < 8; i++) {
      const int idx = tid + 512 * i;                  // idx = k*32 + e
      sPT[(idx & 31) * PTS + (idx >> 5)] = Pb[idx];   // transpose into [e][k]
    }
#pragma unroll
    for (int i = 0; i < 2; i++) {
      const int idx = tid + 512 * i;
      sS[(idx >> 5) * L36 + (idx & 31)] = Sg[(size_t)b * EE * EE + idx];
    }
  }
  if (tid < 16) sScal[tid] = 0.0f;
  const float v0 = scaleP[0] + V0EPS;
  __syncthreads();
  {  // w0 = Ainv0 * P[:,0]
    const float* xb = sPT + 32 * mq;
    float s = 0;
#pragma unroll
    for (int c = 0; c < 32; c++) s += areg[c] * xb[c];
    s += __shfl_xor(s, 1, 64); s += __shfl_xor(s, 2, 64);
    if (mq == 0) sW[SEG(mr)] = s;
  }
  __syncthreads();

#pragma unroll 1
  for (int t = 0; t < EE; ++t) {
    const bool hn = (t + 1 < EE);
    // ---- PH1: Pm = Ainv w ; dgw = G^T w ; qt = Y^T w ; S2 ----
    {
      const float* xb = sW + 40 * mq;
      float s = 0;
#pragma unroll
      for (int c = 0; c < 16; c++) s += areg[c] * xb[c];
#pragma unroll
      for (int c = 0; c < 16; c++) s += areg[16 + c] * xb[20 + c];
      s += __shfl_xor(s, 1, 64); s += __shfl_xor(s, 2, 64);
      if (mq == 0) sPm[SEG(mr)] = s;
    }
    if (tid < 256) {
      const int s8 = tid >> 3, p3 = tid & 7;
      if (s8 < t) {
        const float* gr = sGT + s8 * LTR + 16 * p3;
        const float* wr_ = sW + 20 * p3;
        float s = 0;
#pragma unroll
        for (int kk = 0; kk < 16; kk++) s += gr[kk] * wr_[kk];
        s += __shfl_xor(s, 1, 64); s += __shfl_xor(s, 2, 64); s += __shfl_xor(s, 4, 64);
        if (p3 == 0) sDgw[s8] = s;
      } else if (s8 == 31) {  // s8==31 never used by dgw (s8<t, t<=31): S2 here
        const float* wp = sW + 20 * p3;
        float s = 0;
#pragma unroll
        for (int kk = 0; kk < 16; kk++) s += wp[kk] * wp[kk];
        s += __shfl_xor(s, 1, 64); s += __shfl_xor(s, 2, 64); s += __shfl_xor(s, 4, 64);
        if (p3 == 0) sScal[SC_S2] = s;
      }
    } else {
      const int j = (tid - 256) >> 3, p3 = tid & 7;
      if (j < t) {
        const float* yr = sYT + j * LTR + 16 * p3;
        const float* wr_ = sW + 20 * p3;
        float s = 0;
#pragma unroll
        for (int kk = 0; kk < 16; kk++) s += yr[kk] * wr_[kk];
        s += __shfl_xor(s, 1, 64); s += __shfl_xor(s, 2, 64); s += __shfl_xor(s, 4, 64);
        if (p3 == 0) sQt[j] = s;
      }
    }
    __syncthreads();
    // ---- PH2: wU ; D_t ; Egg_t ; sigma ; KL ; R22 ----
    if (tid < 256) {  // wU[k] = v0 w[k] - sum_{j<t} Y[k][j] qt[j]
      const int k = tid >> 1, h = tid & 1;
      const float* yk = sYk + k * LKM + 16 * h;
      const float* qb = sQt + 16 * h;
      float a = 0;
#pragma unroll
      for (int u = 0; u < 16; u++) {
        const int j = 16 * h + u;
        a += (j < t) ? yk[u] * qb[u] : 0.0f;
      }
      a += __shfl_xor(a, 1, 64);
      if (h == 0) sWU[SEG(k)] = v0 * sW[SEG(k)] - a;
    } else if (tid < 384) {  // Egg append (k-major recurrence)
      const int k = tid - 256;
      float a = sW[SEG(k)];
      const float* ek = sEk + k * LKM;
      const int nc = (t + 3) >> 2;
#pragma unroll 1
      for (int c4 = 0; c4 < nc; ++c4) {
        const float4 ev = *(const float4*)(ek + 4 * c4);
        const float4 dv = *(const float4*)(sDgw + 4 * c4);
        const int u0 = 4 * c4;
        a -= ((u0 + 0 < t) ? ev.x * dv.x : 0.0f) + ((u0 + 1 < t) ? ev.y * dv.y : 0.0f) +
             ((u0 + 2 < t) ? ev.z * dv.z : 0.0f) + ((u0 + 3 < t) ? ev.w * dv.w : 0.0f);
      }
      sEk[k * LKM + t] = a;
      sEggT[t * LTR + k] = a;
    } else if (tid < 448) {  // wave 6: lanes<32: D append ; lanes>=32: R22 = w.Pm
      if (ln < 32) {
        const int r2 = ln;
        float a = (r2 == t) ? 1.0f : 0.0f;
        for (int s2 = 0; s2 < t; ++s2) a -= sDgw[s2] * sD[s2 * L36 + r2];
        sD[t * L36 + r2] = a;
      } else {
        const int k0 = (ln - 32) * 4;
        const float4 wv4 = *(const float4*)(sW + SEG(k0));
        const float4 pm4 = *(const float4*)(sPm + SEG(k0));
        float a = wv4.x * pm4.x + wv4.y * pm4.y + wv4.z * pm4.z + wv4.w * pm4.w;
        a = wsum32(a);
        if (ln == 32) sScal[SC_R22] = a;
      }
    } else {  // wave 7: sigma ; KL
      const float s2v = sScal[SC_S2];
      float a = (ln < t) ? sQt[ln] * sQt[ln] : 0.0f;
      a = wsum64(a);
      if (ln == 0) {
        sScal[SC_SIG] = v0 * s2v - a + 1.0f;
        sScal[SC_KL] += s2v;
      }
    }
    __syncthreads();
    // ---- PH3: Pu = Ainv wU ; dz ; B1 ; B2 ; R12 ; G/Y appends ----
    {
      const float* xb = sWU + 40 * mq;
      float s = 0;
#pragma unroll
      for (int c = 0; c < 16; c++) s += areg[c] * xb[c];
#pragma unroll
      for (int c = 0; c < 16; c++) s += areg[16 + c] * xb[20 + c];
      s += __shfl_xor(s, 1, 64); s += __shfl_xor(s, 2, 64);
      if (mq == 0) sPu[SEG(mr)] = s;
    }
    if (tid < 256) {  // dz[s4] = D[s4,:].S[:,t+1] - Egg^T[s4,:].P[:,t+1]
      const int s4 = tid >> 3, p3 = tid & 7;
      if (hn && s4 <= t) {
        const float* er = sEggT + s4 * LTR + 16 * p3;
        const float* pr = sPT + (t + 1) * PTS + 16 * p3;
        float a = 0;
#pragma unroll
        for (int kk = 0; kk < 16; kk++) a -= er[kk] * pr[kk];
        const float4 dv = *(const float4*)(sD + s4 * L36 + 4 * p3);
        const float4 sv = *(const float4*)(sS + (t + 1) * L36 + 4 * p3);  // S row == col (symmetric)
        a += dv.x * sv.x + dv.y * sv.y + dv.z * sv.z + dv.w * sv.w;
        a += __shfl_xor(a, 1, 64); a += __shfl_xor(a, 2, 64); a += __shfl_xor(a, 4, 64);
        if (p3 == 0) sDz[s4] = a;
      }
    } else if (tid < 320) {  // wave 4: B2 = Egg_t . P[:,t]
      float a = sEggT[t * LTR + ln] * sPT[t * PTS + ln] +
                sEggT[t * LTR + ln + 64] * sPT[t * PTS + ln + 64];
      a = wsum64(a);
      if (ln == 0) sScal[SC_B2] = a;
    } else if (tid < 384) {  // wave 5: lanes<32: B1 ; lanes>=32: R12 = wU.Pm
      if (ln < 32) {
        float a = sD[t * L36 + ln] * sS[t * L36 + ln];
        a = wsum32(a);
        if (ln == 0) sScal[SC_B1] = a;
      } else {
        const int k0 = (ln - 32) * 4;
        const float4 wu4 = *(const float4*)(sWU + SEG(k0));
        const float4 pm4 = *(const float4*)(sPm + SEG(k0));
        float a = wu4.x * pm4.x + wu4.y * pm4.y + wu4.z * pm4.z + wu4.w * pm4.w;
        a = wsum32(a);
        if (ln == 32) sScal[SC_R12] = a;
      }
    } else if (tid < 448) {  // wave 6: G/Y appends (both layouts)
      const float sig = sScal[SC_SIG];
      const float rsq = rsqrtf(sig);
#pragma unroll
      for (int u = 0; u < 2; u++) {
        const int k = ln + 64 * u;
        const float wu = sWU[SEG(k)];
        const float gv = wu / sig;
        const float yv = wu * rsq;
        sGT[t * LTR + k] = gv;
        sGk[k * LKM + t] = gv;
        sYT[t * LTR + k] = yv;
        sYk[k * LKM + t] = yv;
      }
    }
    __syncthreads();
    // ---- PH4: q_next ; R11 ----
    if (hn) {
      const float* gk = sGk + mr * LKM + 8 * mq;
      const float* dzb = sDz + 8 * mq;
      float a = 0;
#pragma unroll
      for (int u = 0; u < 8; u++) {
        const int s2 = 8 * mq + u;
        a += (s2 < t) ? gk[u] * dzb[u] : 0.0f;
      }
      a += __shfl_xor(a, 1, 64); a += __shfl_xor(a, 2, 64);
      if (mq == 0)
        sQ[SEG(mr)] = sPT[(t + 1) * PTS + mr] + a + (sWU[SEG(mr)] / sScal[SC_SIG]) * sDz[t];
    }
    if (wv == 0) {  // R11 = wU . Pu
      float a = sWU[SEG(ln)] * sPu[SEG(ln)] + sWU[SEG(ln + 64)] * sPu[SEG(ln + 64)];
      a = wsum64(a);
      if (ln == 0) sScal[SC_R11] = a;
    }
    __syncthreads();
    // ---- PH5: Ainv rank-2 update (per-thread scalar finalize) ; w_next ----
    {
      const float4 sc0 = *(const float4*)(sScal);      // S2, SIG, KL, B1
      const float4 sc1 = *(const float4*)(sScal + 4);  // B2, R11, R12, R22
      const float rs = 1.0f / sc0.y;
      const float beta = sc0.w - sc1.x - sc0.x;
      const float e11 = sc1.y * rs * rs;
      const float e12 = sc1.z * rs + 1.0f;
      const float e22 = sc1.w - beta;
      const float rd = 1.0f / (e11 * e22 - e12 * e12);
      const float t11 = e22 * rd, t12 = -e12 * rd, t22 = e11 * rd;
      const float u1r = sPu[SEG(mr)] * rs, u2r = sPm[SEG(mr)];
      const float* pub = sPu + 40 * mq;
      const float* pmb = sPm + 40 * mq;
#pragma unroll
      for (int c = 0; c < 16; c++) {
        const float u1c = pub[c] * rs;
        const float u2c = pmb[c];
        areg[c] -= u1r * (t11 * u1c + t12 * u2c) + u2r * (t12 * u1c + t22 * u2c);
      }
#pragma unroll
      for (int c = 0; c < 16; c++) {
        const float u1c = pub[20 + c] * rs;
        const float u2c = pmb[20 + c];
        areg[16 + c] -= u1r * (t11 * u1c + t12 * u2c) + u2r * (t12 * u1c + t22 * u2c);
      }
    }
    if (hn) {
      const float* xb = sQ + 40 * mq;
      float s = 0;
#pragma unroll
      for (int c = 0; c < 16; c++) s += areg[c] * xb[c];
#pragma unroll
      for (int c = 0; c < 16; c++) s += areg[16 + c] * xb[20 + c];
      s += __shfl_xor(s, 1, 64); s += __shfl_xor(s, 2, 64);
      if (mq == 0) sW[SEG(mr)] = s;
    }
    __syncthreads();
  }

  // ---- epilogue ----
  {
    float4* aout = (float4*)(wsAinvP + (size_t)b * KK * KK + mr * KK + 32 * mq);
#pragma unroll
    for (int u = 0; u < 8; u++) {
      float4 o;
      o.x = areg[4 * u]; o.y = areg[4 * u + 1]; o.z = areg[4 * u + 2]; o.w = areg[4 * u + 3];
      aout[u] = o;
    }
  }
#pragma unroll
  for (int i = 0; i < 8; i++) {
    const int idx = tid + 512 * i;  // idx = k*32 + e (global layout unchanged)
    wsG[(size_t)b * 4096 + idx] = sGT[(idx & 31) * LTR + (idx >> 5)];
    wsEggT[(size_t)b * 4096 + idx] = sEggT[(idx >> 7) * LTR + (idx & 127)];
  }
#pragma unroll
  for (int i = 0; i < 2; i++) {
    const int idx = tid + 512 * i;
    wsD[(size_t)b * 1024 + idx] = sD[(idx >> 5) * L36 + (idx & 31)];
  }
  if (tid == 0) wsKL[b] = sScal[SC_KL];
}

// ---------------- Kernel 4 (fused postA+postB), one WG per batch ----------------
__global__ __launch_bounds__(1024) void postAB_kernel(
    const float* __restrict__ Pg, const float* __restrict__ Sg,
    const float* __restrict__ wsAinvP, const float* __restrict__ wsG,
    const float* __restrict__ wsEggT, const float* __restrict__ wsD,
    const float* __restrict__ x, const float* __restrict__ M0,
    const float* __restrict__ znoise,
    float* __restrict__ wsKLr, float* __restrict__ out) {
  __shared__ __align__(16) float SM[25856];  // 103.4 KB, lifetime-aliased
  float* sP    = SM;            // 4352  [128][34]
  float* sG    = SM + 4352;     // 4352
  float* sRhs  = SM + 8704;     // 4352
  float* sWr   = SM + 13056;    // 4352
  float* sEggT = SM + 17408;    // 4224  [32][132]
  float* sD    = SM + 21632;    // 1056  [32][33]
  float* sS    = SM + 22688;    // 1056
  float* sR1   = SM + 23744;    // 1056
  float* sGam  = SM + 24800;    // 1056
  float* sWt   = SM;            // 5440 floats: overlays dead sP + head of sG (postB)
  float* Mch   = SM + 8704;     // 8320 floats: overlays dead sRhs + sWr (postB)

  const int tid = threadIdx.x, b = blockIdx.x;
  const int r = tid >> 3, q = tid & 7;
#pragma unroll
  for (int i = 0; i < 4; i++) {
    const int idx = tid + 1024 * i;
    sP[(idx >> 5) * LPA + (idx & 31)] = Pg[(size_t)b * 4096 + idx];
    sG[(idx >> 5) * LPA + (idx & 31)] = wsG[(size_t)b * 4096 + idx];
    sEggT[(idx >> 7) * LTR + (idx & 127)] = wsEggT[(size_t)b * 4096 + idx];
  }
  sD[(tid >> 5) * L33 + (tid & 31)] = wsD[(size_t)b * 1024 + tid];
  sS[(tid >> 5) * L33 + (tid & 31)] = Sg[(size_t)b * 1024 + tid];
  __syncthreads();
  // R1 = D S - Egg^T P
  {
    const int s = tid >> 5, e = tid & 31;
    float acc = 0;
#pragma unroll 4
    for (int f = 0; f < 32; f++) acc += sD[s * L33 + f] * sS[f * L33 + e];
#pragma unroll 4
    for (int rr = 0; rr < 128; rr++) acc -= sEggT[s * LTR + rr] * sP[rr * LPA + e];
    sR1[s * L33 + e] = acc;
  }
  __syncthreads();
  // rhs = P + G R1
  {
#pragma unroll
    for (int u = 0; u < 4; u++) {
      const int e = q + 8 * u;
      float acc = sP[r * LPA + e];
#pragma unroll 4
      for (int s = 0; s < 32; s++) acc += sG[r * LPA + s] * sR1[s * L33 + e];
      sRhs[r * LPA + e] = acc;
    }
  }
  __syncthreads();
  // w_read = Ainv_post rhs
  {
    float areg[16];
    const float4* a4 = (const float4*)(wsAinvP + (size_t)b * KK * KK + r * KK + 16 * q);
#pragma unroll
    for (int u = 0; u < 4; u++) {
      const float4 t4 = a4[u];
      areg[4 * u] = t4.x; areg[4 * u + 1] = t4.y; areg[4 * u + 2] = t4.z; areg[4 * u + 3] = t4.w;
    }
#pragma unroll 1
    for (int e = 0; e < 32; ++e) {
      float s = 0;
#pragma unroll
      for (int c = 0; c < 16; c++) s += areg[c] * sRhs[(16 * q + c) * LPA + e];
      s += __shfl_xor(s, 1, 64); s += __shfl_xor(s, 2, 64); s += __shfl_xor(s, 4, 64);
      if (q == 0) sWr[r * LPA + e] = s;
    }
  }
  __syncthreads();
  // Gam = G^T w
  {
    const int s = tid >> 5, e = tid & 31;
    float acc = 0;
#pragma unroll 4
    for (int rr = 0; rr < 128; rr++) acc += sG[rr * LPA + s] * sWr[rr * LPA + e];
    sGam[s * L33 + e] = acc;
  }
  __syncthreads();
  // Wc = w - Egg Gam -> sWt[0..127] ; Vc = D^T Gam -> sWt[128..159] ; KLr
  // (sWt overlays sP and head of sG — both dead now)
  {
#pragma unroll
    for (int u = 0; u < 4; u++) {
      const int e = q + 8 * u;
      float acc = sWr[r * LPA + e];
#pragma unroll 4
      for (int s = 0; s < 32; s++) acc -= sEggT[s * LTR + r] * sGam[s * L33 + e];
      sWt[r * 34 + e] = acc;
    }
    const int s7 = tid >> 5, e7 = tid & 31;
    float acc2 = 0;
#pragma unroll 4
    for (int f = 0; f < 32; f++) acc2 += sD[f * L33 + s7] * sGam[f * L33 + e7];
    sWt[(128 + s7) * 34 + e7] = acc2;
    if (tid < 512) {
      const int e6 = tid >> 4, p6 = tid & 15;
      float s = 0;
#pragma unroll
      for (int u = 0; u < 8; u++) {
        const float w_ = sWr[(8 * p6 + u) * LPA + e6];
        s += w_ * w_;
      }
      s += __shfl_xor(s, 1, 64); s += __shfl_xor(s, 2, 64);
      s += __shfl_xor(s, 4, 64); s += __shfl_xor(s, 8, 64);
      if (p6 == 0) wsKLr[b * EE + e6] = s;
    }
  }
  __syncthreads();

  // ===== postB: z_mean = [M0; Z]^T [Wc; Vc] + noise (Mch overlays dead sRhs+sWr) =====
  {
    const int srow = tid >> 7, sc4 = tid & 127;
    const float4* M4 = (const float4*)M0;
    const float4* X4 = (const float4*)(x + (size_t)b * EE * CC);
    float4 st = M4[srow * 128 + sc4];
    int buf = 0;
    const int e = tid & 31, cseg = tid >> 5;
    float acc[16];
#pragma unroll
    for (int u = 0; u < 16; u++) acc[u] = 0;
#pragma unroll 1
    for (int ch = 0; ch < 20; ++ch) {
      ((float4*)(Mch + buf * 4160 + srow * 520))[sc4] = st;
      __syncthreads();
      if (ch + 1 < 20) {
        st = (ch + 1 < 16) ? M4[((ch + 1) * 8 + srow) * 128 + sc4]
                           : X4[((ch + 1 - 16) * 8 + srow) * 128 + sc4];
      }
#pragma unroll
      for (int kk = 0; kk < 8; kk++) {
        const float wk = sWt[(ch * 8 + kk) * 34 + e];
        const float* mr = Mch + buf * 4160 + kk * 520 + 16 * cseg;
        const float4 m0 = *(const float4*)(mr);
        const float4 m1 = *(const float4*)(mr + 4);
        const float4 m2 = *(const float4*)(mr + 8);
        const float4 m3 = *(const float4*)(mr + 12);
        acc[0] += wk * m0.x;  acc[1] += wk * m0.y;  acc[2] += wk * m0.z;  acc[3] += wk * m0.w;
        acc[4] += wk * m1.x;  acc[5] += wk * m1.y;  acc[6] += wk * m1.z;  acc[7] += wk * m1.w;
        acc[8] += wk * m2.x;  acc[9] += wk * m2.y;  acc[10] += wk * m2.z; acc[11] += wk * m2.w;
        acc[12] += wk * m3.x; acc[13] += wk * m3.y; acc[14] += wk * m3.z; acc[15] += wk * m3.w;
      }
      buf ^= 1;
    }
    {
      const size_t ob = ((size_t)b * EE + e) * CC + 16 * cseg;
      const size_t nb = ((size_t)e * BB + b) * CC + 16 * cseg;
#pragma unroll
      for (int u = 0; u < 4; u++) {
        const float4 nz = *(const float4*)(znoise + nb + 4 * u);
        float4 o;
        o.x = acc[4 * u] + nz.x;     o.y = acc[4 * u + 1] + nz.y;
        o.z = acc[4 * u + 2] + nz.z; o.w = acc[4 * u + 3] + nz.w;
        *(float4*)(out + ob + 4 * u) = o;
      }
    }
  }
}

// ---------------- Kernel 5: total divergence ----------------
__global__ __launch_bounds__(256) void final_kernel(const float* __restrict__ wsKL,
                                                    const float* __restrict__ wsKLr,
                                                    const float* __restrict__ lwsP,
                                                    float* __restrict__ out) {
  __shared__ float sPp[256];
  const int tid = threadIdx.x;
  float s = 0.0f;
  if (tid < 64) s += wsKL[tid];
  for (int i = tid; i < 2048; i += 256) s += wsKLr[i];
  sPp[tid] = s;
  __syncthreads();
  for (int off = 128; off > 0; off >>= 1) {
    if (tid < off) sPp[tid] += sPp[tid + off];
    __syncthreads();
  }
  if (tid == 0) {
    const float lws = lwsP[0];
    const float sw2 = expf(2.0f * lws);
    out[(size_t)BB * EE * CC] =
        0.5f * sPp[0] / (float)(EE * BB) + (float)KK * (sw2 - 1.0f - 2.0f * lws);
  }
}

extern "C" void kernel_launch(void* const* d_in, const int* in_sizes, int n_in,
                              void* d_out, int out_size, void* d_ws, size_t ws_size,
                              hipStream_t stream) {
  (void)in_sizes; (void)n_in; (void)out_size; (void)ws_size;
  const float* x = (const float*)d_in[0];        // [B,E,C]
  const float* M0 = (const float*)d_in[1];       // [K,C]
  const float* scaleP = (const float*)d_in[2];   // scalar
  const float* lwsP = (const float*)d_in[3];     // scalar
  const float* znoise = (const float*)d_in[4];   // [E,B,C]
  float* out = (float*)d_out;

  float* ws = (float*)d_ws;
  float* wsP = ws;                        // 64*128*32 = 262144
  float* wsS = wsP + 262144;              // 64*32*32  = 65536
  float* wsA0 = wsS + 65536;              // 16384
  float* wsAinv0 = wsA0 + 16384;          // 16384
  float* wsAinvP = wsAinv0 + 16384;       // 64*16384 = 1048576
  float* wsG = wsAinvP + 1048576;         // 64*4096 = 262144
  float* wsEggT = wsG + 262144;           // 262144
  float* wsD = wsEggT + 262144;           // 65536
  float* wsKL = wsD + 65536;              // 64
  float* wsKLr = wsKL + 64;               // 2048

  a0_kernel<<<KK, 256, 0, stream>>>(M0, wsA0);
  psinv_kernel<<<65, 1024, 0, stream>>>(x, M0, wsP, wsS, wsA0, wsAinv0);
  scan_kernel<<<BB, 512, 0, stream>>>(wsP, wsS, scaleP, wsAinv0,
                                      wsAinvP, wsG, wsEggT, wsD, wsKL);
  postAB_kernel<<<BB, 1024, 0, stream>>>(wsP, wsS, wsAinvP, wsG, wsEggT, wsD,
                                         x, M0, znoise, wsKLr, out);
  final_kernel<<<1, 256, 0, stream>>>(wsKL, wsKLr, lwsP, out);
}

// Round 3
// 359.804 us; speedup vs baseline: 1.0569x; 1.0426x over previous
//
#include <hip/hip_runtime.h>

// (B,E,K,C) = (64,32,128,512), fp32.
#define BB 64
#define EE 32
#define KK 128
#define CC 512
#define V0EPS 1e-7f

#define LPA 34    // [128][34] padded stride (postA kernel)
#define LTR 132   // [32][132] padded stride
#define L33 33    // [32][33] padded stride (postA kernel)
#define PTS 132   // scan: P^T row stride
#define LKM 36    // scan: k-major row stride (G/Y/Egg)
#define L36 36    // scan: S/D row stride
#define LWT 176   // postB: Wt^T row stride (176 mod 32 == 16 -> 2-way, free)
// segment-padded K-vector layout: element i lives at (i/16)*20 + (i%16)
#define SEG(i) ((((i) >> 4) * 20) + ((i) & 15))

// scan sScal slots (order matters: read as two float4s in PH5)
#define SC_S2  0
#define SC_SIG 1
#define SC_KL  2
#define SC_B1  3
#define SC_B2  4
#define SC_R11 5
#define SC_R12 6
#define SC_R22 7

__device__ __forceinline__ float wsum64(float v) {
#pragma unroll
  for (int m = 32; m >= 1; m >>= 1) v += __shfl_xor(v, m, 64);
  return v;
}

__device__ __forceinline__ float wsum32(float v) {  // reduce within aligned 32-lane half
#pragma unroll
  for (int m = 16; m >= 1; m >>= 1) v += __shfl_xor(v, m, 64);
  return v;
}

// ---------------- Kernel 1: A0 = M0 M0^T + I (256 WGs: k x l-half) ----------------
__global__ __launch_bounds__(256) void a0_kernel(const float* __restrict__ M0,
                                                 float* __restrict__ wsA0) {
  __shared__ __align__(16) float sRow[CC];
  const int k = blockIdx.x >> 1, half = blockIdx.x & 1;
  for (int c = threadIdx.x; c < CC; c += 256) sRow[c] = M0[k * CC + c];
  __syncthreads();
  const int wv = threadIdx.x >> 6, ln = threadIdx.x & 63;
  const float4* zr = (const float4*)(sRow + 8 * ln);
  const float4 z0 = zr[0], z1 = zr[1];
  for (int li = 0; li < 16; ++li) {
    const int l = half * 64 + wv * 16 + li;
    const float4* rp = (const float4*)(M0 + l * CC + 8 * ln);
    const float4 a = rp[0], b = rp[1];
    float s = a.x * z0.x + a.y * z0.y + a.z * z0.z + a.w * z0.w +
              b.x * z1.x + b.y * z1.y + b.z * z1.z + b.w * z1.w;
    s = wsum64(s);
    if (ln == 0) wsA0[k * KK + l] = s + (l == k ? 1.0f : 0.0f);
  }
}

// ------- Kernel 2: block 0 -> inv(A0) ; blocks 1..256 -> (b, k-quarter) of P, c-quarter of S -------
__global__ __launch_bounds__(1024) void psinv_kernel(const float* __restrict__ x,
                                                     const float* __restrict__ M0,
                                                     float* __restrict__ wsP,
                                                     float* __restrict__ wsSp,
                                                     const float* __restrict__ A0g,
                                                     float* __restrict__ Ainv0) {
  __shared__ __align__(16) float zAll[32][520];
  __shared__ __align__(16) float Mch[2][16][520];
  __shared__ float sFb[2][128];
  __shared__ __align__(16) float sPv[2][256];
  __shared__ float sScal[2];
  const int tid = threadIdx.x;

  if (blockIdx.x > 0) {
    // ================= ps body: P rows kq*32..kq*32+31 ; S partial over c-quarter =================
    const int b = (blockIdx.x - 1) >> 2, kq = (blockIdx.x - 1) & 3;
    {
      const float4* x4 = (const float4*)(x + (size_t)b * EE * CC);
#pragma unroll
      for (int i = 0; i < 4; i++) {
        const int F = tid + 1024 * i, e = F >> 7, c4 = F & 127;
        ((float4*)zAll[e])[c4] = x4[F];
      }
    }
    const float4* M4 = (const float4*)M0;
    const int srow = tid >> 7, sc4 = tid & 127;
    const int kbase = kq * 32;
    float4 st0 = M4[(kbase + srow) * 128 + sc4];
    float4 st1 = M4[(kbase + 8 + srow) * 128 + sc4];
    int buf = 0;
    const int p = tid & 7;           // 8 threads per dot
    const int ep = (tid >> 3) & 15;  // episodes 2*ep, 2*ep+1  (0..31)
    const int kp = tid >> 7;         // k rows kp, kp+8
#pragma unroll 1
    for (int kc = 0; kc < 2; ++kc) {
      ((float4*)Mch[buf][srow])[sc4] = st0;
      ((float4*)Mch[buf][8 + srow])[sc4] = st1;
      __syncthreads();
      if (kc == 0) {
        st0 = M4[(kbase + 16 + srow) * 128 + sc4];
        st1 = M4[(kbase + 24 + srow) * 128 + sc4];
      }
      float s00 = 0, s01 = 0, s10 = 0, s11 = 0;
      const float* m0 = Mch[buf][kp];
      const float* m1 = Mch[buf][kp + 8];
      const float* z0 = zAll[2 * ep];
      const float* z1 = zAll[2 * ep + 1];
#pragma unroll
      for (int u = 0; u < 16; u++) {
        const int c = 4 * p + 32 * u;
        const float4 a0 = *(const float4*)(m0 + c);
        const float4 a1 = *(const float4*)(m1 + c);
        const float4 b0 = *(const float4*)(z0 + c);
        const float4 b1 = *(const float4*)(z1 + c);
        s00 += a0.x * b0.x + a0.y * b0.y + a0.z * b0.z + a0.w * b0.w;
        s01 += a0.x * b1.x + a0.y * b1.y + a0.z * b1.z + a0.w * b1.w;
        s10 += a1.x * b0.x + a1.y * b0.y + a1.z * b0.z + a1.w * b0.w;
        s11 += a1.x * b1.x + a1.y * b1.y + a1.z * b1.z + a1.w * b1.w;
      }
#pragma unroll
      for (int m = 1; m <= 4; m <<= 1) {
        s00 += __shfl_xor(s00, m, 64); s01 += __shfl_xor(s01, m, 64);
        s10 += __shfl_xor(s10, m, 64); s11 += __shfl_xor(s11, m, 64);
      }
      if (p == 0) {
        float* Pb = wsP + (size_t)b * KK * EE;
        Pb[(kbase + kc * 16 + kp) * EE + 2 * ep] = s00;
        Pb[(kbase + kc * 16 + kp) * EE + 2 * ep + 1] = s01;
        Pb[(kbase + kc * 16 + kp + 8) * EE + 2 * ep] = s10;
        Pb[(kbase + kc * 16 + kp + 8) * EE + 2 * ep + 1] = s11;
      }
      buf ^= 1;
    }
    // S partial = Z[:, cq] Z[:, cq]^T
    {
      const int e = tid >> 5, f = tid & 31;
      const float4* ze = ((const float4*)zAll[e]) + 32 * kq;
      const float4* zf = ((const float4*)zAll[f]) + 32 * kq;
      float a0 = 0, a1 = 0, a2 = 0, a3 = 0;
#pragma unroll 4
      for (int u = 0; u < 32; u++) {
        const float4 A = ze[u], Bq = zf[u];
        a0 += A.x * Bq.x; a1 += A.y * Bq.y; a2 += A.z * Bq.z; a3 += A.w * Bq.w;
      }
      wsSp[((size_t)b * 4 + kq) * 1024 + e * EE + f] = (a0 + a1) + (a2 + a3);
    }
  } else {
    // ================= inv0 body (block 0): register GJ, conditional pivot loads =================
    const int r = tid >> 3, q = tid & 7;
    float wreg[16], vreg[16];
    {
      const float4* a4 = (const float4*)(A0g + r * KK + 16 * q);
#pragma unroll
      for (int u = 0; u < 4; u++) {
        const float4 t4 = a4[u];
        wreg[4 * u] = t4.x; wreg[4 * u + 1] = t4.y; wreg[4 * u + 2] = t4.z; wreg[4 * u + 3] = t4.w;
      }
#pragma unroll
      for (int c = 0; c < 16; c++) vreg[c] = (16 * q + c == r) ? 1.0f : 0.0f;
    }
    if (q == 0) sFb[0][r] = wreg[0];
    if (r == 0) {
#pragma unroll
      for (int c = 0; c < 16; c++) { sPv[0][16 * q + c] = wreg[c]; sPv[0][128 + 16 * q + c] = vreg[c]; }
    }
    if (tid == 0) sScal[0] = 1.0f / wreg[0];
    __syncthreads();
#pragma unroll 1
    for (int j = 0; j < KK; ++j) {
      const int sl = j & 1, sn = sl ^ 1;
      const float f = sFb[sl][r] * sScal[sl];
      if (r != j) {
        if (16 * q + 15 >= j) {
          const float4* w4 = (const float4*)(sPv[sl] + 16 * q);
#pragma unroll
          for (int u = 0; u < 4; u++) {
            const float4 aa = w4[u];
            wreg[4 * u] -= f * aa.x; wreg[4 * u + 1] -= f * aa.y;
            wreg[4 * u + 2] -= f * aa.z; wreg[4 * u + 3] -= f * aa.w;
          }
        }
        if (16 * q <= j) {
          const float4* v4 = (const float4*)(sPv[sl] + 128 + 16 * q);
#pragma unroll
          for (int u = 0; u < 4; u++) {
            const float4 bb = v4[u];
            vreg[4 * u] -= f * bb.x; vreg[4 * u + 1] -= f * bb.y;
            vreg[4 * u + 2] -= f * bb.z; vreg[4 * u + 3] -= f * bb.w;
          }
        }
      }
      if (j + 1 < KK) {
        const int jn = j + 1;
        float wval = 0.0f;
#pragma unroll
        for (int c = 0; c < 16; c++) if (c == (jn & 15)) wval = wreg[c];
        if (q == (jn >> 4)) sFb[sn][r] = wval;
        if (r == jn) {
#pragma unroll
          for (int c = 0; c < 16; c++) { sPv[sn][16 * q + c] = wreg[c]; sPv[sn][128 + 16 * q + c] = vreg[c]; }
        }
        if (r == jn && q == (jn >> 4)) sScal[sn] = 1.0f / wval;
      }
      __syncthreads();
    }
    {
      float dval = 0.0f;
#pragma unroll
      for (int c = 0; c < 16; c++) if (c == (r & 15)) dval = wreg[c];
      if (q == (r >> 4)) sFb[0][r] = dval;
    }
    __syncthreads();
    {
      const float sc = 1.0f / sFb[0][r];
      float4* o4 = (float4*)(Ainv0 + r * KK + 16 * q);
#pragma unroll
      for (int u = 0; u < 4; u++) {
        float4 o;
        o.x = vreg[4 * u] * sc; o.y = vreg[4 * u + 1] * sc;
        o.z = vreg[4 * u + 2] * sc; o.w = vreg[4 * u + 3] * sc;
        o4[u] = o;
      }
    }
  }
}

// ---------------- Kernel 3: scan, 512 threads, one WG per batch (unchanged except S-partials sum) ----------------
__global__ __launch_bounds__(512) void scan_kernel(
    const float* __restrict__ Pg, const float* __restrict__ Sg,  // Sg = 4 partials per batch
    const float* __restrict__ scaleP, const float* __restrict__ Ainv0,
    float* __restrict__ wsAinvP, float* __restrict__ wsG,
    float* __restrict__ wsEggT, float* __restrict__ wsD,
    float* __restrict__ wsKL) {
  __shared__ __align__(16) float sPT[EE * PTS];    // P^T : [e][k]
  __shared__ __align__(16) float sGT[EE * LTR];    // G^T : [t][k]
  __shared__ __align__(16) float sYT[EE * LTR];    // Y^T : [t][k]
  __shared__ __align__(16) float sEggT[EE * LTR];  // Egg^T : [t][k]
  __shared__ __align__(16) float sGk[KK * LKM];    // G  : [k][t]
  __shared__ __align__(16) float sYk[KK * LKM];    // Y  : [k][j]
  __shared__ __align__(16) float sEk[KK * LKM];    // Egg: [k][s]
  __shared__ __align__(16) float sS[EE * L36];     // S (symmetric)
  __shared__ __align__(16) float sD[EE * L36];     // D : [s][r2]
  __shared__ __align__(16) float sW[160];
  __shared__ __align__(16) float sWU[160];
  __shared__ __align__(16) float sPu[160];
  __shared__ __align__(16) float sPm[160];
  __shared__ __align__(16) float sQ[160];
  __shared__ __align__(16) float sDz[EE];
  __shared__ __align__(16) float sDgw[EE];
  __shared__ __align__(16) float sQt[EE];
  __shared__ __align__(16) float sScal[16];

  const int tid = threadIdx.x, wv = tid >> 6, ln = tid & 63;
  const int mr = tid >> 2, mq = tid & 3;  // matvec: row mr, col-quarter mq
  const int b = blockIdx.x;

  float areg[32];
  {
    const float4* a4 = (const float4*)(Ainv0 + mr * KK + 32 * mq);
#pragma unroll
    for (int u = 0; u < 8; u++) {
      const float4 t4 = a4[u];
      areg[4 * u] = t4.x; areg[4 * u + 1] = t4.y; areg[4 * u + 2] = t4.z; areg[4 * u + 3] = t4.w;
    }
  }
  {
    const float* Pb = Pg + (size_t)b * KK * EE;
#pragma unroll
    for (int i = 0; i < 8; i++) {
      const int idx = tid + 512 * i;                  // idx = k*32 + e
      sPT[(idx & 31) * PTS + (idx >> 5)] = Pb[idx];   // transpose into [e][k]
    }
    const float* Sb = Sg + (size_t)b * 4096;
#pragma unroll
    for (int i = 0; i < 2; i++) {
      const int idx = tid + 512 * i;
      sS[(idx >> 5) * L36 + (idx & 31)] =
          Sb[idx] + Sb[idx + 1024] + Sb[idx + 2048] + Sb[idx + 3072];
    }
  }
  if (tid < 16) sScal[tid] = 0.0f;
  const float v0 = scaleP[0] + V0EPS;
  __syncthreads();
  {  // w0 = Ainv0 * P[:,0]
    const float* xb = sPT + 32 * mq;
    float s = 0;
#pragma unroll
    for (int c = 0; c < 32; c++) s += areg[c] * xb[c];
    s += __shfl_xor(s, 1, 64); s += __shfl_xor(s, 2, 64);
    if (mq == 0) sW[SEG(mr)] = s;
  }
  __syncthreads();

#pragma unroll 1
  for (int t = 0; t < EE; ++t) {
    const bool hn = (t + 1 < EE);
    // ---- PH1: Pm = Ainv w ; dgw = G^T w ; qt = Y^T w ; S2 ----
    {
      const float* xb = sW + 40 * mq;
      float s = 0;
#pragma unroll
      for (int c = 0; c < 16; c++) s += areg[c] * xb[c];
#pragma unroll
      for (int c = 0; c < 16; c++) s += areg[16 + c] * xb[20 + c];
      s += __shfl_xor(s, 1, 64); s += __shfl_xor(s, 2, 64);
      if (mq == 0) sPm[SEG(mr)] = s;
    }
    if (tid < 256) {
      const int s8 = tid >> 3, p3 = tid & 7;
      if (s8 < t) {
        const float* gr = sGT + s8 * LTR + 16 * p3;
        const float* wr_ = sW + 20 * p3;
        float s = 0;
#pragma unroll
        for (int kk = 0; kk < 16; kk++) s += gr[kk] * wr_[kk];
        s += __shfl_xor(s, 1, 64); s += __shfl_xor(s, 2, 64); s += __shfl_xor(s, 4, 64);
        if (p3 == 0) sDgw[s8] = s;
      } else if (s8 == 31) {  // s8==31 never used by dgw: S2 here
        const float* wp = sW + 20 * p3;
        float s = 0;
#pragma unroll
        for (int kk = 0; kk < 16; kk++) s += wp[kk] * wp[kk];
        s += __shfl_xor(s, 1, 64); s += __shfl_xor(s, 2, 64); s += __shfl_xor(s, 4, 64);
        if (p3 == 0) sScal[SC_S2] = s;
      }
    } else {
      const int j = (tid - 256) >> 3, p3 = tid & 7;
      if (j < t) {
        const float* yr = sYT + j * LTR + 16 * p3;
        const float* wr_ = sW + 20 * p3;
        float s = 0;
#pragma unroll
        for (int kk = 0; kk < 16; kk++) s += yr[kk] * wr_[kk];
        s += __shfl_xor(s, 1, 64); s += __shfl_xor(s, 2, 64); s += __shfl_xor(s, 4, 64);
        if (p3 == 0) sQt[j] = s;
      }
    }
    __syncthreads();
    // ---- PH2: wU ; D_t ; Egg_t ; sigma ; KL ; R22 ----
    if (tid < 256) {  // wU[k] = v0 w[k] - sum_{j<t} Y[k][j] qt[j]
      const int k = tid >> 1, h = tid & 1;
      const float* yk = sYk + k * LKM + 16 * h;
      const float* qb = sQt + 16 * h;
      float a = 0;
#pragma unroll
      for (int u = 0; u < 16; u++) {
        const int j = 16 * h + u;
        a += (j < t) ? yk[u] * qb[u] : 0.0f;
      }
      a += __shfl_xor(a, 1, 64);
      if (h == 0) sWU[SEG(k)] = v0 * sW[SEG(k)] - a;
    } else if (tid < 384) {  // Egg append (k-major recurrence)
      const int k = tid - 256;
      float a = sW[SEG(k)];
      const float* ek = sEk + k * LKM;
      const int nc = (t + 3) >> 2;
#pragma unroll 1
      for (int c4 = 0; c4 < nc; ++c4) {
        const float4 ev = *(const float4*)(ek + 4 * c4);
        const float4 dv = *(const float4*)(sDgw + 4 * c4);
        const int u0 = 4 * c4;
        a -= ((u0 + 0 < t) ? ev.x * dv.x : 0.0f) + ((u0 + 1 < t) ? ev.y * dv.y : 0.0f) +
             ((u0 + 2 < t) ? ev.z * dv.z : 0.0f) + ((u0 + 3 < t) ? ev.w * dv.w : 0.0f);
      }
      sEk[k * LKM + t] = a;
      sEggT[t * LTR + k] = a;
    } else if (tid < 448) {  // wave 6: lanes<32: D append ; lanes>=32: R22 = w.Pm
      if (ln < 32) {
        const int r2 = ln;
        float a = (r2 == t) ? 1.0f : 0.0f;
        for (int s2 = 0; s2 < t; ++s2) a -= sDgw[s2] * sD[s2 * L36 + r2];
        sD[t * L36 + r2] = a;
      } else {
        const int k0 = (ln - 32) * 4;
        const float4 wv4 = *(const float4*)(sW + SEG(k0));
        const float4 pm4 = *(const float4*)(sPm + SEG(k0));
        float a = wv4.x * pm4.x + wv4.y * pm4.y + wv4.z * pm4.z + wv4.w * pm4.w;
        a = wsum32(a);
        if (ln == 32) sScal[SC_R22] = a;
      }
    } else {  // wave 7: sigma ; KL
      const float s2v = sScal[SC_S2];
      float a = (ln < t) ? sQt[ln] * sQt[ln] : 0.0f;
      a = wsum64(a);
      if (ln == 0) {
        sScal[SC_SIG] = v0 * s2v - a + 1.0f;
        sScal[SC_KL] += s2v;
      }
    }
    __syncthreads();
    // ---- PH3: Pu = Ainv wU ; dz ; B1 ; B2 ; R12 ; G/Y appends ----
    {
      const float* xb = sWU + 40 * mq;
      float s = 0;
#pragma unroll
      for (int c = 0; c < 16; c++) s += areg[c] * xb[c];
#pragma unroll
      for (int c = 0; c < 16; c++) s += areg[16 + c] * xb[20 + c];
      s += __shfl_xor(s, 1, 64); s += __shfl_xor(s, 2, 64);
      if (mq == 0) sPu[SEG(mr)] = s;
    }
    if (tid < 256) {  // dz[s4] = D[s4,:].S[:,t+1] - Egg^T[s4,:].P[:,t+1]
      const int s4 = tid >> 3, p3 = tid & 7;
      if (hn && s4 <= t) {
        const float* er = sEggT + s4 * LTR + 16 * p3;
        const float* pr = sPT + (t + 1) * PTS + 16 * p3;
        float a = 0;
#pragma unroll
        for (int kk = 0; kk < 16; kk++) a -= er[kk] * pr[kk];
        const float4 dv = *(const float4*)(sD + s4 * L36 + 4 * p3);
        const float4 sv = *(const float4*)(sS + (t + 1) * L36 + 4 * p3);  // S symmetric
        a += dv.x * sv.x + dv.y * sv.y + dv.z * sv.z + dv.w * sv.w;
        a += __shfl_xor(a, 1, 64); a += __shfl_xor(a, 2, 64); a += __shfl_xor(a, 4, 64);
        if (p3 == 0) sDz[s4] = a;
      }
    } else if (tid < 320) {  // wave 4: B2 = Egg_t . P[:,t]
      float a = sEggT[t * LTR + ln] * sPT[t * PTS + ln] +
                sEggT[t * LTR + ln + 64] * sPT[t * PTS + ln + 64];
      a = wsum64(a);
      if (ln == 0) sScal[SC_B2] = a;
    } else if (tid < 384) {  // wave 5: lanes<32: B1 ; lanes>=32: R12 = wU.Pm
      if (ln < 32) {
        float a = sD[t * L36 + ln] * sS[t * L36 + ln];
        a = wsum32(a);
        if (ln == 0) sScal[SC_B1] = a;
      } else {
        const int k0 = (ln - 32) * 4;
        const float4 wu4 = *(const float4*)(sWU + SEG(k0));
        const float4 pm4 = *(const float4*)(sPm + SEG(k0));
        float a = wu4.x * pm4.x + wu4.y * pm4.y + wu4.z * pm4.z + wu4.w * pm4.w;
        a = wsum32(a);
        if (ln == 32) sScal[SC_R12] = a;
      }
    } else if (tid < 448) {  // wave 6: G/Y appends (both layouts)
      const float sig = sScal[SC_SIG];
      const float rsq = rsqrtf(sig);
#pragma unroll
      for (int u = 0; u < 2; u++) {
        const int k = ln + 64 * u;
        const float wu = sWU[SEG(k)];
        const float gv = wu / sig;
        const float yv = wu * rsq;
        sGT[t * LTR + k] = gv;
        sGk[k * LKM + t] = gv;
        sYT[t * LTR + k] = yv;
        sYk[k * LKM + t] = yv;
      }
    }
    __syncthreads();
    // ---- PH4: q_next ; R11 ----
    if (hn) {
      const float* gk = sGk + mr * LKM + 8 * mq;
      const float* dzb = sDz + 8 * mq;
      float a = 0;
#pragma unroll
      for (int u = 0; u < 8; u++) {
        const int s2 = 8 * mq + u;
        a += (s2 < t) ? gk[u] * dzb[u] : 0.0f;
      }
      a += __shfl_xor(a, 1, 64); a += __shfl_xor(a, 2, 64);
      if (mq == 0)
        sQ[SEG(mr)] = sPT[(t + 1) * PTS + mr] + a + (sWU[SEG(mr)] / sScal[SC_SIG]) * sDz[t];
    }
    if (wv == 0) {  // R11 = wU . Pu
      float a = sWU[SEG(ln)] * sPu[SEG(ln)] + sWU[SEG(ln + 64)] * sPu[SEG(ln + 64)];
      a = wsum64(a);
      if (ln == 0) sScal[SC_R11] = a;
    }
    __syncthreads();
    // ---- PH5: Ainv rank-2 update (per-thread scalar finalize) ; w_next ----
    {
      const float4 sc0 = *(const float4*)(sScal);      // S2, SIG, KL, B1
      const float4 sc1 = *(const float4*)(sScal + 4);  // B2, R11, R12, R22
      const float rs = 1.0f / sc0.y;
      const float beta = sc0.w - sc1.x - sc0.x;
      const float e11 = sc1.y * rs * rs;
      const float e12 = sc1.z * rs + 1.0f;
      const float e22 = sc1.w - beta;
      const float rd = 1.0f / (e11 * e22 - e12 * e12);
      const float t11 = e22 * rd, t12 = -e12 * rd, t22 = e11 * rd;
      const float u1r = sPu[SEG(mr)] * rs, u2r = sPm[SEG(mr)];
      const float* pub = sPu + 40 * mq;
      const float* pmb = sPm + 40 * mq;
#pragma unroll
      for (int c = 0; c < 16; c++) {
        const float u1c = pub[c] * rs;
        const float u2c = pmb[c];
        areg[c] -= u1r * (t11 * u1c + t12 * u2c) + u2r * (t12 * u1c + t22 * u2c);
      }
#pragma unroll
      for (int c = 0; c < 16; c++) {
        const float u1c = pub[20 + c] * rs;
        const float u2c = pmb[20 + c];
        areg[16 + c] -= u1r * (t11 * u1c + t12 * u2c) + u2r * (t12 * u1c + t22 * u2c);
      }
    }
    if (hn) {
      const float* xb = sQ + 40 * mq;
      float s = 0;
#pragma unroll
      for (int c = 0; c < 16; c++) s += areg[c] * xb[c];
#pragma unroll
      for (int c = 0; c < 16; c++) s += areg[16 + c] * xb[20 + c];
      s += __shfl_xor(s, 1, 64); s += __shfl_xor(s, 2, 64);
      if (mq == 0) sW[SEG(mr)] = s;
    }
    __syncthreads();
  }

  // ---- epilogue ----
  {
    float4* aout = (float4*)(wsAinvP + (size_t)b * KK * KK + mr * KK + 32 * mq);
#pragma unroll
    for (int u = 0; u < 8; u++) {
      float4 o;
      o.x = areg[4 * u]; o.y = areg[4 * u + 1]; o.z = areg[4 * u + 2]; o.w = areg[4 * u + 3];
      aout[u] = o;
    }
  }
#pragma unroll
  for (int i = 0; i < 8; i++) {
    const int idx = tid + 512 * i;  // idx = k*32 + e (global layout unchanged)
    wsG[(size_t)b * 4096 + idx] = sGT[(idx & 31) * LTR + (idx >> 5)];
    wsEggT[(size_t)b * 4096 + idx] = sEggT[(idx >> 7) * LTR + (idx & 127)];
  }
#pragma unroll
  for (int i = 0; i < 2; i++) {
    const int idx = tid + 512 * i;
    wsD[(size_t)b * 1024 + idx] = sD[(idx >> 5) * L36 + (idx & 31)];
  }
  if (tid == 0) wsKL[b] = sScal[SC_KL];
}

// ---------------- Kernel 4a: postA — per-batch algebra, exports Wt[160][32] ----------------
__global__ __launch_bounds__(1024) void postA_kernel(
    const float* __restrict__ Pg, const float* __restrict__ Sgp,
    const float* __restrict__ wsAinvP, const float* __restrict__ wsG,
    const float* __restrict__ wsEggT, const float* __restrict__ wsD,
    float* __restrict__ wsKLr, float* __restrict__ wsWt) {
  __shared__ __align__(16) float SM[25856];  // 103.4 KB, lifetime-aliased
  float* sP    = SM;            // 4352  [128][34]
  float* sG    = SM + 4352;     // 4352
  float* sRhs  = SM + 8704;     // 4352
  float* sWr   = SM + 13056;    // 4352
  float* sEggT = SM + 17408;    // 4224  [32][132]
  float* sD    = SM + 21632;    // 1056  [32][33]
  float* sS    = SM + 22688;    // 1056
  float* sR1   = SM + 23744;    // 1056
  float* sGam  = SM + 24800;    // 1056
  float* sWt   = SM;            // 5440 floats: overlays dead sP + head of sG

  const int tid = threadIdx.x, b = blockIdx.x;
  const int r = tid >> 3, q = tid & 7;
#pragma unroll
  for (int i = 0; i < 4; i++) {
    const int idx = tid + 1024 * i;
    sP[(idx >> 5) * LPA + (idx & 31)] = Pg[(size_t)b * 4096 + idx];
    sG[(idx >> 5) * LPA + (idx & 31)] = wsG[(size_t)b * 4096 + idx];
    sEggT[(idx >> 7) * LTR + (idx & 127)] = wsEggT[(size_t)b * 4096 + idx];
  }
  sD[(tid >> 5) * L33 + (tid & 31)] = wsD[(size_t)b * 1024 + tid];
  {
    const float* Sb = Sgp + (size_t)b * 4096;
    sS[(tid >> 5) * L33 + (tid & 31)] =
        Sb[tid] + Sb[tid + 1024] + Sb[tid + 2048] + Sb[tid + 3072];
  }
  __syncthreads();
  // R1 = D S - Egg^T P
  {
    const int s = tid >> 5, e = tid & 31;
    float acc = 0;
#pragma unroll 4
    for (int f = 0; f < 32; f++) acc += sD[s * L33 + f] * sS[f * L33 + e];
#pragma unroll 4
    for (int rr = 0; rr < 128; rr++) acc -= sEggT[s * LTR + rr] * sP[rr * LPA + e];
    sR1[s * L33 + e] = acc;
  }
  __syncthreads();
  // rhs = P + G R1
  {
#pragma unroll
    for (int u = 0; u < 4; u++) {
      const int e = q + 8 * u;
      float acc = sP[r * LPA + e];
#pragma unroll 4
      for (int s = 0; s < 32; s++) acc += sG[r * LPA + s] * sR1[s * L33 + e];
      sRhs[r * LPA + e] = acc;
    }
  }
  __syncthreads();
  // w_read = Ainv_post rhs
  {
    float areg[16];
    const float4* a4 = (const float4*)(wsAinvP + (size_t)b * KK * KK + r * KK + 16 * q);
#pragma unroll
    for (int u = 0; u < 4; u++) {
      const float4 t4 = a4[u];
      areg[4 * u] = t4.x; areg[4 * u + 1] = t4.y; areg[4 * u + 2] = t4.z; areg[4 * u + 3] = t4.w;
    }
#pragma unroll 1
    for (int e = 0; e < 32; ++e) {
      float s = 0;
#pragma unroll
      for (int c = 0; c < 16; c++) s += areg[c] * sRhs[(16 * q + c) * LPA + e];
      s += __shfl_xor(s, 1, 64); s += __shfl_xor(s, 2, 64); s += __shfl_xor(s, 4, 64);
      if (q == 0) sWr[r * LPA + e] = s;
    }
  }
  __syncthreads();
  // Gam = G^T w
  {
    const int s = tid >> 5, e = tid & 31;
    float acc = 0;
#pragma unroll 4
    for (int rr = 0; rr < 128; rr++) acc += sG[rr * LPA + s] * sWr[rr * LPA + e];
    sGam[s * L33 + e] = acc;
  }
  __syncthreads();
  // Wc = w - Egg Gam -> sWt[0..127] ; Vc = D^T Gam -> sWt[128..159] ; KLr
  {
#pragma unroll
    for (int u = 0; u < 4; u++) {
      const int e = q + 8 * u;
      float acc = sWr[r * LPA + e];
#pragma unroll 4
      for (int s = 0; s < 32; s++) acc -= sEggT[s * LTR + r] * sGam[s * L33 + e];
      sWt[r * 34 + e] = acc;
    }
    const int s7 = tid >> 5, e7 = tid & 31;
    float acc2 = 0;
#pragma unroll 4
    for (int f = 0; f < 32; f++) acc2 += sD[f * L33 + s7] * sGam[f * L33 + e7];
    sWt[(128 + s7) * 34 + e7] = acc2;
    if (tid < 512) {
      const int e6 = tid >> 4, p6 = tid & 15;
      float s = 0;
#pragma unroll
      for (int u = 0; u < 8; u++) {
        const float w_ = sWr[(8 * p6 + u) * LPA + e6];
        s += w_ * w_;
      }
      s += __shfl_xor(s, 1, 64); s += __shfl_xor(s, 2, 64);
      s += __shfl_xor(s, 4, 64); s += __shfl_xor(s, 8, 64);
      if (p6 == 0) wsKLr[b * EE + e6] = s;
    }
  }
  __syncthreads();
  // export Wt (coalesced, row-major [160][32])
#pragma unroll
  for (int i = 0; i < 5; i++) {
    const int idx = tid + 1024 * i;
    wsWt[(size_t)b * 5120 + idx] = sWt[(idx >> 5) * 34 + (idx & 31)];
  }
}

// ---------------- Kernel 4b: postB — z_mean GEMM, 4 WGs per batch (c-quarters) ----------------
__global__ __launch_bounds__(512) void postB_kernel(
    const float* __restrict__ wsWt, const float* __restrict__ x,
    const float* __restrict__ M0, const float* __restrict__ znoise,
    float* __restrict__ out) {
  __shared__ __align__(16) float sWtT[32 * LWT];   // Wt^T : [e][row], stride 176
  __shared__ __align__(16) float Mch[2 * 16 * 132];
  const int tid = threadIdx.x;
  const int b = blockIdx.x >> 2, cq = blockIdx.x & 3;
  {
    const float* Wg = wsWt + (size_t)b * 5120;
#pragma unroll
    for (int i = 0; i < 10; i++) {
      const int idx = tid + 512 * i;  // row = idx>>5, e = idx&31
      sWtT[(idx & 31) * LWT + (idx >> 5)] = Wg[idx];
    }
  }
  const int srow = tid >> 5, sc4 = tid & 31;  // stage: 16 rows x 32 float4 (128 cols)
  const int e = tid & 31, cs = tid >> 5;      // compute: episode e, col-octet cs
  const float* xb = x + (size_t)b * EE * CC;
  const int cbase = cq * 128;
  float4 st = *(const float4*)(M0 + srow * CC + cbase + 4 * sc4);  // ch2=0 rows are all M0
  float acc[8];
#pragma unroll
  for (int u = 0; u < 8; u++) acc[u] = 0.0f;
  int buf = 0;
#pragma unroll 1
  for (int ch2 = 0; ch2 < 10; ++ch2) {
    *(float4*)(Mch + buf * 2112 + srow * 132 + 4 * sc4) = st;
    __syncthreads();
    if (ch2 + 1 < 10) {
      const int row = (ch2 + 1) * 16 + srow;
      st = (row < 128) ? *(const float4*)(M0 + row * CC + cbase + 4 * sc4)
                       : *(const float4*)(xb + (row - 128) * CC + cbase + 4 * sc4);
    }
    const float4* wt4 = (const float4*)(sWtT + e * LWT + ch2 * 16);
    const float4 wa = wt4[0], wb = wt4[1], wc = wt4[2], wd = wt4[3];
    const float wv16[16] = {wa.x, wa.y, wa.z, wa.w, wb.x, wb.y, wb.z, wb.w,
                            wc.x, wc.y, wc.z, wc.w, wd.x, wd.y, wd.z, wd.w};
#pragma unroll
    for (int kk = 0; kk < 16; ++kk) {
      const float* mrp = Mch + buf * 2112 + kk * 132 + cs * 8;
      const float4 m0 = *(const float4*)(mrp);
      const float4 m1 = *(const float4*)(mrp + 4);
      const float wk = wv16[kk];
      acc[0] += wk * m0.x; acc[1] += wk * m0.y; acc[2] += wk * m0.z; acc[3] += wk * m0.w;
      acc[4] += wk * m1.x; acc[5] += wk * m1.y; acc[6] += wk * m1.z; acc[7] += wk * m1.w;
    }
    buf ^= 1;
  }
  {
    const size_t ob = ((size_t)b * EE + e) * CC + cbase + cs * 8;
    const size_t nb = ((size_t)e * BB + b) * CC + cbase + cs * 8;
#pragma unroll
    for (int u = 0; u < 2; u++) {
      const float4 nz = *(const float4*)(znoise + nb + 4 * u);
      float4 o;
      o.x = acc[4 * u] + nz.x;     o.y = acc[4 * u + 1] + nz.y;
      o.z = acc[4 * u + 2] + nz.z; o.w = acc[4 * u + 3] + nz.w;
      *(float4*)(out + ob + 4 * u) = o;
    }
  }
}

// ---------------- Kernel 5: total divergence ----------------
__global__ __launch_bounds__(256) void final_kernel(const float* __restrict__ wsKL,
                                                    const float* __restrict__ wsKLr,
                                                    const float* __restrict__ lwsP,
                                                    float* __restrict__ out) {
  __shared__ float sPp[256];
  const int tid = threadIdx.x;
  float s = 0.0f;
  if (tid < 64) s += wsKL[tid];
  for (int i = tid; i < 2048; i += 256) s += wsKLr[i];
  sPp[tid] = s;
  __syncthreads();
  for (int off = 128; off > 0; off >>= 1) {
    if (tid < off) sPp[tid] += sPp[tid + off];
    __syncthreads();
  }
  if (tid == 0) {
    const float lws = lwsP[0];
    const float sw2 = expf(2.0f * lws);
    out[(size_t)BB * EE * CC] =
        0.5f * sPp[0] / (float)(EE * BB) + (float)KK * (sw2 - 1.0f - 2.0f * lws);
  }
}

extern "C" void kernel_launch(void* const* d_in, const int* in_sizes, int n_in,
                              void* d_out, int out_size, void* d_ws, size_t ws_size,
                              hipStream_t stream) {
  (void)in_sizes; (void)n_in; (void)out_size; (void)ws_size;
  const float* x = (const float*)d_in[0];        // [B,E,C]
  const float* M0 = (const float*)d_in[1];       // [K,C]
  const float* scaleP = (const float*)d_in[2];   // scalar
  const float* lwsP = (const float*)d_in[3];     // scalar
  const float* znoise = (const float*)d_in[4];   // [E,B,C]
  float* out = (float*)d_out;

  float* ws = (float*)d_ws;
  float* wsP = ws;                        // 262144
  float* wsSp = wsP + 262144;             // 262144 (64 x 4 partials x 1024)
  float* wsA0 = wsSp + 262144;            // 16384
  float* wsAinv0 = wsA0 + 16384;          // 16384
  float* wsAinvP = wsAinv0 + 16384;       // 1048576
  float* wsG = wsAinvP + 1048576;         // 262144
  float* wsEggT = wsG + 262144;           // 262144
  float* wsD = wsEggT + 262144;           // 65536
  float* wsKL = wsD + 65536;              // 64
  float* wsKLr = wsKL + 64;               // 2048
  float* wsWt = wsKLr + 2048;             // 327680 (64 x 160 x 32)

  a0_kernel<<<256, 256, 0, stream>>>(M0, wsA0);
  psinv_kernel<<<257, 1024, 0, stream>>>(x, M0, wsP, wsSp, wsA0, wsAinv0);
  scan_kernel<<<BB, 512, 0, stream>>>(wsP, wsSp, scaleP, wsAinv0,
                                      wsAinvP, wsG, wsEggT, wsD, wsKL);
  postA_kernel<<<BB, 1024, 0, stream>>>(wsP, wsSp, wsAinvP, wsG, wsEggT, wsD,
                                        wsKLr, wsWt);
  postB_kernel<<<256, 512, 0, stream>>>(wsWt, x, M0, znoise, out);
  final_kernel<<<1, 256, 0, stream>>>(wsKL, wsKLr, lwsP, out);
}

// Round 4
// 289.175 us; speedup vs baseline: 1.3150x; 1.2442x over previous
//
#include <hip/hip_runtime.h>

// (B,E,K,C) = (64,32,128,512), fp32.
#define BB 64
#define EE 32
#define KK 128
#define CC 512
#define V0EPS 1e-7f

#define LTR 132   // [32][132] padded stride
#define PTS 132   // scan: P^T / RhsT / WrT row stride (132 floats = 528B, 16B-aligned)
#define LKM 36    // scan: k-major row stride (G/Y/Egg)
#define L36 36    // scan: S/D row stride
#define LWT 176   // postB: Wt^T row stride
// segment-padded K-vector layout: element i lives at (i/16)*20 + (i%16)
#define SEG(i) ((((i) >> 4) * 20) + ((i) & 15))

// scan sScal slots (order matters: read as two float4s in PH5)
#define SC_S2  0
#define SC_SIG 1
#define SC_KL  2
#define SC_B1  3
#define SC_B2  4
#define SC_R11 5
#define SC_R12 6
#define SC_R22 7

__device__ __forceinline__ float wsum64(float v) {
#pragma unroll
  for (int m = 32; m >= 1; m >>= 1) v += __shfl_xor(v, m, 64);
  return v;
}

__device__ __forceinline__ float wsum32(float v) {  // reduce within aligned 32-lane half
#pragma unroll
  for (int m = 16; m >= 1; m >>= 1) v += __shfl_xor(v, m, 64);
  return v;
}

__device__ __forceinline__ float dot4(const float4 a, const float4 b) {
  return a.x * b.x + a.y * b.y + a.z * b.z + a.w * b.w;
}

// ---------------- Kernel 1: A0 = M0 M0^T + I (256 WGs: k x l-half) ----------------
__global__ __launch_bounds__(256) void a0_kernel(const float* __restrict__ M0,
                                                 float* __restrict__ wsA0) {
  __shared__ __align__(16) float sRow[CC];
  const int k = blockIdx.x >> 1, half = blockIdx.x & 1;
  for (int c = threadIdx.x; c < CC; c += 256) sRow[c] = M0[k * CC + c];
  __syncthreads();
  const int wv = threadIdx.x >> 6, ln = threadIdx.x & 63;
  const float4* zr = (const float4*)(sRow + 8 * ln);
  const float4 z0 = zr[0], z1 = zr[1];
  for (int li = 0; li < 16; ++li) {
    const int l = half * 64 + wv * 16 + li;
    const float4* rp = (const float4*)(M0 + l * CC + 8 * ln);
    const float4 a = rp[0], b = rp[1];
    float s = dot4(a, z0) + dot4(b, z1);
    s = wsum64(s);
    if (ln == 0) wsA0[k * KK + l] = s + (l == k ? 1.0f : 0.0f);
  }
}

// ------- Kernel 2: block 0 -> inv(A0) ; blocks 1..256 -> (b, k-quarter) of P, c-quarter of S -------
__global__ __launch_bounds__(1024) void psinv_kernel(const float* __restrict__ x,
                                                     const float* __restrict__ M0,
                                                     float* __restrict__ wsP,
                                                     float* __restrict__ wsSp,
                                                     const float* __restrict__ A0g,
                                                     float* __restrict__ Ainv0) {
  __shared__ __align__(16) float zAll[32][520];
  __shared__ __align__(16) float Mch[2][16][520];
  __shared__ float sFb[2][128];
  __shared__ __align__(16) float sPv[2][256];
  __shared__ float sScal[2];
  const int tid = threadIdx.x;

  if (blockIdx.x > 0) {
    // ================= ps body: P rows kq*32..kq*32+31 ; S partial over c-quarter =================
    const int b = (blockIdx.x - 1) >> 2, kq = (blockIdx.x - 1) & 3;
    {
      const float4* x4 = (const float4*)(x + (size_t)b * EE * CC);
#pragma unroll
      for (int i = 0; i < 4; i++) {
        const int F = tid + 1024 * i, e = F >> 7, c4 = F & 127;
        ((float4*)zAll[e])[c4] = x4[F];
      }
    }
    const float4* M4 = (const float4*)M0;
    const int srow = tid >> 7, sc4 = tid & 127;
    const int kbase = kq * 32;
    float4 st0 = M4[(kbase + srow) * 128 + sc4];
    float4 st1 = M4[(kbase + 8 + srow) * 128 + sc4];
    int buf = 0;
    const int p = tid & 7;           // 8 threads per dot
    const int ep = (tid >> 3) & 15;  // episodes 2*ep, 2*ep+1  (0..31)
    const int kp = tid >> 7;         // k rows kp, kp+8
#pragma unroll 1
    for (int kc = 0; kc < 2; ++kc) {
      ((float4*)Mch[buf][srow])[sc4] = st0;
      ((float4*)Mch[buf][8 + srow])[sc4] = st1;
      __syncthreads();
      if (kc == 0) {
        st0 = M4[(kbase + 16 + srow) * 128 + sc4];
        st1 = M4[(kbase + 24 + srow) * 128 + sc4];
      }
      float s00 = 0, s01 = 0, s10 = 0, s11 = 0;
      const float* m0 = Mch[buf][kp];
      const float* m1 = Mch[buf][kp + 8];
      const float* z0 = zAll[2 * ep];
      const float* z1 = zAll[2 * ep + 1];
#pragma unroll
      for (int u = 0; u < 16; u++) {
        const int c = 4 * p + 32 * u;
        const float4 a0 = *(const float4*)(m0 + c);
        const float4 a1 = *(const float4*)(m1 + c);
        const float4 b0 = *(const float4*)(z0 + c);
        const float4 b1 = *(const float4*)(z1 + c);
        s00 += dot4(a0, b0); s01 += dot4(a0, b1);
        s10 += dot4(a1, b0); s11 += dot4(a1, b1);
      }
#pragma unroll
      for (int m = 1; m <= 4; m <<= 1) {
        s00 += __shfl_xor(s00, m, 64); s01 += __shfl_xor(s01, m, 64);
        s10 += __shfl_xor(s10, m, 64); s11 += __shfl_xor(s11, m, 64);
      }
      if (p == 0) {
        float* Pb = wsP + (size_t)b * KK * EE;
        Pb[(kbase + kc * 16 + kp) * EE + 2 * ep] = s00;
        Pb[(kbase + kc * 16 + kp) * EE + 2 * ep + 1] = s01;
        Pb[(kbase + kc * 16 + kp + 8) * EE + 2 * ep] = s10;
        Pb[(kbase + kc * 16 + kp + 8) * EE + 2 * ep + 1] = s11;
      }
      buf ^= 1;
    }
    // S partial = Z[:, cq] Z[:, cq]^T
    {
      const int e = tid >> 5, f = tid & 31;
      const float4* ze = ((const float4*)zAll[e]) + 32 * kq;
      const float4* zf = ((const float4*)zAll[f]) + 32 * kq;
      float a0 = 0, a1 = 0, a2 = 0, a3 = 0;
#pragma unroll 4
      for (int u = 0; u < 32; u++) {
        const float4 A = ze[u], Bq = zf[u];
        a0 += A.x * Bq.x; a1 += A.y * Bq.y; a2 += A.z * Bq.z; a3 += A.w * Bq.w;
      }
      wsSp[((size_t)b * 4 + kq) * 1024 + e * EE + f] = (a0 + a1) + (a2 + a3);
    }
  } else {
    // ================= inv0 body (block 0): register GJ, conditional pivot loads =================
    const int r = tid >> 3, q = tid & 7;
    float wreg[16], vreg[16];
    {
      const float4* a4 = (const float4*)(A0g + r * KK + 16 * q);
#pragma unroll
      for (int u = 0; u < 4; u++) {
        const float4 t4 = a4[u];
        wreg[4 * u] = t4.x; wreg[4 * u + 1] = t4.y; wreg[4 * u + 2] = t4.z; wreg[4 * u + 3] = t4.w;
      }
#pragma unroll
      for (int c = 0; c < 16; c++) vreg[c] = (16 * q + c == r) ? 1.0f : 0.0f;
    }
    if (q == 0) sFb[0][r] = wreg[0];
    if (r == 0) {
#pragma unroll
      for (int c = 0; c < 16; c++) { sPv[0][16 * q + c] = wreg[c]; sPv[0][128 + 16 * q + c] = vreg[c]; }
    }
    if (tid == 0) sScal[0] = 1.0f / wreg[0];
    __syncthreads();
#pragma unroll 1
    for (int j = 0; j < KK; ++j) {
      const int sl = j & 1, sn = sl ^ 1;
      const float f = sFb[sl][r] * sScal[sl];
      if (r != j) {
        if (16 * q + 15 >= j) {
          const float4* w4 = (const float4*)(sPv[sl] + 16 * q);
#pragma unroll
          for (int u = 0; u < 4; u++) {
            const float4 aa = w4[u];
            wreg[4 * u] -= f * aa.x; wreg[4 * u + 1] -= f * aa.y;
            wreg[4 * u + 2] -= f * aa.z; wreg[4 * u + 3] -= f * aa.w;
          }
        }
        if (16 * q <= j) {
          const float4* v4 = (const float4*)(sPv[sl] + 128 + 16 * q);
#pragma unroll
          for (int u = 0; u < 4; u++) {
            const float4 bb = v4[u];
            vreg[4 * u] -= f * bb.x; vreg[4 * u + 1] -= f * bb.y;
            vreg[4 * u + 2] -= f * bb.z; vreg[4 * u + 3] -= f * bb.w;
          }
        }
      }
      if (j + 1 < KK) {
        const int jn = j + 1;
        float wval = 0.0f;
#pragma unroll
        for (int c = 0; c < 16; c++) if (c == (jn & 15)) wval = wreg[c];
        if (q == (jn >> 4)) sFb[sn][r] = wval;
        if (r == jn) {
#pragma unroll
          for (int c = 0; c < 16; c++) { sPv[sn][16 * q + c] = wreg[c]; sPv[sn][128 + 16 * q + c] = vreg[c]; }
        }
        if (r == jn && q == (jn >> 4)) sScal[sn] = 1.0f / wval;
      }
      __syncthreads();
    }
    {
      float dval = 0.0f;
#pragma unroll
      for (int c = 0; c < 16; c++) if (c == (r & 15)) dval = wreg[c];
      if (q == (r >> 4)) sFb[0][r] = dval;
    }
    __syncthreads();
    {
      const float sc = 1.0f / sFb[0][r];
      float4* o4 = (float4*)(Ainv0 + r * KK + 16 * q);
#pragma unroll
      for (int u = 0; u < 4; u++) {
        float4 o;
        o.x = vreg[4 * u] * sc; o.y = vreg[4 * u + 1] * sc;
        o.z = vreg[4 * u + 2] * sc; o.w = vreg[4 * u + 3] * sc;
        o4[u] = o;
      }
    }
  }
}

// ---------------- Kernel 3: scan + fused postA, 512 threads, one WG per batch ----------------
// postA fused in: AinvP stays in areg, P/G/Egg/D/S stay in LDS in b128-friendly layouts.
// Outputs only: wsKL, wsKLr, wsWt (Wt transposed [b][e][160]).
__global__ __launch_bounds__(512) void scan_kernel(
    const float* __restrict__ Pg, const float* __restrict__ Sg,  // Sg = 4 partials per batch
    const float* __restrict__ scaleP, const float* __restrict__ Ainv0,
    float* __restrict__ wsKL, float* __restrict__ wsKLr, float* __restrict__ wsWt) {
  __shared__ __align__(16) float sPT[EE * PTS];    // P^T : [e][k]
  __shared__ __align__(16) float sGT[EE * LTR];    // G^T : [t][k]
  __shared__ __align__(16) float sEggT[EE * LTR];  // Egg^T : [t][k]
  __shared__ __align__(16) float uni2[EE * LTR];   // scan: Y^T [t][k] | postA: R1T(0..1151) + GamT(1152..2303)
  __shared__ __align__(16) float uni3[KK * LKM];   // scan: G [k][t]  | postA: WrT [e][k] (stride 132, 4224<=4608)
  __shared__ __align__(16) float uni1[KK * LKM];   // scan: Y [k][j]  | postA: RhsT [e][k] (stride 132)
  __shared__ __align__(16) float sEk[KK * LKM];    // Egg: [k][s]
  __shared__ __align__(16) float sS[EE * L36];     // S (symmetric)
  __shared__ __align__(16) float sD[EE * L36];     // D : [s][r2]
  __shared__ __align__(16) float sW[160];
  __shared__ __align__(16) float sWU[160];
  __shared__ __align__(16) float sPu[160];
  __shared__ __align__(16) float sPm[160];
  __shared__ __align__(16) float sQ[160];
  __shared__ __align__(16) float sDz[EE];
  __shared__ __align__(16) float sDgw[EE];
  __shared__ __align__(16) float sQt[EE];
  __shared__ __align__(16) float sScal[16];

  float* sYT = uni2;
  float* sGk = uni3;
  float* sYk = uni1;

  const int tid = threadIdx.x, wv = tid >> 6, ln = tid & 63;
  const int mr = tid >> 2, mq = tid & 3;  // matvec: row mr, col-quarter mq
  const int b = blockIdx.x;

  float areg[32];
  {
    const float4* a4 = (const float4*)(Ainv0 + mr * KK + 32 * mq);
#pragma unroll
    for (int u = 0; u < 8; u++) {
      const float4 t4 = a4[u];
      areg[4 * u] = t4.x; areg[4 * u + 1] = t4.y; areg[4 * u + 2] = t4.z; areg[4 * u + 3] = t4.w;
    }
  }
  {
    const float* Pb = Pg + (size_t)b * KK * EE;
#pragma unroll
    for (int i = 0; i < 8; i++) {
      const int idx = tid + 512 * i;                  // idx = k*32 + e
      sPT[(idx & 31) * PTS + (idx >> 5)] = Pb[idx];   // transpose into [e][k]
    }
    const float* Sb = Sg + (size_t)b * 4096;
#pragma unroll
    for (int i = 0; i < 2; i++) {
      const int idx = tid + 512 * i;
      sS[(idx >> 5) * L36 + (idx & 31)] =
          Sb[idx] + Sb[idx + 1024] + Sb[idx + 2048] + Sb[idx + 3072];
    }
  }
  if (tid < 16) sScal[tid] = 0.0f;
  const float v0 = scaleP[0] + V0EPS;
  __syncthreads();
  {  // w0 = Ainv0 * P[:,0]
    const float* xb = sPT + 32 * mq;
    float s = 0;
#pragma unroll
    for (int c = 0; c < 32; c++) s += areg[c] * xb[c];
    s += __shfl_xor(s, 1, 64); s += __shfl_xor(s, 2, 64);
    if (mq == 0) sW[SEG(mr)] = s;
  }
  __syncthreads();

#pragma unroll 1
  for (int t = 0; t < EE; ++t) {
    const bool hn = (t + 1 < EE);
    // ---- PH1: Pm = Ainv w ; dgw = G^T w ; qt = Y^T w ; S2 ----
    {
      const float* xb = sW + 40 * mq;
      float s = 0;
#pragma unroll
      for (int c = 0; c < 16; c++) s += areg[c] * xb[c];
#pragma unroll
      for (int c = 0; c < 16; c++) s += areg[16 + c] * xb[20 + c];
      s += __shfl_xor(s, 1, 64); s += __shfl_xor(s, 2, 64);
      if (mq == 0) sPm[SEG(mr)] = s;
    }
    if (tid < 256) {
      const int s8 = tid >> 3, p3 = tid & 7;
      if (s8 < t) {
        const float* gr = sGT + s8 * LTR + 16 * p3;
        const float* wr_ = sW + 20 * p3;
        float s = 0;
#pragma unroll
        for (int kk = 0; kk < 16; kk++) s += gr[kk] * wr_[kk];
        s += __shfl_xor(s, 1, 64); s += __shfl_xor(s, 2, 64); s += __shfl_xor(s, 4, 64);
        if (p3 == 0) sDgw[s8] = s;
      } else if (s8 == 31) {  // s8==31 never used by dgw: S2 here
        const float* wp = sW + 20 * p3;
        float s = 0;
#pragma unroll
        for (int kk = 0; kk < 16; kk++) s += wp[kk] * wp[kk];
        s += __shfl_xor(s, 1, 64); s += __shfl_xor(s, 2, 64); s += __shfl_xor(s, 4, 64);
        if (p3 == 0) sScal[SC_S2] = s;
      }
    } else {
      const int j = (tid - 256) >> 3, p3 = tid & 7;
      if (j < t) {
        const float* yr = sYT + j * LTR + 16 * p3;
        const float* wr_ = sW + 20 * p3;
        float s = 0;
#pragma unroll
        for (int kk = 0; kk < 16; kk++) s += yr[kk] * wr_[kk];
        s += __shfl_xor(s, 1, 64); s += __shfl_xor(s, 2, 64); s += __shfl_xor(s, 4, 64);
        if (p3 == 0) sQt[j] = s;
      }
    }
    __syncthreads();
    // ---- PH2: wU ; D_t ; Egg_t ; sigma ; KL ; R22 ----
    if (tid < 256) {  // wU[k] = v0 w[k] - sum_{j<t} Y[k][j] qt[j]
      const int k = tid >> 1, h = tid & 1;
      const float* yk = sYk + k * LKM + 16 * h;
      const float* qb = sQt + 16 * h;
      float a = 0;
#pragma unroll
      for (int u = 0; u < 16; u++) {
        const int j = 16 * h + u;
        a += (j < t) ? yk[u] * qb[u] : 0.0f;
      }
      a += __shfl_xor(a, 1, 64);
      if (h == 0) sWU[SEG(k)] = v0 * sW[SEG(k)] - a;
    } else if (tid < 384) {  // Egg append (k-major recurrence)
      const int k = tid - 256;
      float a = sW[SEG(k)];
      const float* ek = sEk + k * LKM;
      const int nc = (t + 3) >> 2;
#pragma unroll 1
      for (int c4 = 0; c4 < nc; ++c4) {
        const float4 ev = *(const float4*)(ek + 4 * c4);
        const float4 dv = *(const float4*)(sDgw + 4 * c4);
        const int u0 = 4 * c4;
        a -= ((u0 + 0 < t) ? ev.x * dv.x : 0.0f) + ((u0 + 1 < t) ? ev.y * dv.y : 0.0f) +
             ((u0 + 2 < t) ? ev.z * dv.z : 0.0f) + ((u0 + 3 < t) ? ev.w * dv.w : 0.0f);
      }
      sEk[k * LKM + t] = a;
      sEggT[t * LTR + k] = a;
    } else if (tid < 448) {  // wave 6: lanes<32: D append ; lanes>=32: R22 = w.Pm
      if (ln < 32) {
        const int r2 = ln;
        float a = (r2 == t) ? 1.0f : 0.0f;
        for (int s2 = 0; s2 < t; ++s2) a -= sDgw[s2] * sD[s2 * L36 + r2];
        sD[t * L36 + r2] = a;
      } else {
        const int k0 = (ln - 32) * 4;
        const float4 wv4 = *(const float4*)(sW + SEG(k0));
        const float4 pm4 = *(const float4*)(sPm + SEG(k0));
        float a = dot4(wv4, pm4);
        a = wsum32(a);
        if (ln == 32) sScal[SC_R22] = a;
      }
    } else {  // wave 7: sigma ; KL
      const float s2v = sScal[SC_S2];
      float a = (ln < t) ? sQt[ln] * sQt[ln] : 0.0f;
      a = wsum64(a);
      if (ln == 0) {
        sScal[SC_SIG] = v0 * s2v - a + 1.0f;
        sScal[SC_KL] += s2v;
      }
    }
    __syncthreads();
    // ---- PH3: Pu = Ainv wU ; dz ; B1 ; B2 ; R12 ; G/Y appends ----
    {
      const float* xb = sWU + 40 * mq;
      float s = 0;
#pragma unroll
      for (int c = 0; c < 16; c++) s += areg[c] * xb[c];
#pragma unroll
      for (int c = 0; c < 16; c++) s += areg[16 + c] * xb[20 + c];
      s += __shfl_xor(s, 1, 64); s += __shfl_xor(s, 2, 64);
      if (mq == 0) sPu[SEG(mr)] = s;
    }
    if (tid < 256) {  // dz[s4] = D[s4,:].S[:,t+1] - Egg^T[s4,:].P[:,t+1]
      const int s4 = tid >> 3, p3 = tid & 7;
      if (hn && s4 <= t) {
        const float* er = sEggT + s4 * LTR + 16 * p3;
        const float* pr = sPT + (t + 1) * PTS + 16 * p3;
        float a = 0;
#pragma unroll
        for (int kk = 0; kk < 16; kk++) a -= er[kk] * pr[kk];
        const float4 dv = *(const float4*)(sD + s4 * L36 + 4 * p3);
        const float4 sv = *(const float4*)(sS + (t + 1) * L36 + 4 * p3);  // S symmetric
        a += dot4(dv, sv);
        a += __shfl_xor(a, 1, 64); a += __shfl_xor(a, 2, 64); a += __shfl_xor(a, 4, 64);
        if (p3 == 0) sDz[s4] = a;
      }
    } else if (tid < 320) {  // wave 4: B2 = Egg_t . P[:,t]
      float a = sEggT[t * LTR + ln] * sPT[t * PTS + ln] +
                sEggT[t * LTR + ln + 64] * sPT[t * PTS + ln + 64];
      a = wsum64(a);
      if (ln == 0) sScal[SC_B2] = a;
    } else if (tid < 384) {  // wave 5: lanes<32: B1 ; lanes>=32: R12 = wU.Pm
      if (ln < 32) {
        float a = sD[t * L36 + ln] * sS[t * L36 + ln];
        a = wsum32(a);
        if (ln == 0) sScal[SC_B1] = a;
      } else {
        const int k0 = (ln - 32) * 4;
        const float4 wu4 = *(const float4*)(sWU + SEG(k0));
        const float4 pm4 = *(const float4*)(sPm + SEG(k0));
        float a = dot4(wu4, pm4);
        a = wsum32(a);
        if (ln == 32) sScal[SC_R12] = a;
      }
    } else if (tid < 448) {  // wave 6: G/Y appends (both layouts)
      const float sig = sScal[SC_SIG];
      const float rsq = rsqrtf(sig);
#pragma unroll
      for (int u = 0; u < 2; u++) {
        const int k = ln + 64 * u;
        const float wu = sWU[SEG(k)];
        const float gv = wu / sig;
        const float yv = wu * rsq;
        sGT[t * LTR + k] = gv;
        sGk[k * LKM + t] = gv;
        sYT[t * LTR + k] = yv;
        sYk[k * LKM + t] = yv;
      }
    }
    __syncthreads();
    // ---- PH4: q_next ; R11 ----
    if (hn) {
      const float* gk = sGk + mr * LKM + 8 * mq;
      const float* dzb = sDz + 8 * mq;
      float a = 0;
#pragma unroll
      for (int u = 0; u < 8; u++) {
        const int s2 = 8 * mq + u;
        a += (s2 < t) ? gk[u] * dzb[u] : 0.0f;
      }
      a += __shfl_xor(a, 1, 64); a += __shfl_xor(a, 2, 64);
      if (mq == 0)
        sQ[SEG(mr)] = sPT[(t + 1) * PTS + mr] + a + (sWU[SEG(mr)] / sScal[SC_SIG]) * sDz[t];
    }
    if (wv == 0) {  // R11 = wU . Pu
      float a = sWU[SEG(ln)] * sPu[SEG(ln)] + sWU[SEG(ln + 64)] * sPu[SEG(ln + 64)];
      a = wsum64(a);
      if (ln == 0) sScal[SC_R11] = a;
    }
    __syncthreads();
    // ---- PH5: Ainv rank-2 update (per-thread scalar finalize) ; w_next ----
    {
      const float4 sc0 = *(const float4*)(sScal);      // S2, SIG, KL, B1
      const float4 sc1 = *(const float4*)(sScal + 4);  // B2, R11, R12, R22
      const float rs = 1.0f / sc0.y;
      const float beta = sc0.w - sc1.x - sc0.x;
      const float e11 = sc1.y * rs * rs;
      const float e12 = sc1.z * rs + 1.0f;
      const float e22 = sc1.w - beta;
      const float rd = 1.0f / (e11 * e22 - e12 * e12);
      const float t11 = e22 * rd, t12 = -e12 * rd, t22 = e11 * rd;
      const float u1r = sPu[SEG(mr)] * rs, u2r = sPm[SEG(mr)];
      const float* pub = sPu + 40 * mq;
      const float* pmb = sPm + 40 * mq;
#pragma unroll
      for (int c = 0; c < 16; c++) {
        const float u1c = pub[c] * rs;
        const float u2c = pmb[c];
        areg[c] -= u1r * (t11 * u1c + t12 * u2c) + u2r * (t12 * u1c + t22 * u2c);
      }
#pragma unroll
      for (int c = 0; c < 16; c++) {
        const float u1c = pub[20 + c] * rs;
        const float u2c = pmb[20 + c];
        areg[16 + c] -= u1r * (t11 * u1c + t12 * u2c) + u2r * (t12 * u1c + t22 * u2c);
      }
    }
    if (hn) {
      const float* xb = sQ + 40 * mq;
      float s = 0;
#pragma unroll
      for (int c = 0; c < 16; c++) s += areg[c] * xb[c];
#pragma unroll
      for (int c = 0; c < 16; c++) s += areg[16 + c] * xb[20 + c];
      s += __shfl_xor(s, 1, 64); s += __shfl_xor(s, 2, 64);
      if (mq == 0) sW[SEG(mr)] = s;
    }
    __syncthreads();
  }

  // ================= fused postA =================
  // Aliases over LDS regions dead after the scan loop:
  float* sR1T  = uni2;         // [32][36]  (over dead sYT)
  float* sGamT = uni2 + 1152;  // [32][36]
  float* sRhsT = uni1;         // [32][132] (over dead sYk)
  float* sWrT  = uni3;         // [32][132] (over sGk -- dead after PA1)
  if (tid == 0) wsKL[b] = sScal[SC_KL];

  // ---- PA0: R1T[e][s] = D[s,:].S[e,:] - EggT[s,:].PT[e,:] ----
#pragma unroll
  for (int h = 0; h < 2; ++h) {
    const int lin = tid + 512 * h, s = lin >> 5, e = lin & 31;
    const float4* er = (const float4*)(sEggT + s * LTR);
    const float4* pr = (const float4*)(sPT + e * PTS);
    float a = 0;
#pragma unroll 8
    for (int u = 0; u < 32; ++u) a -= dot4(er[u], pr[u]);
    const float4* dr = (const float4*)(sD + s * L36);
    const float4* sr = (const float4*)(sS + e * L36);
#pragma unroll
    for (int u = 0; u < 8; ++u) a += dot4(dr[u], sr[u]);
    sR1T[e * 36 + s] = a;
  }
  __syncthreads();
  // ---- PA1: RhsT[e][k] = PT[e][k] + sum_s G[k][s] R1T[e][s] ----
  {
    const int k = tid & 127, e4 = tid >> 7;
    float4 g0, g1, g2, g3, g4, g5, g6, g7;
    {
      const float4* gk = (const float4*)(sGk + k * LKM);
      g0 = gk[0]; g1 = gk[1]; g2 = gk[2]; g3 = gk[3];
      g4 = gk[4]; g5 = gk[5]; g6 = gk[6]; g7 = gk[7];
    }
#pragma unroll
    for (int u = 0; u < 8; ++u) {
      const int e = e4 * 8 + u;
      const float4* r1 = (const float4*)(sR1T + e * 36);
      float a = sPT[e * PTS + k];
      a += dot4(g0, r1[0]) + dot4(g1, r1[1]) + dot4(g2, r1[2]) + dot4(g3, r1[3]);
      a += dot4(g4, r1[4]) + dot4(g5, r1[5]) + dot4(g6, r1[6]) + dot4(g7, r1[7]);
      sRhsT[e * PTS + k] = a;
    }
  }
  __syncthreads();
  // ---- PA2: WrT[e][k] = AinvP . rhs[:,e]  (areg matvec, 32 episodes) ----
#pragma unroll 2
  for (int e = 0; e < EE; ++e) {
    const float* xb = sRhsT + e * PTS + 32 * mq;
    float s = 0;
#pragma unroll
    for (int c = 0; c < 32; c++) s += areg[c] * xb[c];
    s += __shfl_xor(s, 1, 64); s += __shfl_xor(s, 2, 64);
    if (mq == 0) sWrT[e * PTS + mr] = s;
  }
  __syncthreads();
  // ---- PA3: GamT[e][s] = sum_k G[k][s] Wr[k][e] = GT[s,:].WrT[e,:] ----
#pragma unroll
  for (int h = 0; h < 2; ++h) {
    const int lin = tid + 512 * h, s = lin >> 5, e = lin & 31;
    const float4* gr = (const float4*)(sGT + s * LTR);
    const float4* wr = (const float4*)(sWrT + e * PTS);
    float a = 0;
#pragma unroll 8
    for (int u = 0; u < 32; ++u) a += dot4(gr[u], wr[u]);
    sGamT[e * 36 + s] = a;
  }
  __syncthreads();
  // ---- PA4: Wc -> wsWt rows 0..127 ; Vc -> rows 128..159 ; KLr ----
  {
    const int k = tid & 127, e4 = tid >> 7;
    float4 E0, E1, E2, E3, E4, E5, E6, E7;
    {
      const float4* ek = (const float4*)(sEk + k * LKM);
      E0 = ek[0]; E1 = ek[1]; E2 = ek[2]; E3 = ek[3];
      E4 = ek[4]; E5 = ek[5]; E6 = ek[6]; E7 = ek[7];
    }
#pragma unroll
    for (int u = 0; u < 8; ++u) {
      const int e = e4 * 8 + u;
      const float4* gm = (const float4*)(sGamT + e * 36);
      float a = sWrT[e * PTS + k];
      a -= dot4(E0, gm[0]) + dot4(E1, gm[1]) + dot4(E2, gm[2]) + dot4(E3, gm[3]);
      a -= dot4(E4, gm[4]) + dot4(E5, gm[5]) + dot4(E6, gm[6]) + dot4(E7, gm[7]);
      wsWt[(size_t)b * 5120 + e * 160 + k] = a;
    }
  }
  {  // Vc[e][sp] = sum_f D[f][sp] * GamT[e][f]
    const int e = tid & 31, sp = tid >> 5;  // sp in 0..15, handle sp and sp+16
    float4 gm[8];
    {
      const float4* g4 = (const float4*)(sGamT + e * 36);
#pragma unroll
      for (int u = 0; u < 8; ++u) gm[u] = g4[u];
    }
#pragma unroll
    for (int h = 0; h < 2; ++h) {
      const int sp2 = sp + 16 * h;
      float a = 0;
#pragma unroll
      for (int u = 0; u < 8; ++u) {
        const float4 g = gm[u];
        a += sD[(4 * u + 0) * L36 + sp2] * g.x + sD[(4 * u + 1) * L36 + sp2] * g.y +
             sD[(4 * u + 2) * L36 + sp2] * g.z + sD[(4 * u + 3) * L36 + sp2] * g.w;
      }
      wsWt[(size_t)b * 5120 + e * 160 + 128 + sp2] = a;
    }
  }
  {  // KLr[e] = sum_k Wr[k][e]^2
    const int e = tid >> 4, p = tid & 15;
    const float4* wr = (const float4*)(sWrT + e * PTS + 8 * p);
    const float4 w0 = wr[0], w1 = wr[1];
    float a = dot4(w0, w0) + dot4(w1, w1);
    a += __shfl_xor(a, 1, 64); a += __shfl_xor(a, 2, 64);
    a += __shfl_xor(a, 4, 64); a += __shfl_xor(a, 8, 64);
    if (p == 0) wsKLr[b * EE + e] = a;
  }
}

// ---------------- Kernel 4: postB (256 WGs) + final (block 256) ----------------
__global__ __launch_bounds__(512) void postBF_kernel(
    const float* __restrict__ wsWt, const float* __restrict__ x,
    const float* __restrict__ M0, const float* __restrict__ znoise,
    const float* __restrict__ wsKL, const float* __restrict__ wsKLr,
    const float* __restrict__ lwsP, float* __restrict__ out) {
  __shared__ __align__(16) float sWtT[32 * LWT];   // Wt^T : [e][row], stride 176
  __shared__ __align__(16) float Mch[2 * 16 * 132];
  const int tid = threadIdx.x;

  if (blockIdx.x == 256) {
    // ======== final: total divergence ========
    float* sPp = sWtT;  // reuse
    float s = 0.0f;
    if (tid < 64) s += wsKL[tid];
    for (int i = tid; i < 2048; i += 512) s += wsKLr[i];
    sPp[tid] = s;
    __syncthreads();
    for (int off = 256; off > 0; off >>= 1) {
      if (tid < off) sPp[tid] += sPp[tid + off];
      __syncthreads();
    }
    if (tid == 0) {
      const float lws = lwsP[0];
      const float sw2 = expf(2.0f * lws);
      out[(size_t)BB * EE * CC] =
          0.5f * sPp[0] / (float)(EE * BB) + (float)KK * (sw2 - 1.0f - 2.0f * lws);
    }
    return;
  }

  const int b = blockIdx.x >> 2, cq = blockIdx.x & 3;
  {
    // wsWt is [b][e][160]: direct (no transpose) load
    const int e = tid >> 4, j = tid & 15;
    const float* Wg = wsWt + (size_t)b * 5120 + e * 160;
#pragma unroll
    for (int u = 0; u < 10; ++u) sWtT[e * LWT + j + 16 * u] = Wg[j + 16 * u];
  }
  const int srow = tid >> 5, sc4 = tid & 31;  // stage: 16 rows x 32 float4 (128 cols)
  const int e = tid & 31, cs = tid >> 5;      // compute: episode e, col-octet cs
  const float* xb = x + (size_t)b * EE * CC;
  const int cbase = cq * 128;
  float4 st = *(const float4*)(M0 + srow * CC + cbase + 4 * sc4);  // ch2=0 rows are all M0
  float acc[8];
#pragma unroll
  for (int u = 0; u < 8; u++) acc[u] = 0.0f;
  int buf = 0;
#pragma unroll 1
  for (int ch2 = 0; ch2 < 10; ++ch2) {
    *(float4*)(Mch + buf * 2112 + srow * 132 + 4 * sc4) = st;
    __syncthreads();
    if (ch2 + 1 < 10) {
      const int row = (ch2 + 1) * 16 + srow;
      st = (row < 128) ? *(const float4*)(M0 + row * CC + cbase + 4 * sc4)
                       : *(const float4*)(xb + (row - 128) * CC + cbase + 4 * sc4);
    }
    const float4* wt4 = (const float4*)(sWtT + e * LWT + ch2 * 16);
    const float4 wa = wt4[0], wb = wt4[1], wc = wt4[2], wd = wt4[3];
    const float wv16[16] = {wa.x, wa.y, wa.z, wa.w, wb.x, wb.y, wb.z, wb.w,
                            wc.x, wc.y, wc.z, wc.w, wd.x, wd.y, wd.z, wd.w};
#pragma unroll
    for (int kk = 0; kk < 16; ++kk) {
      const float* mrp = Mch + buf * 2112 + kk * 132 + cs * 8;
      const float4 m0 = *(const float4*)(mrp);
      const float4 m1 = *(const float4*)(mrp + 4);
      const float wk = wv16[kk];
      acc[0] += wk * m0.x; acc[1] += wk * m0.y; acc[2] += wk * m0.z; acc[3] += wk * m0.w;
      acc[4] += wk * m1.x; acc[5] += wk * m1.y; acc[6] += wk * m1.z; acc[7] += wk * m1.w;
    }
    buf ^= 1;
  }
  {
    const size_t ob = ((size_t)b * EE + e) * CC + cbase + cs * 8;
    const size_t nb = ((size_t)e * BB + b) * CC + cbase + cs * 8;
#pragma unroll
    for (int u = 0; u < 2; u++) {
      const float4 nz = *(const float4*)(znoise + nb + 4 * u);
      float4 o;
      o.x = acc[4 * u] + nz.x;     o.y = acc[4 * u + 1] + nz.y;
      o.z = acc[4 * u + 2] + nz.z; o.w = acc[4 * u + 3] + nz.w;
      *(float4*)(out + ob + 4 * u) = o;
    }
  }
}

extern "C" void kernel_launch(void* const* d_in, const int* in_sizes, int n_in,
                              void* d_out, int out_size, void* d_ws, size_t ws_size,
                              hipStream_t stream) {
  (void)in_sizes; (void)n_in; (void)out_size; (void)ws_size;
  const float* x = (const float*)d_in[0];        // [B,E,C]
  const float* M0 = (const float*)d_in[1];       // [K,C]
  const float* scaleP = (const float*)d_in[2];   // scalar
  const float* lwsP = (const float*)d_in[3];     // scalar
  const float* znoise = (const float*)d_in[4];   // [E,B,C]
  float* out = (float*)d_out;

  float* ws = (float*)d_ws;
  float* wsP = ws;                        // 262144
  float* wsSp = wsP + 262144;             // 262144 (64 x 4 partials x 1024)
  float* wsA0 = wsSp + 262144;            // 16384
  float* wsAinv0 = wsA0 + 16384;          // 16384
  float* wsKL = wsAinv0 + 16384;          // 64
  float* wsKLr = wsKL + 64;               // 2048
  float* wsWt = wsKLr + 2048;             // 327680 (64 x 32 x 160, [b][e][row])

  a0_kernel<<<256, 256, 0, stream>>>(M0, wsA0);
  psinv_kernel<<<257, 1024, 0, stream>>>(x, M0, wsP, wsSp, wsA0, wsAinv0);
  scan_kernel<<<BB, 512, 0, stream>>>(wsP, wsSp, scaleP, wsAinv0,
                                      wsKL, wsKLr, wsWt);
  postBF_kernel<<<257, 512, 0, stream>>>(wsWt, x, M0, znoise, wsKL, wsKLr, lwsP, out);
  final_kernel_dummy:;
}

// Round 5
// 287.890 us; speedup vs baseline: 1.3209x; 1.0045x over previous
//
#include <hip/hip_runtime.h>

// (B,E,K,C) = (64,32,128,512), fp32.
#define BB 64
#define EE 32
#define KK 128
#define CC 512
#define V0EPS 1e-7f

#define LTR 132   // [32][132] padded stride
#define PTS 132   // scan: P^T / RhsT / WrT row stride
#define LKM 36    // scan: k-major row stride (G/Y/Egg)
#define L36 36    // scan: S/D row stride
#define LWT 176   // postB: Wt^T row stride
// segment-padded K-vector layout: element i lives at (i/16)*20 + (i%16)
#define SEG(i) ((((i) >> 4) * 20) + ((i) & 15))

// scan sScal slots (order matters: read as two float4s in PH5)
#define SC_S2  0
#define SC_SIG 1
#define SC_KL  2
#define SC_B1  3
#define SC_B2  4
#define SC_R11 5
#define SC_R12 6
#define SC_R22 7

__device__ __forceinline__ float wsum64(float v) {
#pragma unroll
  for (int m = 32; m >= 1; m >>= 1) v += __shfl_xor(v, m, 64);
  return v;
}

__device__ __forceinline__ float wsum32(float v) {  // reduce within aligned 32-lane half
#pragma unroll
  for (int m = 16; m >= 1; m >>= 1) v += __shfl_xor(v, m, 64);
  return v;
}

__device__ __forceinline__ float dot4(const float4 a, const float4 b) {
  return a.x * b.x + a.y * b.y + a.z * b.z + a.w * b.w;
}

// ---------------- Kernel 1: A0 = M0 M0^T + I (256 WGs: k x l-half) ----------------
__global__ __launch_bounds__(256) void a0_kernel(const float* __restrict__ M0,
                                                 float* __restrict__ wsA0) {
  __shared__ __align__(16) float sRow[CC];
  const int k = blockIdx.x >> 1, half = blockIdx.x & 1;
  for (int c = threadIdx.x; c < CC; c += 256) sRow[c] = M0[k * CC + c];
  __syncthreads();
  const int wv = threadIdx.x >> 6, ln = threadIdx.x & 63;
  const float4* zr = (const float4*)(sRow + 8 * ln);
  const float4 z0 = zr[0], z1 = zr[1];
  for (int li = 0; li < 16; ++li) {
    const int l = half * 64 + wv * 16 + li;
    const float4* rp = (const float4*)(M0 + l * CC + 8 * ln);
    const float4 a = rp[0], b = rp[1];
    float s = dot4(a, z0) + dot4(b, z1);
    s = wsum64(s);
    if (ln == 0) wsA0[k * KK + l] = s + (l == k ? 1.0f : 0.0f);
  }
}

// ------- Kernel 2: block 0 -> inv(A0) ; blocks 1..256 -> (b, k-quarter) of P, c-quarter of S -------
__global__ __launch_bounds__(1024) void psinv_kernel(const float* __restrict__ x,
                                                     const float* __restrict__ M0,
                                                     float* __restrict__ wsP,
                                                     float* __restrict__ wsSp,
                                                     const float* __restrict__ A0g,
                                                     float* __restrict__ Ainv0) {
  __shared__ __align__(16) float zAll[32][520];
  __shared__ __align__(16) float Mch[2][16][520];
  __shared__ float sFb[2][128];
  __shared__ __align__(16) float sPv[2][256];
  __shared__ float sScal[2];
  const int tid = threadIdx.x;

  if (blockIdx.x > 0) {
    // ================= ps body: P rows kq*32..kq*32+31 ; S partial over c-quarter =================
    const int b = (blockIdx.x - 1) >> 2, kq = (blockIdx.x - 1) & 3;
    {
      const float4* x4 = (const float4*)(x + (size_t)b * EE * CC);
#pragma unroll
      for (int i = 0; i < 4; i++) {
        const int F = tid + 1024 * i, e = F >> 7, c4 = F & 127;
        ((float4*)zAll[e])[c4] = x4[F];
      }
    }
    const float4* M4 = (const float4*)M0;
    const int srow = tid >> 7, sc4 = tid & 127;
    const int kbase = kq * 32;
    float4 st0 = M4[(kbase + srow) * 128 + sc4];
    float4 st1 = M4[(kbase + 8 + srow) * 128 + sc4];
    int buf = 0;
    const int p = tid & 7;           // 8 threads per dot
    const int ep = (tid >> 3) & 15;  // episodes 2*ep, 2*ep+1  (0..31)
    const int kp = tid >> 7;         // k rows kp, kp+8
#pragma unroll 1
    for (int kc = 0; kc < 2; ++kc) {
      ((float4*)Mch[buf][srow])[sc4] = st0;
      ((float4*)Mch[buf][8 + srow])[sc4] = st1;
      __syncthreads();
      if (kc == 0) {
        st0 = M4[(kbase + 16 + srow) * 128 + sc4];
        st1 = M4[(kbase + 24 + srow) * 128 + sc4];
      }
      float s00 = 0, s01 = 0, s10 = 0, s11 = 0;
      const float* m0 = Mch[buf][kp];
      const float* m1 = Mch[buf][kp + 8];
      const float* z0 = zAll[2 * ep];
      const float* z1 = zAll[2 * ep + 1];
#pragma unroll
      for (int u = 0; u < 16; u++) {
        const int c = 4 * p + 32 * u;
        const float4 a0 = *(const float4*)(m0 + c);
        const float4 a1 = *(const float4*)(m1 + c);
        const float4 b0 = *(const float4*)(z0 + c);
        const float4 b1 = *(const float4*)(z1 + c);
        s00 += dot4(a0, b0); s01 += dot4(a0, b1);
        s10 += dot4(a1, b0); s11 += dot4(a1, b1);
      }
#pragma unroll
      for (int m = 1; m <= 4; m <<= 1) {
        s00 += __shfl_xor(s00, m, 64); s01 += __shfl_xor(s01, m, 64);
        s10 += __shfl_xor(s10, m, 64); s11 += __shfl_xor(s11, m, 64);
      }
      if (p == 0) {
        float* Pb = wsP + (size_t)b * KK * EE;
        Pb[(kbase + kc * 16 + kp) * EE + 2 * ep] = s00;
        Pb[(kbase + kc * 16 + kp) * EE + 2 * ep + 1] = s01;
        Pb[(kbase + kc * 16 + kp + 8) * EE + 2 * ep] = s10;
        Pb[(kbase + kc * 16 + kp + 8) * EE + 2 * ep + 1] = s11;
      }
      buf ^= 1;
    }
    // S partial = Z[:, cq] Z[:, cq]^T
    {
      const int e = tid >> 5, f = tid & 31;
      const float4* ze = ((const float4*)zAll[e]) + 32 * kq;
      const float4* zf = ((const float4*)zAll[f]) + 32 * kq;
      float a0 = 0, a1 = 0, a2 = 0, a3 = 0;
#pragma unroll 4
      for (int u = 0; u < 32; u++) {
        const float4 A = ze[u], Bq = zf[u];
        a0 += A.x * Bq.x; a1 += A.y * Bq.y; a2 += A.z * Bq.z; a3 += A.w * Bq.w;
      }
      wsSp[((size_t)b * 4 + kq) * 1024 + e * EE + f] = (a0 + a1) + (a2 + a3);
    }
  } else {
    // ================= inv0 body (block 0): register GJ, conditional pivot loads =================
    const int r = tid >> 3, q = tid & 7;
    float wreg[16], vreg[16];
    {
      const float4* a4 = (const float4*)(A0g + r * KK + 16 * q);
#pragma unroll
      for (int u = 0; u < 4; u++) {
        const float4 t4 = a4[u];
        wreg[4 * u] = t4.x; wreg[4 * u + 1] = t4.y; wreg[4 * u + 2] = t4.z; wreg[4 * u + 3] = t4.w;
      }
#pragma unroll
      for (int c = 0; c < 16; c++) vreg[c] = (16 * q + c == r) ? 1.0f : 0.0f;
    }
    if (q == 0) sFb[0][r] = wreg[0];
    if (r == 0) {
#pragma unroll
      for (int c = 0; c < 16; c++) { sPv[0][16 * q + c] = wreg[c]; sPv[0][128 + 16 * q + c] = vreg[c]; }
    }
    if (tid == 0) sScal[0] = 1.0f / wreg[0];
    __syncthreads();
#pragma unroll 1
    for (int j = 0; j < KK; ++j) {
      const int sl = j & 1, sn = sl ^ 1;
      const float f = sFb[sl][r] * sScal[sl];
      if (r != j) {
        if (16 * q + 15 >= j) {
          const float4* w4 = (const float4*)(sPv[sl] + 16 * q);
#pragma unroll
          for (int u = 0; u < 4; u++) {
            const float4 aa = w4[u];
            wreg[4 * u] -= f * aa.x; wreg[4 * u + 1] -= f * aa.y;
            wreg[4 * u + 2] -= f * aa.z; wreg[4 * u + 3] -= f * aa.w;
          }
        }
        if (16 * q <= j) {
          const float4* v4 = (const float4*)(sPv[sl] + 128 + 16 * q);
#pragma unroll
          for (int u = 0; u < 4; u++) {
            const float4 bb = v4[u];
            vreg[4 * u] -= f * bb.x; vreg[4 * u + 1] -= f * bb.y;
            vreg[4 * u + 2] -= f * bb.z; vreg[4 * u + 3] -= f * bb.w;
          }
        }
      }
      if (j + 1 < KK) {
        const int jn = j + 1;
        float wval = 0.0f;
#pragma unroll
        for (int c = 0; c < 16; c++) if (c == (jn & 15)) wval = wreg[c];
        if (q == (jn >> 4)) sFb[sn][r] = wval;
        if (r == jn) {
#pragma unroll
          for (int c = 0; c < 16; c++) { sPv[sn][16 * q + c] = wreg[c]; sPv[sn][128 + 16 * q + c] = vreg[c]; }
        }
        if (r == jn && q == (jn >> 4)) sScal[sn] = 1.0f / wval;
      }
      __syncthreads();
    }
    {
      float dval = 0.0f;
#pragma unroll
      for (int c = 0; c < 16; c++) if (c == (r & 15)) dval = wreg[c];
      if (q == (r >> 4)) sFb[0][r] = dval;
    }
    __syncthreads();
    {
      const float sc = 1.0f / sFb[0][r];
      float4* o4 = (float4*)(Ainv0 + r * KK + 16 * q);
#pragma unroll
      for (int u = 0; u < 4; u++) {
        float4 o;
        o.x = vreg[4 * u] * sc; o.y = vreg[4 * u + 1] * sc;
        o.z = vreg[4 * u + 2] * sc; o.w = vreg[4 * u + 3] * sc;
        o4[u] = o;
      }
    }
  }
}

// ---------------- Kernel 3: scan + fused postA, 1024 threads, one WG per batch ----------------
// 16-wave latency-hiding round: M-group (tid<512, holds areg[32]) does exactly ONE
// matvec-class job per phase; X-group (tid>=512) carries dgw/qt/Egg/dz/reductions on
// dedicated waves. dz[s<t] moved to PH2 idle waves; D-append parallel-reduced.
// Algebra and LDS layouts identical to the verified R4 kernel.
__global__ __launch_bounds__(1024) void scan_kernel(
    const float* __restrict__ Pg, const float* __restrict__ Sg,  // Sg = 4 partials per batch
    const float* __restrict__ scaleP, const float* __restrict__ Ainv0,
    float* __restrict__ wsKL, float* __restrict__ wsKLr, float* __restrict__ wsWt) {
  __shared__ __align__(16) float sPT[EE * PTS];    // P^T : [e][k]
  __shared__ __align__(16) float sGT[EE * LTR];    // G^T : [t][k]
  __shared__ __align__(16) float sEggT[EE * LTR];  // Egg^T : [t][k]
  __shared__ __align__(16) float uni2[EE * LTR];   // scan: Y^T | postA: R1T + GamT
  __shared__ __align__(16) float uni3[KK * LKM];   // scan: G [k][t] | postA: WrT [e][k]
  __shared__ __align__(16) float uni1[KK * LKM];   // scan: Y [k][j] | postA: RhsT [e][k]
  __shared__ __align__(16) float sEk[KK * LKM];    // Egg: [k][s]
  __shared__ __align__(16) float sS[EE * L36];     // S (symmetric)
  __shared__ __align__(16) float sD[EE * L36];     // D : [s][r2]
  __shared__ __align__(16) float sW[160];
  __shared__ __align__(16) float sWU[160];
  __shared__ __align__(16) float sPu[160];
  __shared__ __align__(16) float sPm[160];
  __shared__ __align__(16) float sQ[160];
  __shared__ __align__(16) float sDz[EE];
  __shared__ __align__(16) float sDgw[EE];
  __shared__ __align__(16) float sQt[EE];
  __shared__ __align__(16) float sScal[16];

  float* sYT = uni2;
  float* sGk = uni3;
  float* sYk = uni1;

  const int tid = threadIdx.x, ln = tid & 63;
  const int mr = (tid >> 2) & 127, mq = tid & 3;  // M-group matvec mapping (tid<512)
  const int b = blockIdx.x;

  float areg[32];
  if (tid < 512) {
    const float4* a4 = (const float4*)(Ainv0 + mr * KK + 32 * mq);
#pragma unroll
    for (int u = 0; u < 8; u++) {
      const float4 t4 = a4[u];
      areg[4 * u] = t4.x; areg[4 * u + 1] = t4.y; areg[4 * u + 2] = t4.z; areg[4 * u + 3] = t4.w;
    }
  }
  {
    const float* Pb = Pg + (size_t)b * KK * EE;
#pragma unroll
    for (int i = 0; i < 4; i++) {
      const int idx = tid + 1024 * i;                 // idx = k*32 + e
      sPT[(idx & 31) * PTS + (idx >> 5)] = Pb[idx];   // transpose into [e][k]
    }
    const float* Sb = Sg + (size_t)b * 4096;
    sS[(tid >> 5) * L36 + (tid & 31)] =
        Sb[tid] + Sb[tid + 1024] + Sb[tid + 2048] + Sb[tid + 3072];
  }
  if (tid < 16) sScal[tid] = 0.0f;
  const float v0 = scaleP[0] + V0EPS;
  __syncthreads();
  if (tid < 512) {  // w0 = Ainv0 * P[:,0]
    const float* xb = sPT + 32 * mq;
    float s = 0;
#pragma unroll
    for (int c = 0; c < 32; c++) s += areg[c] * xb[c];
    s += __shfl_xor(s, 1, 64); s += __shfl_xor(s, 2, 64);
    if (mq == 0) sW[SEG(mr)] = s;
  }
  __syncthreads();

#pragma unroll 1
  for (int t = 0; t < EE; ++t) {
    const bool hn = (t + 1 < EE);
    // ---- PH1: M: Pm = Ainv w | X: dgw = G^T w ; qt = Y^T w ; S2 ----
    if (tid < 512) {
      const float* xb = sW + 40 * mq;
      float s = 0;
#pragma unroll
      for (int c = 0; c < 16; c++) s += areg[c] * xb[c];
#pragma unroll
      for (int c = 0; c < 16; c++) s += areg[16 + c] * xb[20 + c];
      s += __shfl_xor(s, 1, 64); s += __shfl_xor(s, 2, 64);
      if (mq == 0) sPm[SEG(mr)] = s;
    } else if (tid < 768) {  // waves 8-11: dgw + S2
      const int s8 = (tid - 512) >> 3, p3 = tid & 7;
      if (s8 < t) {
        const float* gr = sGT + s8 * LTR + 16 * p3;
        const float* wr_ = sW + 20 * p3;
        float s = 0;
#pragma unroll
        for (int kk = 0; kk < 16; kk++) s += gr[kk] * wr_[kk];
        s += __shfl_xor(s, 1, 64); s += __shfl_xor(s, 2, 64); s += __shfl_xor(s, 4, 64);
        if (p3 == 0) sDgw[s8] = s;
      } else if (s8 == 31) {  // s8==31 never used by dgw: S2 here
        const float* wp = sW + 20 * p3;
        float s = 0;
#pragma unroll
        for (int kk = 0; kk < 16; kk++) s += wp[kk] * wp[kk];
        s += __shfl_xor(s, 1, 64); s += __shfl_xor(s, 2, 64); s += __shfl_xor(s, 4, 64);
        if (p3 == 0) sScal[SC_S2] = s;
      }
    } else {  // waves 12-15: qt
      const int j = (tid - 768) >> 3, p3 = tid & 7;
      if (j < t) {
        const float* yr = sYT + j * LTR + 16 * p3;
        const float* wr_ = sW + 20 * p3;
        float s = 0;
#pragma unroll
        for (int kk = 0; kk < 16; kk++) s += yr[kk] * wr_[kk];
        s += __shfl_xor(s, 1, 64); s += __shfl_xor(s, 2, 64); s += __shfl_xor(s, 4, 64);
        if (p3 == 0) sQt[j] = s;
      }
    }
    __syncthreads();
    // ---- PH2: wU ; D_t(parallel) ; R22 ; sigma/KL ; Egg_t ; dz[s<t] ----
    if (tid < 256) {  // waves 0-3: wU[k] = v0 w[k] - sum_{j<t} Y[k][j] qt[j]
      const int k = tid >> 1, h = tid & 1;
      const float* yk = sYk + k * LKM + 16 * h;
      const float* qb = sQt + 16 * h;
      float a = 0;
#pragma unroll
      for (int u = 0; u < 16; u++) {
        const int j = 16 * h + u;
        a += (j < t) ? yk[u] * qb[u] : 0.0f;
      }
      a += __shfl_xor(a, 1, 64);
      if (h == 0) sWU[SEG(k)] = v0 * sW[SEG(k)] - a;
    } else if (tid < 384) {  // waves 4-5: D append, 4 threads per r2
      const int r2 = (tid - 256) >> 2, p = tid & 3;
      float a = 0;
#pragma unroll
      for (int u = 0; u < 8; u++) {
        const int s2 = p + 4 * u;
        a += (s2 < t) ? sDgw[s2] * sD[s2 * L36 + r2] : 0.0f;
      }
      a += __shfl_xor(a, 1, 64); a += __shfl_xor(a, 2, 64);
      if (p == 0) sD[t * L36 + r2] = ((r2 == t) ? 1.0f : 0.0f) - a;
    } else if (tid < 448) {  // wave 6: R22 = w.Pm
      float a = sW[SEG(ln)] * sPm[SEG(ln)] + sW[SEG(ln + 64)] * sPm[SEG(ln + 64)];
      a = wsum64(a);
      if (ln == 0) sScal[SC_R22] = a;
    } else if (tid < 512) {  // wave 7: sigma ; KL
      const float s2v = sScal[SC_S2];
      float a = (ln < t) ? sQt[ln] * sQt[ln] : 0.0f;
      a = wsum64(a);
      if (ln == 0) {
        sScal[SC_SIG] = v0 * s2v - a + 1.0f;
        sScal[SC_KL] += s2v;
      }
    } else if (tid < 640) {  // waves 8-9: Egg append (k-major recurrence)
      const int k = tid - 512;
      float a = sW[SEG(k)];
      const float* ek = sEk + k * LKM;
      const int nc = (t + 3) >> 2;
#pragma unroll 1
      for (int c4 = 0; c4 < nc; ++c4) {
        const float4 ev = *(const float4*)(ek + 4 * c4);
        const float4 dv = *(const float4*)(sDgw + 4 * c4);
        const int u0 = 4 * c4;
        a -= ((u0 + 0 < t) ? ev.x * dv.x : 0.0f) + ((u0 + 1 < t) ? ev.y * dv.y : 0.0f) +
             ((u0 + 2 < t) ? ev.z * dv.z : 0.0f) + ((u0 + 3 < t) ? ev.w * dv.w : 0.0f);
      }
      sEk[k * LKM + t] = a;
      sEggT[t * LTR + k] = a;
    } else if (tid < 896) {  // waves 10-13: dz[s4] for s4 < t (rows < t all exist)
      const int s4 = (tid - 640) >> 3, p3 = tid & 7;
      if (hn && s4 < t) {
        const float* er = sEggT + s4 * LTR + 16 * p3;
        const float* pr = sPT + (t + 1) * PTS + 16 * p3;
        float a = 0;
#pragma unroll
        for (int kk = 0; kk < 16; kk++) a -= er[kk] * pr[kk];
        const float4 dv = *(const float4*)(sD + s4 * L36 + 4 * p3);
        const float4 sv = *(const float4*)(sS + (t + 1) * L36 + 4 * p3);  // S symmetric
        a += dot4(dv, sv);
        a += __shfl_xor(a, 1, 64); a += __shfl_xor(a, 2, 64); a += __shfl_xor(a, 4, 64);
        if (p3 == 0) sDz[s4] = a;
      }
    }
    __syncthreads();
    // ---- PH3: M: Pu = Ainv wU | X: dz[t] ; B2 ; B1+R12 ; G/Y appends ----
    if (tid < 512) {
      const float* xb = sWU + 40 * mq;
      float s = 0;
#pragma unroll
      for (int c = 0; c < 16; c++) s += areg[c] * xb[c];
#pragma unroll
      for (int c = 0; c < 16; c++) s += areg[16 + c] * xb[20 + c];
      s += __shfl_xor(s, 1, 64); s += __shfl_xor(s, 2, 64);
      if (mq == 0) sPu[SEG(mr)] = s;
    } else if (tid < 576) {  // wave 8: dz[t] = D[t,:].S[:,t+1] - Egg[t,:].P[:,t+1]
      if (hn) {
        float a = -(sEggT[t * LTR + ln] * sPT[(t + 1) * PTS + ln] +
                    sEggT[t * LTR + ln + 64] * sPT[(t + 1) * PTS + ln + 64]);
        if (ln < 32) a += sD[t * L36 + ln] * sS[(t + 1) * L36 + ln];
        a = wsum64(a);
        if (ln == 0) sDz[t] = a;
      }
    } else if (tid < 640) {  // wave 9: B2 = Egg_t . P[:,t]
      float a = sEggT[t * LTR + ln] * sPT[t * PTS + ln] +
                sEggT[t * LTR + ln + 64] * sPT[t * PTS + ln + 64];
      a = wsum64(a);
      if (ln == 0) sScal[SC_B2] = a;
    } else if (tid < 704) {  // wave 10: lanes<32: B1 ; lanes>=32: R12 = wU.Pm
      if (ln < 32) {
        float a = sD[t * L36 + ln] * sS[t * L36 + ln];
        a = wsum32(a);
        if (ln == 0) sScal[SC_B1] = a;
      } else {
        const int k0 = (ln - 32) * 4;
        const float4 wu4 = *(const float4*)(sWU + SEG(k0));
        const float4 pm4 = *(const float4*)(sPm + SEG(k0));
        float a = dot4(wu4, pm4);
        a = wsum32(a);
        if (ln == 32) sScal[SC_R12] = a;
      }
    } else if (tid < 768) {  // wave 11: G/Y appends (both layouts)
      const float sig = sScal[SC_SIG];
      const float rsq = rsqrtf(sig);
#pragma unroll
      for (int u = 0; u < 2; u++) {
        const int k = ln + 64 * u;
        const float wu = sWU[SEG(k)];
        const float gv = wu / sig;
        const float yv = wu * rsq;
        sGT[t * LTR + k] = gv;
        sGk[k * LKM + t] = gv;
        sYT[t * LTR + k] = yv;
        sYk[k * LKM + t] = yv;
      }
    }
    __syncthreads();
    // ---- PH4: M: q_next | X: R11 ----
    if (tid < 512) {
      if (hn) {
        const float* gk = sGk + mr * LKM + 8 * mq;
        const float* dzb = sDz + 8 * mq;
        float a = 0;
#pragma unroll
        for (int u = 0; u < 8; u++) {
          const int s2 = 8 * mq + u;
          a += (s2 < t) ? gk[u] * dzb[u] : 0.0f;
        }
        a += __shfl_xor(a, 1, 64); a += __shfl_xor(a, 2, 64);
        if (mq == 0)
          sQ[SEG(mr)] = sPT[(t + 1) * PTS + mr] + a + (sWU[SEG(mr)] / sScal[SC_SIG]) * sDz[t];
      }
    } else if (tid < 576) {  // wave 8: R11 = wU . Pu
      float a = sWU[SEG(ln)] * sPu[SEG(ln)] + sWU[SEG(ln + 64)] * sPu[SEG(ln + 64)];
      a = wsum64(a);
      if (ln == 0) sScal[SC_R11] = a;
    }
    __syncthreads();
    // ---- PH5: M: Ainv rank-2 update + w_next ----
    if (tid < 512) {
      {
        const float4 sc0 = *(const float4*)(sScal);      // S2, SIG, KL, B1
        const float4 sc1 = *(const float4*)(sScal + 4);  // B2, R11, R12, R22
        const float rs = 1.0f / sc0.y;
        const float beta = sc0.w - sc1.x - sc0.x;
        const float e11 = sc1.y * rs * rs;
        const float e12 = sc1.z * rs + 1.0f;
        const float e22 = sc1.w - beta;
        const float rd = 1.0f / (e11 * e22 - e12 * e12);
        const float t11 = e22 * rd, t12 = -e12 * rd, t22 = e11 * rd;
        const float u1r = sPu[SEG(mr)] * rs, u2r = sPm[SEG(mr)];
        const float* pub = sPu + 40 * mq;
        const float* pmb = sPm + 40 * mq;
#pragma unroll
        for (int c = 0; c < 16; c++) {
          const float u1c = pub[c] * rs;
          const float u2c = pmb[c];
          areg[c] -= u1r * (t11 * u1c + t12 * u2c) + u2r * (t12 * u1c + t22 * u2c);
        }
#pragma unroll
        for (int c = 0; c < 16; c++) {
          const float u1c = pub[20 + c] * rs;
          const float u2c = pmb[20 + c];
          areg[16 + c] -= u1r * (t11 * u1c + t12 * u2c) + u2r * (t12 * u1c + t22 * u2c);
        }
      }
      if (hn) {
        const float* xb = sQ + 40 * mq;
        float s = 0;
#pragma unroll
        for (int c = 0; c < 16; c++) s += areg[c] * xb[c];
#pragma unroll
        for (int c = 0; c < 16; c++) s += areg[16 + c] * xb[20 + c];
        s += __shfl_xor(s, 1, 64); s += __shfl_xor(s, 2, 64);
        if (mq == 0) sW[SEG(mr)] = s;
      }
    }
    __syncthreads();
  }

  // ================= fused postA =================
  float* sR1T  = uni2;         // [32][36]  (over dead sYT)
  float* sGamT = uni2 + 1152;  // [32][36]
  float* sRhsT = uni1;         // [32][132] (over dead sYk)
  float* sWrT  = uni3;         // [32][132] (over sGk -- dead after PA1)
  if (tid == 0) wsKL[b] = sScal[SC_KL];

  // ---- PA0: R1T[e][s] = D[s,:].S[e,:] - EggT[s,:].PT[e,:] ----
  {
    const int s = tid >> 5, e = tid & 31;
    const float4* er = (const float4*)(sEggT + s * LTR);
    const float4* pr = (const float4*)(sPT + e * PTS);
    float a = 0;
#pragma unroll 8
    for (int u = 0; u < 32; ++u) a -= dot4(er[u], pr[u]);
    const float4* dr = (const float4*)(sD + s * L36);
    const float4* sr = (const float4*)(sS + e * L36);
#pragma unroll
    for (int u = 0; u < 8; ++u) a += dot4(dr[u], sr[u]);
    sR1T[e * 36 + s] = a;
  }
  __syncthreads();
  // ---- PA1: RhsT[e][k] = PT[e][k] + sum_s G[k][s] R1T[e][s] ----
  {
    const int k = tid & 127, e8 = tid >> 7;
    float4 g0, g1, g2, g3, g4, g5, g6, g7;
    {
      const float4* gk = (const float4*)(sGk + k * LKM);
      g0 = gk[0]; g1 = gk[1]; g2 = gk[2]; g3 = gk[3];
      g4 = gk[4]; g5 = gk[5]; g6 = gk[6]; g7 = gk[7];
    }
#pragma unroll
    for (int u = 0; u < 4; ++u) {
      const int e = e8 * 4 + u;
      const float4* r1 = (const float4*)(sR1T + e * 36);
      float a = sPT[e * PTS + k];
      a += dot4(g0, r1[0]) + dot4(g1, r1[1]) + dot4(g2, r1[2]) + dot4(g3, r1[3]);
      a += dot4(g4, r1[4]) + dot4(g5, r1[5]) + dot4(g6, r1[6]) + dot4(g7, r1[7]);
      sRhsT[e * PTS + k] = a;
    }
  }
  __syncthreads();
  // ---- PA2: WrT[e][k] = AinvP . rhs[:,e]  (areg matvec, 32 episodes, M-group) ----
  if (tid < 512) {
#pragma unroll 2
    for (int e = 0; e < EE; ++e) {
      const float* xb = sRhsT + e * PTS + 32 * mq;
      float s = 0;
#pragma unroll
      for (int c = 0; c < 32; c++) s += areg[c] * xb[c];
      s += __shfl_xor(s, 1, 64); s += __shfl_xor(s, 2, 64);
      if (mq == 0) sWrT[e * PTS + mr] = s;
    }
  }
  __syncthreads();
  // ---- PA3: GamT[e][s] = GT[s,:].WrT[e,:] ----
  {
    const int s = tid >> 5, e = tid & 31;
    const float4* gr = (const float4*)(sGT + s * LTR);
    const float4* wr = (const float4*)(sWrT + e * PTS);
    float a = 0;
#pragma unroll 8
    for (int u = 0; u < 32; ++u) a += dot4(gr[u], wr[u]);
    sGamT[e * 36 + s] = a;
  }
  __syncthreads();
  // ---- PA4: Wc -> wsWt rows 0..127 ; Vc -> rows 128..159 ; KLr ----
  {
    const int k = tid & 127, e8 = tid >> 7;
    float4 E0, E1, E2, E3, E4, E5, E6, E7;
    {
      const float4* ek = (const float4*)(sEk + k * LKM);
      E0 = ek[0]; E1 = ek[1]; E2 = ek[2]; E3 = ek[3];
      E4 = ek[4]; E5 = ek[5]; E6 = ek[6]; E7 = ek[7];
    }
#pragma unroll
    for (int u = 0; u < 4; ++u) {
      const int e = e8 * 4 + u;
      const float4* gm = (const float4*)(sGamT + e * 36);
      float a = sWrT[e * PTS + k];
      a -= dot4(E0, gm[0]) + dot4(E1, gm[1]) + dot4(E2, gm[2]) + dot4(E3, gm[3]);
      a -= dot4(E4, gm[4]) + dot4(E5, gm[5]) + dot4(E6, gm[6]) + dot4(E7, gm[7]);
      wsWt[(size_t)b * 5120 + e * 160 + k] = a;
    }
  }
  {  // Vc[e][sp] = sum_f D[f][sp] * GamT[e][f]
    const int e = tid & 31, sp = tid >> 5;  // sp 0..31
    float4 gm[8];
    {
      const float4* g4 = (const float4*)(sGamT + e * 36);
#pragma unroll
      for (int u = 0; u < 8; ++u) gm[u] = g4[u];
    }
    float a = 0;
#pragma unroll
    for (int u = 0; u < 8; ++u) {
      const float4 g = gm[u];
      a += sD[(4 * u + 0) * L36 + sp] * g.x + sD[(4 * u + 1) * L36 + sp] * g.y +
           sD[(4 * u + 2) * L36 + sp] * g.z + sD[(4 * u + 3) * L36 + sp] * g.w;
    }
    wsWt[(size_t)b * 5120 + e * 160 + 128 + sp] = a;
  }
  {  // KLr[e] = sum_k Wr[k][e]^2
    const int e = tid >> 5, p = tid & 31;
    const float4 w0 = *(const float4*)(sWrT + e * PTS + 4 * p);
    float a = dot4(w0, w0);
    a = wsum32(a);
    if ((tid & 31) == 0) wsKLr[b * EE + e] = a;
  }
}

// ---------------- Kernel 4: postB (256 WGs) + final (block 256) ----------------
__global__ __launch_bounds__(512) void postBF_kernel(
    const float* __restrict__ wsWt, const float* __restrict__ x,
    const float* __restrict__ M0, const float* __restrict__ znoise,
    const float* __restrict__ wsKL, const float* __restrict__ wsKLr,
    const float* __restrict__ lwsP, float* __restrict__ out) {
  __shared__ __align__(16) float sWtT[32 * LWT];   // Wt^T : [e][row], stride 176
  __shared__ __align__(16) float Mch[2 * 16 * 132];
  const int tid = threadIdx.x;

  if (blockIdx.x == 256) {
    // ======== final: total divergence ========
    float* sPp = sWtT;  // reuse
    float s = 0.0f;
    if (tid < 64) s += wsKL[tid];
    for (int i = tid; i < 2048; i += 512) s += wsKLr[i];
    sPp[tid] = s;
    __syncthreads();
    for (int off = 256; off > 0; off >>= 1) {
      if (tid < off) sPp[tid] += sPp[tid + off];
      __syncthreads();
    }
    if (tid == 0) {
      const float lws = lwsP[0];
      const float sw2 = expf(2.0f * lws);
      out[(size_t)BB * EE * CC] =
          0.5f * sPp[0] / (float)(EE * BB) + (float)KK * (sw2 - 1.0f - 2.0f * lws);
    }
    return;
  }

  const int b = blockIdx.x >> 2, cq = blockIdx.x & 3;
  {
    // wsWt is [b][e][160]: direct (no transpose) load
    const int e = tid >> 4, j = tid & 15;
    const float* Wg = wsWt + (size_t)b * 5120 + e * 160;
#pragma unroll
    for (int u = 0; u < 10; ++u) sWtT[e * LWT + j + 16 * u] = Wg[j + 16 * u];
  }
  const int srow = tid >> 5, sc4 = tid & 31;  // stage: 16 rows x 32 float4 (128 cols)
  const int e = tid & 31, cs = tid >> 5;      // compute: episode e, col-octet cs
  const float* xb = x + (size_t)b * EE * CC;
  const int cbase = cq * 128;
  float4 st = *(const float4*)(M0 + srow * CC + cbase + 4 * sc4);  // ch2=0 rows are all M0
  float acc[8];
#pragma unroll
  for (int u = 0; u < 8; u++) acc[u] = 0.0f;
  int buf = 0;
#pragma unroll 1
  for (int ch2 = 0; ch2 < 10; ++ch2) {
    *(float4*)(Mch + buf * 2112 + srow * 132 + 4 * sc4) = st;
    __syncthreads();
    if (ch2 + 1 < 10) {
      const int row = (ch2 + 1) * 16 + srow;
      st = (row < 128) ? *(const float4*)(M0 + row * CC + cbase + 4 * sc4)
                       : *(const float4*)(xb + (row - 128) * CC + cbase + 4 * sc4);
    }
    const float4* wt4 = (const float4*)(sWtT + e * LWT + ch2 * 16);
    const float4 wa = wt4[0], wb = wt4[1], wc = wt4[2], wd = wt4[3];
    const float wv16[16] = {wa.x, wa.y, wa.z, wa.w, wb.x, wb.y, wb.z, wb.w,
                            wc.x, wc.y, wc.z, wc.w, wd.x, wd.y, wd.z, wd.w};
#pragma unroll
    for (int kk = 0; kk < 16; ++kk) {
      const float* mrp = Mch + buf * 2112 + kk * 132 + cs * 8;
      const float4 m0 = *(const float4*)(mrp);
      const float4 m1 = *(const float4*)(mrp + 4);
      const float wk = wv16[kk];
      acc[0] += wk * m0.x; acc[1] += wk * m0.y; acc[2] += wk * m0.z; acc[3] += wk * m0.w;
      acc[4] += wk * m1.x; acc[5] += wk * m1.y; acc[6] += wk * m1.z; acc[7] += wk * m1.w;
    }
    buf ^= 1;
  }
  {
    const size_t ob = ((size_t)b * EE + e) * CC + cbase + cs * 8;
    const size_t nb = ((size_t)e * BB + b) * CC + cbase + cs * 8;
#pragma unroll
    for (int u = 0; u < 2; u++) {
      const float4 nz = *(const float4*)(znoise + nb + 4 * u);
      float4 o;
      o.x = acc[4 * u] + nz.x;     o.y = acc[4 * u + 1] + nz.y;
      o.z = acc[4 * u + 2] + nz.z; o.w = acc[4 * u + 3] + nz.w;
      *(float4*)(out + ob + 4 * u) = o;
    }
  }
}

extern "C" void kernel_launch(void* const* d_in, const int* in_sizes, int n_in,
                              void* d_out, int out_size, void* d_ws, size_t ws_size,
                              hipStream_t stream) {
  (void)in_sizes; (void)n_in; (void)out_size; (void)ws_size;
  const float* x = (const float*)d_in[0];        // [B,E,C]
  const float* M0 = (const float*)d_in[1];       // [K,C]
  const float* scaleP = (const float*)d_in[2];   // scalar
  const float* lwsP = (const float*)d_in[3];     // scalar
  const float* znoise = (const float*)d_in[4];   // [E,B,C]
  float* out = (float*)d_out;

  float* ws = (float*)d_ws;
  float* wsP = ws;                        // 262144
  float* wsSp = wsP + 262144;             // 262144 (64 x 4 partials x 1024)
  float* wsA0 = wsSp + 262144;            // 16384
  float* wsAinv0 = wsA0 + 16384;          // 16384
  float* wsKL = wsAinv0 + 16384;          // 64
  float* wsKLr = wsKL + 64;               // 2048
  float* wsWt = wsKLr + 2048;             // 327680 (64 x 32 x 160, [b][e][row])

  a0_kernel<<<256, 256, 0, stream>>>(M0, wsA0);
  psinv_kernel<<<257, 1024, 0, stream>>>(x, M0, wsP, wsSp, wsA0, wsAinv0);
  scan_kernel<<<BB, 1024, 0, stream>>>(wsP, wsSp, scaleP, wsAinv0,
                                       wsKL, wsKLr, wsWt);
  postBF_kernel<<<257, 512, 0, stream>>>(wsWt, x, M0, znoise, wsKL, wsKLr, lwsP, out);
}

// Round 6
// 270.916 us; speedup vs baseline: 1.4037x; 1.0627x over previous
//
#include <hip/hip_runtime.h>

// (B,E,K,C) = (64,32,128,512), fp32.
#define BB 64
#define EE 32
#define KK 128
#define CC 512
#define V0EPS 1e-7f

#define LTR 132   // [32][132] padded stride
#define PTS 132   // scan: P^T / RhsT / WrT row stride
#define LKM 36    // scan: k-major row stride (G/Y/Egg)
#define L36 36    // scan: S/D row stride
#define LWT 176   // postB: Wt^T row stride
// segment-padded K-vector layout: element i lives at (i/16)*20 + (i%16)
#define SEG(i) ((((i) >> 4) * 20) + ((i) & 15))

// scan sScal slots (order matters: read as two float4s in PH5)
#define SC_S2  0
#define SC_SIG 1
#define SC_KL  2
#define SC_B1  3
#define SC_B2  4
#define SC_R11 5
#define SC_R12 6
#define SC_R22 7

__device__ __forceinline__ float wsum64(float v) {
#pragma unroll
  for (int m = 32; m >= 1; m >>= 1) v += __shfl_xor(v, m, 64);
  return v;
}

__device__ __forceinline__ float wsum32(float v) {  // reduce within aligned 32-lane half
#pragma unroll
  for (int m = 16; m >= 1; m >>= 1) v += __shfl_xor(v, m, 64);
  return v;
}

__device__ __forceinline__ float dot4(const float4 a, const float4 b) {
  return a.x * b.x + a.y * b.y + a.z * b.z + a.w * b.w;
}

// ---------------- Kernel 1: A0 = M0 M0^T + I (256 WGs: k x l-half) ----------------
__global__ __launch_bounds__(256) void a0_kernel(const float* __restrict__ M0,
                                                 float* __restrict__ wsA0) {
  __shared__ __align__(16) float sRow[CC];
  const int k = blockIdx.x >> 1, half = blockIdx.x & 1;
  for (int c = threadIdx.x; c < CC; c += 256) sRow[c] = M0[k * CC + c];
  __syncthreads();
  const int wv = threadIdx.x >> 6, ln = threadIdx.x & 63;
  const float4* zr = (const float4*)(sRow + 8 * ln);
  const float4 z0 = zr[0], z1 = zr[1];
  for (int li = 0; li < 16; ++li) {
    const int l = half * 64 + wv * 16 + li;
    const float4* rp = (const float4*)(M0 + l * CC + 8 * ln);
    const float4 a = rp[0], b = rp[1];
    float s = dot4(a, z0) + dot4(b, z1);
    s = wsum64(s);
    if (ln == 0) wsA0[k * KK + l] = s + (l == k ? 1.0f : 0.0f);
  }
}

// ------- Kernel 2: block 0 -> inv(A0) via 2-pivot GJ ; blocks 1..256 -> P/S partials -------
__global__ __launch_bounds__(1024) void psinv_kernel(const float* __restrict__ x,
                                                     const float* __restrict__ M0,
                                                     float* __restrict__ wsP,
                                                     float* __restrict__ wsSp,
                                                     const float* __restrict__ A0g,
                                                     float* __restrict__ Ainv0) {
  __shared__ __align__(16) float zAll[32][520];
  __shared__ __align__(16) float Mch[2][16][520];
  __shared__ __align__(16) float sFb[2][2][128];   // [buf][col j / j+1][row]
  __shared__ __align__(16) float sPv[2][2][256];   // [buf][row j / j+1][A-part 128 | I-part 128]
  const int tid = threadIdx.x;

  if (blockIdx.x > 0) {
    // ================= ps body: P rows kq*32..kq*32+31 ; S partial over c-quarter =================
    const int b = (blockIdx.x - 1) >> 2, kq = (blockIdx.x - 1) & 3;
    {
      const float4* x4 = (const float4*)(x + (size_t)b * EE * CC);
#pragma unroll
      for (int i = 0; i < 4; i++) {
        const int F = tid + 1024 * i, e = F >> 7, c4 = F & 127;
        ((float4*)zAll[e])[c4] = x4[F];
      }
    }
    const float4* M4 = (const float4*)M0;
    const int srow = tid >> 7, sc4 = tid & 127;
    const int kbase = kq * 32;
    float4 st0 = M4[(kbase + srow) * 128 + sc4];
    float4 st1 = M4[(kbase + 8 + srow) * 128 + sc4];
    int buf = 0;
    const int p = tid & 7;           // 8 threads per dot
    const int ep = (tid >> 3) & 15;  // episodes 2*ep, 2*ep+1  (0..31)
    const int kp = tid >> 7;         // k rows kp, kp+8
#pragma unroll 1
    for (int kc = 0; kc < 2; ++kc) {
      ((float4*)Mch[buf][srow])[sc4] = st0;
      ((float4*)Mch[buf][8 + srow])[sc4] = st1;
      __syncthreads();
      if (kc == 0) {
        st0 = M4[(kbase + 16 + srow) * 128 + sc4];
        st1 = M4[(kbase + 24 + srow) * 128 + sc4];
      }
      float s00 = 0, s01 = 0, s10 = 0, s11 = 0;
      const float* m0 = Mch[buf][kp];
      const float* m1 = Mch[buf][kp + 8];
      const float* z0 = zAll[2 * ep];
      const float* z1 = zAll[2 * ep + 1];
#pragma unroll
      for (int u = 0; u < 16; u++) {
        const int c = 4 * p + 32 * u;
        const float4 a0 = *(const float4*)(m0 + c);
        const float4 a1 = *(const float4*)(m1 + c);
        const float4 b0 = *(const float4*)(z0 + c);
        const float4 b1 = *(const float4*)(z1 + c);
        s00 += dot4(a0, b0); s01 += dot4(a0, b1);
        s10 += dot4(a1, b0); s11 += dot4(a1, b1);
      }
#pragma unroll
      for (int m = 1; m <= 4; m <<= 1) {
        s00 += __shfl_xor(s00, m, 64); s01 += __shfl_xor(s01, m, 64);
        s10 += __shfl_xor(s10, m, 64); s11 += __shfl_xor(s11, m, 64);
      }
      if (p == 0) {
        float* Pb = wsP + (size_t)b * KK * EE;
        Pb[(kbase + kc * 16 + kp) * EE + 2 * ep] = s00;
        Pb[(kbase + kc * 16 + kp) * EE + 2 * ep + 1] = s01;
        Pb[(kbase + kc * 16 + kp + 8) * EE + 2 * ep] = s10;
        Pb[(kbase + kc * 16 + kp + 8) * EE + 2 * ep + 1] = s11;
      }
      buf ^= 1;
    }
    // S partial = Z[:, cq] Z[:, cq]^T
    {
      const int e = tid >> 5, f = tid & 31;
      const float4* ze = ((const float4*)zAll[e]) + 32 * kq;
      const float4* zf = ((const float4*)zAll[f]) + 32 * kq;
      float a0 = 0, a1 = 0, a2 = 0, a3 = 0;
#pragma unroll 4
      for (int u = 0; u < 32; u++) {
        const float4 A = ze[u], Bq = zf[u];
        a0 += A.x * Bq.x; a1 += A.y * Bq.y; a2 += A.z * Bq.z; a3 += A.w * Bq.w;
      }
      wsSp[((size_t)b * 4 + kq) * 1024 + e * EE + f] = (a0 + a1) + (a2 + a3);
    }
  } else {
    // ======== inv0 body (block 0): 2-pivot register GJ, 64 super-iterations ========
    // Per super-iteration (pivots j, j+1): exact composition of two eliminations via
    // the 2x2 pivot block: g=p10/p00, p11'=p11-g*p01, alpha=c0[r]/p00 (0 if r==j),
    // beta=(c1[r]-alpha*p01)/p11' (0 if r==j+1); row_r -= (alpha-beta*g)*row_j + beta*row_{j+1}.
    const int r = tid >> 3, q = tid & 7;
    float wreg[16], vreg[16];
    {
      const float4* a4 = (const float4*)(A0g + r * KK + 16 * q);
#pragma unroll
      for (int u = 0; u < 4; u++) {
        const float4 t4 = a4[u];
        wreg[4 * u] = t4.x; wreg[4 * u + 1] = t4.y; wreg[4 * u + 2] = t4.z; wreg[4 * u + 3] = t4.w;
      }
#pragma unroll
      for (int c = 0; c < 16; c++) vreg[c] = (16 * q + c == r) ? 1.0f : 0.0f;
    }
    // prologue: stage cols 0,1 and rows 0,1
    if (q == 0) { sFb[0][0][r] = wreg[0]; sFb[0][1][r] = wreg[1]; }
    if (r == 0) {
#pragma unroll
      for (int c = 0; c < 16; c++) { sPv[0][0][16 * q + c] = wreg[c]; sPv[0][0][128 + 16 * q + c] = vreg[c]; }
    }
    if (r == 1) {
#pragma unroll
      for (int c = 0; c < 16; c++) { sPv[0][1][16 * q + c] = wreg[c]; sPv[0][1][128 + 16 * q + c] = vreg[c]; }
    }
    __syncthreads();
#pragma unroll 1
    for (int jj = 0; jj < 64; ++jj) {
      const int j = 2 * jj, db = jj & 1, dn = db ^ 1;
      const float* c0 = sFb[db][0];
      const float* c1 = sFb[db][1];
      const float* rj = sPv[db][0];
      const float* rj1 = sPv[db][1];
      const float p00 = c0[j], p10 = c0[j + 1], p01 = c1[j], p11 = c1[j + 1];
      const float rp00 = 1.0f / p00;
      const float g = p10 * rp00;
      const float rp11 = 1.0f / (p11 - g * p01);
      const float alpha = (r == j) ? 0.0f : c0[r] * rp00;
      const float beta = (r == j + 1) ? 0.0f : (c1[r] - alpha * p01) * rp11;
      const float ca = alpha - beta * g, cb = beta;
      if (16 * q + 15 >= j) {  // A-part: only cols >= j are touched (rows j/j+1 zero left of j)
        const float4* w0 = (const float4*)(rj + 16 * q);
        const float4* w1 = (const float4*)(rj1 + 16 * q);
#pragma unroll
        for (int u = 0; u < 4; u++) {
          const float4 a0 = w0[u], a1 = w1[u];
          wreg[4 * u]     -= ca * a0.x + cb * a1.x;
          wreg[4 * u + 1] -= ca * a0.y + cb * a1.y;
          wreg[4 * u + 2] -= ca * a0.z + cb * a1.z;
          wreg[4 * u + 3] -= ca * a0.w + cb * a1.w;
        }
      }
      if (16 * q <= j + 1) {  // I-part: rows j/j+1 nonzero only in cols <= j+1
        const float4* v0 = (const float4*)(rj + 128 + 16 * q);
        const float4* v1 = (const float4*)(rj1 + 128 + 16 * q);
#pragma unroll
        for (int u = 0; u < 4; u++) {
          const float4 a0 = v0[u], a1 = v1[u];
          vreg[4 * u]     -= ca * a0.x + cb * a1.x;
          vreg[4 * u + 1] -= ca * a0.y + cb * a1.y;
          vreg[4 * u + 2] -= ca * a0.z + cb * a1.z;
          vreg[4 * u + 3] -= ca * a0.w + cb * a1.w;
        }
      }
      if (jj + 1 < 64) {  // stage cols/rows j+2, j+3 (post-update values)
        const int j2 = j + 2, j3 = j + 3;
        float w2 = 0.0f, w3 = 0.0f;
#pragma unroll
        for (int c = 0; c < 16; c++) {
          if (c == (j2 & 15)) w2 = wreg[c];
          if (c == (j3 & 15)) w3 = wreg[c];
        }
        if (q == (j2 >> 4)) sFb[dn][0][r] = w2;
        if (q == (j3 >> 4)) sFb[dn][1][r] = w3;
        if (r == j2) {
#pragma unroll
          for (int c = 0; c < 16; c++) { sPv[dn][0][16 * q + c] = wreg[c]; sPv[dn][0][128 + 16 * q + c] = vreg[c]; }
        }
        if (r == j3) {
#pragma unroll
          for (int c = 0; c < 16; c++) { sPv[dn][1][16 * q + c] = wreg[c]; sPv[dn][1][128 + 16 * q + c] = vreg[c]; }
        }
      }
      __syncthreads();
    }
    {
      float dval = 0.0f;
#pragma unroll
      for (int c = 0; c < 16; c++) if (c == (r & 15)) dval = wreg[c];
      if (q == (r >> 4)) sFb[0][0][r] = dval;
    }
    __syncthreads();
    {
      const float sc = 1.0f / sFb[0][0][r];
      float4* o4 = (float4*)(Ainv0 + r * KK + 16 * q);
#pragma unroll
      for (int u = 0; u < 4; u++) {
        float4 o;
        o.x = vreg[4 * u] * sc; o.y = vreg[4 * u + 1] * sc;
        o.z = vreg[4 * u + 2] * sc; o.w = vreg[4 * u + 3] * sc;
        o4[u] = o;
      }
    }
  }
}

// ---------------- Kernel 3: scan + fused postA, 1024 threads, one WG per batch ----------------
// (unchanged from R5: M-group tid<512 holds areg[32], one matvec job per phase;
//  X-group tid>=512 carries dgw/qt/Egg/dz/reductions on dedicated waves.)
__global__ __launch_bounds__(1024) void scan_kernel(
    const float* __restrict__ Pg, const float* __restrict__ Sg,  // Sg = 4 partials per batch
    const float* __restrict__ scaleP, const float* __restrict__ Ainv0,
    float* __restrict__ wsKL, float* __restrict__ wsKLr, float* __restrict__ wsWt) {
  __shared__ __align__(16) float sPT[EE * PTS];    // P^T : [e][k]
  __shared__ __align__(16) float sGT[EE * LTR];    // G^T : [t][k]
  __shared__ __align__(16) float sEggT[EE * LTR];  // Egg^T : [t][k]
  __shared__ __align__(16) float uni2[EE * LTR];   // scan: Y^T | postA: R1T + GamT
  __shared__ __align__(16) float uni3[KK * LKM];   // scan: G [k][t] | postA: WrT [e][k]
  __shared__ __align__(16) float uni1[KK * LKM];   // scan: Y [k][j] | postA: RhsT [e][k]
  __shared__ __align__(16) float sEk[KK * LKM];    // Egg: [k][s]
  __shared__ __align__(16) float sS[EE * L36];     // S (symmetric)
  __shared__ __align__(16) float sD[EE * L36];     // D : [s][r2]
  __shared__ __align__(16) float sW[160];
  __shared__ __align__(16) float sWU[160];
  __shared__ __align__(16) float sPu[160];
  __shared__ __align__(16) float sPm[160];
  __shared__ __align__(16) float sQ[160];
  __shared__ __align__(16) float sDz[EE];
  __shared__ __align__(16) float sDgw[EE];
  __shared__ __align__(16) float sQt[EE];
  __shared__ __align__(16) float sScal[16];

  float* sYT = uni2;
  float* sGk = uni3;
  float* sYk = uni1;

  const int tid = threadIdx.x, ln = tid & 63;
  const int mr = (tid >> 2) & 127, mq = tid & 3;  // M-group matvec mapping (tid<512)
  const int b = blockIdx.x;

  float areg[32];
  if (tid < 512) {
    const float4* a4 = (const float4*)(Ainv0 + mr * KK + 32 * mq);
#pragma unroll
    for (int u = 0; u < 8; u++) {
      const float4 t4 = a4[u];
      areg[4 * u] = t4.x; areg[4 * u + 1] = t4.y; areg[4 * u + 2] = t4.z; areg[4 * u + 3] = t4.w;
    }
  }
  {
    const float* Pb = Pg + (size_t)b * KK * EE;
#pragma unroll
    for (int i = 0; i < 4; i++) {
      const int idx = tid + 1024 * i;                 // idx = k*32 + e
      sPT[(idx & 31) * PTS + (idx >> 5)] = Pb[idx];   // transpose into [e][k]
    }
    const float* Sb = Sg + (size_t)b * 4096;
    sS[(tid >> 5) * L36 + (tid & 31)] =
        Sb[tid] + Sb[tid + 1024] + Sb[tid + 2048] + Sb[tid + 3072];
  }
  if (tid < 16) sScal[tid] = 0.0f;
  const float v0 = scaleP[0] + V0EPS;
  __syncthreads();
  if (tid < 512) {  // w0 = Ainv0 * P[:,0]
    const float* xb = sPT + 32 * mq;
    float s = 0;
#pragma unroll
    for (int c = 0; c < 32; c++) s += areg[c] * xb[c];
    s += __shfl_xor(s, 1, 64); s += __shfl_xor(s, 2, 64);
    if (mq == 0) sW[SEG(mr)] = s;
  }
  __syncthreads();

#pragma unroll 1
  for (int t = 0; t < EE; ++t) {
    const bool hn = (t + 1 < EE);
    // ---- PH1: M: Pm = Ainv w | X: dgw = G^T w ; qt = Y^T w ; S2 ----
    if (tid < 512) {
      const float* xb = sW + 40 * mq;
      float s = 0;
#pragma unroll
      for (int c = 0; c < 16; c++) s += areg[c] * xb[c];
#pragma unroll
      for (int c = 0; c < 16; c++) s += areg[16 + c] * xb[20 + c];
      s += __shfl_xor(s, 1, 64); s += __shfl_xor(s, 2, 64);
      if (mq == 0) sPm[SEG(mr)] = s;
    } else if (tid < 768) {  // waves 8-11: dgw + S2
      const int s8 = (tid - 512) >> 3, p3 = tid & 7;
      if (s8 < t) {
        const float* gr = sGT + s8 * LTR + 16 * p3;
        const float* wr_ = sW + 20 * p3;
        float s = 0;
#pragma unroll
        for (int kk = 0; kk < 16; kk++) s += gr[kk] * wr_[kk];
        s += __shfl_xor(s, 1, 64); s += __shfl_xor(s, 2, 64); s += __shfl_xor(s, 4, 64);
        if (p3 == 0) sDgw[s8] = s;
      } else if (s8 == 31) {  // s8==31 never used by dgw: S2 here
        const float* wp = sW + 20 * p3;
        float s = 0;
#pragma unroll
        for (int kk = 0; kk < 16; kk++) s += wp[kk] * wp[kk];
        s += __shfl_xor(s, 1, 64); s += __shfl_xor(s, 2, 64); s += __shfl_xor(s, 4, 64);
        if (p3 == 0) sScal[SC_S2] = s;
      }
    } else {  // waves 12-15: qt
      const int j = (tid - 768) >> 3, p3 = tid & 7;
      if (j < t) {
        const float* yr = sYT + j * LTR + 16 * p3;
        const float* wr_ = sW + 20 * p3;
        float s = 0;
#pragma unroll
        for (int kk = 0; kk < 16; kk++) s += yr[kk] * wr_[kk];
        s += __shfl_xor(s, 1, 64); s += __shfl_xor(s, 2, 64); s += __shfl_xor(s, 4, 64);
        if (p3 == 0) sQt[j] = s;
      }
    }
    __syncthreads();
    // ---- PH2: wU ; D_t(parallel) ; R22 ; sigma/KL ; Egg_t ; dz[s<t] ----
    if (tid < 256) {  // waves 0-3: wU[k] = v0 w[k] - sum_{j<t} Y[k][j] qt[j]
      const int k = tid >> 1, h = tid & 1;
      const float* yk = sYk + k * LKM + 16 * h;
      const float* qb = sQt + 16 * h;
      float a = 0;
#pragma unroll
      for (int u = 0; u < 16; u++) {
        const int j = 16 * h + u;
        a += (j < t) ? yk[u] * qb[u] : 0.0f;
      }
      a += __shfl_xor(a, 1, 64);
      if (h == 0) sWU[SEG(k)] = v0 * sW[SEG(k)] - a;
    } else if (tid < 384) {  // waves 4-5: D append, 4 threads per r2
      const int r2 = (tid - 256) >> 2, p = tid & 3;
      float a = 0;
#pragma unroll
      for (int u = 0; u < 8; u++) {
        const int s2 = p + 4 * u;
        a += (s2 < t) ? sDgw[s2] * sD[s2 * L36 + r2] : 0.0f;
      }
      a += __shfl_xor(a, 1, 64); a += __shfl_xor(a, 2, 64);
      if (p == 0) sD[t * L36 + r2] = ((r2 == t) ? 1.0f : 0.0f) - a;
    } else if (tid < 448) {  // wave 6: R22 = w.Pm
      float a = sW[SEG(ln)] * sPm[SEG(ln)] + sW[SEG(ln + 64)] * sPm[SEG(ln + 64)];
      a = wsum64(a);
      if (ln == 0) sScal[SC_R22] = a;
    } else if (tid < 512) {  // wave 7: sigma ; KL
      const float s2v = sScal[SC_S2];
      float a = (ln < t) ? sQt[ln] * sQt[ln] : 0.0f;
      a = wsum64(a);
      if (ln == 0) {
        sScal[SC_SIG] = v0 * s2v - a + 1.0f;
        sScal[SC_KL] += s2v;
      }
    } else if (tid < 640) {  // waves 8-9: Egg append (k-major recurrence)
      const int k = tid - 512;
      float a = sW[SEG(k)];
      const float* ek = sEk + k * LKM;
      const int nc = (t + 3) >> 2;
#pragma unroll 1
      for (int c4 = 0; c4 < nc; ++c4) {
        const float4 ev = *(const float4*)(ek + 4 * c4);
        const float4 dv = *(const float4*)(sDgw + 4 * c4);
        const int u0 = 4 * c4;
        a -= ((u0 + 0 < t) ? ev.x * dv.x : 0.0f) + ((u0 + 1 < t) ? ev.y * dv.y : 0.0f) +
             ((u0 + 2 < t) ? ev.z * dv.z : 0.0f) + ((u0 + 3 < t) ? ev.w * dv.w : 0.0f);
      }
      sEk[k * LKM + t] = a;
      sEggT[t * LTR + k] = a;
    } else if (tid < 896) {  // waves 10-13: dz[s4] for s4 < t (rows < t all exist)
      const int s4 = (tid - 640) >> 3, p3 = tid & 7;
      if (hn && s4 < t) {
        const float* er = sEggT + s4 * LTR + 16 * p3;
        const float* pr = sPT + (t + 1) * PTS + 16 * p3;
        float a = 0;
#pragma unroll
        for (int kk = 0; kk < 16; kk++) a -= er[kk] * pr[kk];
        const float4 dv = *(const float4*)(sD + s4 * L36 + 4 * p3);
        const float4 sv = *(const float4*)(sS + (t + 1) * L36 + 4 * p3);  // S symmetric
        a += dot4(dv, sv);
        a += __shfl_xor(a, 1, 64); a += __shfl_xor(a, 2, 64); a += __shfl_xor(a, 4, 64);
        if (p3 == 0) sDz[s4] = a;
      }
    }
    __syncthreads();
    // ---- PH3: M: Pu = Ainv wU | X: dz[t] ; B2 ; B1+R12 ; G/Y appends ----
    if (tid < 512) {
      const float* xb = sWU + 40 * mq;
      float s = 0;
#pragma unroll
      for (int c = 0; c < 16; c++) s += areg[c] * xb[c];
#pragma unroll
      for (int c = 0; c < 16; c++) s += areg[16 + c] * xb[20 + c];
      s += __shfl_xor(s, 1, 64); s += __shfl_xor(s, 2, 64);
      if (mq == 0) sPu[SEG(mr)] = s;
    } else if (tid < 576) {  // wave 8: dz[t] = D[t,:].S[:,t+1] - Egg[t,:].P[:,t+1]
      if (hn) {
        float a = -(sEggT[t * LTR + ln] * sPT[(t + 1) * PTS + ln] +
                    sEggT[t * LTR + ln + 64] * sPT[(t + 1) * PTS + ln + 64]);
        if (ln < 32) a += sD[t * L36 + ln] * sS[(t + 1) * L36 + ln];
        a = wsum64(a);
        if (ln == 0) sDz[t] = a;
      }
    } else if (tid < 640) {  // wave 9: B2 = Egg_t . P[:,t]
      float a = sEggT[t * LTR + ln] * sPT[t * PTS + ln] +
                sEggT[t * LTR + ln + 64] * sPT[t * PTS + ln + 64];
      a = wsum64(a);
      if (ln == 0) sScal[SC_B2] = a;
    } else if (tid < 704) {  // wave 10: lanes<32: B1 ; lanes>=32: R12 = wU.Pm
      if (ln < 32) {
        float a = sD[t * L36 + ln] * sS[t * L36 + ln];
        a = wsum32(a);
        if (ln == 0) sScal[SC_B1] = a;
      } else {
        const int k0 = (ln - 32) * 4;
        const float4 wu4 = *(const float4*)(sWU + SEG(k0));
        const float4 pm4 = *(const float4*)(sPm + SEG(k0));
        float a = dot4(wu4, pm4);
        a = wsum32(a);
        if (ln == 32) sScal[SC_R12] = a;
      }
    } else if (tid < 768) {  // wave 11: G/Y appends (both layouts)
      const float sig = sScal[SC_SIG];
      const float rsq = rsqrtf(sig);
#pragma unroll
      for (int u = 0; u < 2; u++) {
        const int k = ln + 64 * u;
        const float wu = sWU[SEG(k)];
        const float gv = wu / sig;
        const float yv = wu * rsq;
        sGT[t * LTR + k] = gv;
        sGk[k * LKM + t] = gv;
        sYT[t * LTR + k] = yv;
        sYk[k * LKM + t] = yv;
      }
    }
    __syncthreads();
    // ---- PH4: M: q_next | X: R11 ----
    if (tid < 512) {
      if (hn) {
        const float* gk = sGk + mr * LKM + 8 * mq;
        const float* dzb = sDz + 8 * mq;
        float a = 0;
#pragma unroll
        for (int u = 0; u < 8; u++) {
          const int s2 = 8 * mq + u;
          a += (s2 < t) ? gk[u] * dzb[u] : 0.0f;
        }
        a += __shfl_xor(a, 1, 64); a += __shfl_xor(a, 2, 64);
        if (mq == 0)
          sQ[SEG(mr)] = sPT[(t + 1) * PTS + mr] + a + (sWU[SEG(mr)] / sScal[SC_SIG]) * sDz[t];
      }
    } else if (tid < 576) {  // wave 8: R11 = wU . Pu
      float a = sWU[SEG(ln)] * sPu[SEG(ln)] + sWU[SEG(ln + 64)] * sPu[SEG(ln + 64)];
      a = wsum64(a);
      if (ln == 0) sScal[SC_R11] = a;
    }
    __syncthreads();
    // ---- PH5: M: Ainv rank-2 update + w_next ----
    if (tid < 512) {
      {
        const float4 sc0 = *(const float4*)(sScal);      // S2, SIG, KL, B1
        const float4 sc1 = *(const float4*)(sScal + 4);  // B2, R11, R12, R22
        const float rs = 1.0f / sc0.y;
        const float beta = sc0.w - sc1.x - sc0.x;
        const float e11 = sc1.y * rs * rs;
        const float e12 = sc1.z * rs + 1.0f;
        const float e22 = sc1.w - beta;
        const float rd = 1.0f / (e11 * e22 - e12 * e12);
        const float t11 = e22 * rd, t12 = -e12 * rd, t22 = e11 * rd;
        const float u1r = sPu[SEG(mr)] * rs, u2r = sPm[SEG(mr)];
        const float* pub = sPu + 40 * mq;
        const float* pmb = sPm + 40 * mq;
#pragma unroll
        for (int c = 0; c < 16; c++) {
          const float u1c = pub[c] * rs;
          const float u2c = pmb[c];
          areg[c] -= u1r * (t11 * u1c + t12 * u2c) + u2r * (t12 * u1c + t22 * u2c);
        }
#pragma unroll
        for (int c = 0; c < 16; c++) {
          const float u1c = pub[20 + c] * rs;
          const float u2c = pmb[20 + c];
          areg[16 + c] -= u1r * (t11 * u1c + t12 * u2c) + u2r * (t12 * u1c + t22 * u2c);
        }
      }
      if (hn) {
        const float* xb = sQ + 40 * mq;
        float s = 0;
#pragma unroll
        for (int c = 0; c < 16; c++) s += areg[c] * xb[c];
#pragma unroll
        for (int c = 0; c < 16; c++) s += areg[16 + c] * xb[20 + c];
        s += __shfl_xor(s, 1, 64); s += __shfl_xor(s, 2, 64);
        if (mq == 0) sW[SEG(mr)] = s;
      }
    }
    __syncthreads();
  }

  // ================= fused postA =================
  float* sR1T  = uni2;         // [32][36]  (over dead sYT)
  float* sGamT = uni2 + 1152;  // [32][36]
  float* sRhsT = uni1;         // [32][132] (over dead sYk)
  float* sWrT  = uni3;         // [32][132] (over sGk -- dead after PA1)
  if (tid == 0) wsKL[b] = sScal[SC_KL];

  // ---- PA0: R1T[e][s] = D[s,:].S[e,:] - EggT[s,:].PT[e,:] ----
  {
    const int s = tid >> 5, e = tid & 31;
    const float4* er = (const float4*)(sEggT + s * LTR);
    const float4* pr = (const float4*)(sPT + e * PTS);
    float a = 0;
#pragma unroll 8
    for (int u = 0; u < 32; ++u) a -= dot4(er[u], pr[u]);
    const float4* dr = (const float4*)(sD + s * L36);
    const float4* sr = (const float4*)(sS + e * L36);
#pragma unroll
    for (int u = 0; u < 8; ++u) a += dot4(dr[u], sr[u]);
    sR1T[e * 36 + s] = a;
  }
  __syncthreads();
  // ---- PA1: RhsT[e][k] = PT[e][k] + sum_s G[k][s] R1T[e][s] ----
  {
    const int k = tid & 127, e8 = tid >> 7;
    float4 g0, g1, g2, g3, g4, g5, g6, g7;
    {
      const float4* gk = (const float4*)(sGk + k * LKM);
      g0 = gk[0]; g1 = gk[1]; g2 = gk[2]; g3 = gk[3];
      g4 = gk[4]; g5 = gk[5]; g6 = gk[6]; g7 = gk[7];
    }
#pragma unroll
    for (int u = 0; u < 4; ++u) {
      const int e = e8 * 4 + u;
      const float4* r1 = (const float4*)(sR1T + e * 36);
      float a = sPT[e * PTS + k];
      a += dot4(g0, r1[0]) + dot4(g1, r1[1]) + dot4(g2, r1[2]) + dot4(g3, r1[3]);
      a += dot4(g4, r1[4]) + dot4(g5, r1[5]) + dot4(g6, r1[6]) + dot4(g7, r1[7]);
      sRhsT[e * PTS + k] = a;
    }
  }
  __syncthreads();
  // ---- PA2: WrT[e][k] = AinvP . rhs[:,e]  (areg matvec, 32 episodes, M-group) ----
  if (tid < 512) {
#pragma unroll 2
    for (int e = 0; e < EE; ++e) {
      const float* xb = sRhsT + e * PTS + 32 * mq;
      float s = 0;
#pragma unroll
      for (int c = 0; c < 32; c++) s += areg[c] * xb[c];
      s += __shfl_xor(s, 1, 64); s += __shfl_xor(s, 2, 64);
      if (mq == 0) sWrT[e * PTS + mr] = s;
    }
  }
  __syncthreads();
  // ---- PA3: GamT[e][s] = GT[s,:].WrT[e,:] ----
  {
    const int s = tid >> 5, e = tid & 31;
    const float4* gr = (const float4*)(sGT + s * LTR);
    const float4* wr = (const float4*)(sWrT + e * PTS);
    float a = 0;
#pragma unroll 8
    for (int u = 0; u < 32; ++u) a += dot4(gr[u], wr[u]);
    sGamT[e * 36 + s] = a;
  }
  __syncthreads();
  // ---- PA4: Wc -> wsWt rows 0..127 ; Vc -> rows 128..159 ; KLr ----
  {
    const int k = tid & 127, e8 = tid >> 7;
    float4 E0, E1, E2, E3, E4, E5, E6, E7;
    {
      const float4* ek = (const float4*)(sEk + k * LKM);
      E0 = ek[0]; E1 = ek[1]; E2 = ek[2]; E3 = ek[3];
      E4 = ek[4]; E5 = ek[5]; E6 = ek[6]; E7 = ek[7];
    }
#pragma unroll
    for (int u = 0; u < 4; ++u) {
      const int e = e8 * 4 + u;
      const float4* gm = (const float4*)(sGamT + e * 36);
      float a = sWrT[e * PTS + k];
      a -= dot4(E0, gm[0]) + dot4(E1, gm[1]) + dot4(E2, gm[2]) + dot4(E3, gm[3]);
      a -= dot4(E4, gm[4]) + dot4(E5, gm[5]) + dot4(E6, gm[6]) + dot4(E7, gm[7]);
      wsWt[(size_t)b * 5120 + e * 160 + k] = a;
    }
  }
  {  // Vc[e][sp] = sum_f D[f][sp] * GamT[e][f]
    const int e = tid & 31, sp = tid >> 5;  // sp 0..31
    float4 gm[8];
    {
      const float4* g4 = (const float4*)(sGamT + e * 36);
#pragma unroll
      for (int u = 0; u < 8; ++u) gm[u] = g4[u];
    }
    float a = 0;
#pragma unroll
    for (int u = 0; u < 8; ++u) {
      const float4 g = gm[u];
      a += sD[(4 * u + 0) * L36 + sp] * g.x + sD[(4 * u + 1) * L36 + sp] * g.y +
           sD[(4 * u + 2) * L36 + sp] * g.z + sD[(4 * u + 3) * L36 + sp] * g.w;
    }
    wsWt[(size_t)b * 5120 + e * 160 + 128 + sp] = a;
  }
  {  // KLr[e] = sum_k Wr[k][e]^2
    const int e = tid >> 5, p = tid & 31;
    const float4 w0 = *(const float4*)(sWrT + e * PTS + 4 * p);
    float a = dot4(w0, w0);
    a = wsum32(a);
    if ((tid & 31) == 0) wsKLr[b * EE + e] = a;
  }
}

// ---------------- Kernel 4: postB (256 WGs) + final (block 256) ----------------
__global__ __launch_bounds__(512) void postBF_kernel(
    const float* __restrict__ wsWt, const float* __restrict__ x,
    const float* __restrict__ M0, const float* __restrict__ znoise,
    const float* __restrict__ wsKL, const float* __restrict__ wsKLr,
    const float* __restrict__ lwsP, float* __restrict__ out) {
  __shared__ __align__(16) float sWtT[32 * LWT];   // Wt^T : [e][row], stride 176
  __shared__ __align__(16) float Mch[2 * 16 * 132];
  const int tid = threadIdx.x;

  if (blockIdx.x == 256) {
    // ======== final: total divergence ========
    float* sPp = sWtT;  // reuse
    float s = 0.0f;
    if (tid < 64) s += wsKL[tid];
    for (int i = tid; i < 2048; i += 512) s += wsKLr[i];
    sPp[tid] = s;
    __syncthreads();
    for (int off = 256; off > 0; off >>= 1) {
      if (tid < off) sPp[tid] += sPp[tid + off];
      __syncthreads();
    }
    if (tid == 0) {
      const float lws = lwsP[0];
      const float sw2 = expf(2.0f * lws);
      out[(size_t)BB * EE * CC] =
          0.5f * sPp[0] / (float)(EE * BB) + (float)KK * (sw2 - 1.0f - 2.0f * lws);
    }
    return;
  }

  const int b = blockIdx.x >> 2, cq = blockIdx.x & 3;
  {
    // wsWt is [b][e][160]: direct (no transpose) load
    const int e = tid >> 4, j = tid & 15;
    const float* Wg = wsWt + (size_t)b * 5120 + e * 160;
#pragma unroll
    for (int u = 0; u < 10; ++u) sWtT[e * LWT + j + 16 * u] = Wg[j + 16 * u];
  }
  const int srow = tid >> 5, sc4 = tid & 31;  // stage: 16 rows x 32 float4 (128 cols)
  const int e = tid & 31, cs = tid >> 5;      // compute: episode e, col-octet cs
  const float* xb = x + (size_t)b * EE * CC;
  const int cbase = cq * 128;
  float4 st = *(const float4*)(M0 + srow * CC + cbase + 4 * sc4);  // ch2=0 rows are all M0
  float acc[8];
#pragma unroll
  for (int u = 0; u < 8; u++) acc[u] = 0.0f;
  int buf = 0;
#pragma unroll 1
  for (int ch2 = 0; ch2 < 10; ++ch2) {
    *(float4*)(Mch + buf * 2112 + srow * 132 + 4 * sc4) = st;
    __syncthreads();
    if (ch2 + 1 < 10) {
      const int row = (ch2 + 1) * 16 + srow;
      st = (row < 128) ? *(const float4*)(M0 + row * CC + cbase + 4 * sc4)
                       : *(const float4*)(xb + (row - 128) * CC + cbase + 4 * sc4);
    }
    const float4* wt4 = (const float4*)(sWtT + e * LWT + ch2 * 16);
    const float4 wa = wt4[0], wb = wt4[1], wc = wt4[2], wd = wt4[3];
    const float wv16[16] = {wa.x, wa.y, wa.z, wa.w, wb.x, wb.y, wb.z, wb.w,
                            wc.x, wc.y, wc.z, wc.w, wd.x, wd.y, wd.z, wd.w};
#pragma unroll
    for (int kk = 0; kk < 16; ++kk) {
      const float* mrp = Mch + buf * 2112 + kk * 132 + cs * 8;
      const float4 m0 = *(const float4*)(mrp);
      const float4 m1 = *(const float4*)(mrp + 4);
      const float wk = wv16[kk];
      acc[0] += wk * m0.x; acc[1] += wk * m0.y; acc[2] += wk * m0.z; acc[3] += wk * m0.w;
      acc[4] += wk * m1.x; acc[5] += wk * m1.y; acc[6] += wk * m1.z; acc[7] += wk * m1.w;
    }
    buf ^= 1;
  }
  {
    const size_t ob = ((size_t)b * EE + e) * CC + cbase + cs * 8;
    const size_t nb = ((size_t)e * BB + b) * CC + cbase + cs * 8;
#pragma unroll
    for (int u = 0; u < 2; u++) {
      const float4 nz = *(const float4*)(znoise + nb + 4 * u);
      float4 o;
      o.x = acc[4 * u] + nz.x;     o.y = acc[4 * u + 1] + nz.y;
      o.z = acc[4 * u + 2] + nz.z; o.w = acc[4 * u + 3] + nz.w;
      *(float4*)(out + ob + 4 * u) = o;
    }
  }
}

extern "C" void kernel_launch(void* const* d_in, const int* in_sizes, int n_in,
                              void* d_out, int out_size, void* d_ws, size_t ws_size,
                              hipStream_t stream) {
  (void)in_sizes; (void)n_in; (void)out_size; (void)ws_size;
  const float* x = (const float*)d_in[0];        // [B,E,C]
  const float* M0 = (const float*)d_in[1];       // [K,C]
  const float* scaleP = (const float*)d_in[2];   // scalar
  const float* lwsP = (const float*)d_in[3];     // scalar
  const float* znoise = (const float*)d_in[4];   // [E,B,C]
  float* out = (float*)d_out;

  float* ws = (float*)d_ws;
  float* wsP = ws;                        // 262144
  float* wsSp = wsP + 262144;             // 262144 (64 x 4 partials x 1024)
  float* wsA0 = wsSp + 262144;            // 16384
  float* wsAinv0 = wsA0 + 16384;          // 16384
  float* wsKL = wsAinv0 + 16384;          // 64
  float* wsKLr = wsKL + 64;               // 2048
  float* wsWt = wsKLr + 2048;             // 327680 (64 x 32 x 160, [b][e][row])

  a0_kernel<<<256, 256, 0, stream>>>(M0, wsA0);
  psinv_kernel<<<257, 1024, 0, stream>>>(x, M0, wsP, wsSp, wsA0, wsAinv0);
  scan_kernel<<<BB, 1024, 0, stream>>>(wsP, wsSp, scaleP, wsAinv0,
                                       wsKL, wsKLr, wsWt);
  postBF_kernel<<<257, 512, 0, stream>>>(wsWt, x, M0, znoise, wsKL, wsKLr, lwsP, out);
}

// Round 7
// 268.489 us; speedup vs baseline: 1.4163x; 1.0090x over previous
//
#include <hip/hip_runtime.h>

// (B,E,K,C) = (64,32,128,512), fp32.
#define BB 64
#define EE 32
#define KK 128
#define CC 512
#define V0EPS 1e-7f

#define LTR 132   // [32][132] padded stride
#define PTS 132   // scan: P^T / RhsT / WrT row stride
#define LKM 36    // scan: k-major row stride (G/Y/Egg)
#define L36 36    // scan: S/D row stride
#define LWT 176   // postB: Wt^T row stride
// segment-padded K-vector layout: element i lives at (i/16)*20 + (i%16)
#define SEG(i) ((((i) >> 4) * 20) + ((i) & 15))

// scan sScal slots (order matters: read as two float4s in PH5)
#define SC_S2  0
#define SC_SIG 1
#define SC_KL  2
#define SC_B1  3
#define SC_B2  4
#define SC_R11 5
#define SC_R12 6
#define SC_R22 7

__device__ __forceinline__ float wsum64(float v) {
#pragma unroll
  for (int m = 32; m >= 1; m >>= 1) v += __shfl_xor(v, m, 64);
  return v;
}

__device__ __forceinline__ float wsum32(float v) {  // reduce within aligned 32-lane half
#pragma unroll
  for (int m = 16; m >= 1; m >>= 1) v += __shfl_xor(v, m, 64);
  return v;
}

__device__ __forceinline__ float dot4(const float4 a, const float4 b) {
  return a.x * b.x + a.y * b.y + a.z * b.z + a.w * b.w;
}

// ---------------- Kernel 1: A0 = M0 M0^T + I (512 WGs: k x l-quarter) ----------------
__global__ __launch_bounds__(256) void a0_kernel(const float* __restrict__ M0,
                                                 float* __restrict__ wsA0) {
  __shared__ __align__(16) float sRow[CC];
  const int k = blockIdx.x >> 2, quarter = blockIdx.x & 3;
  for (int c = threadIdx.x; c < CC; c += 256) sRow[c] = M0[k * CC + c];
  __syncthreads();
  const int wv = threadIdx.x >> 6, ln = threadIdx.x & 63;
  const float4* zr = (const float4*)(sRow + 8 * ln);
  const float4 z0 = zr[0], z1 = zr[1];
  for (int li = 0; li < 8; ++li) {
    const int l = quarter * 32 + wv * 8 + li;
    const float4* rp = (const float4*)(M0 + l * CC + 8 * ln);
    const float4 a = rp[0], b = rp[1];
    float s = dot4(a, z0) + dot4(b, z1);
    s = wsum64(s);
    if (ln == 0) wsA0[k * KK + l] = s + (l == k ? 1.0f : 0.0f);
  }
}

// ------- Kernel 2: block 0 -> inv(A0) via 2-pivot GJ ; blocks 1..256 -> P/S partials -------
__global__ __launch_bounds__(1024) void psinv_kernel(const float* __restrict__ x,
                                                     const float* __restrict__ M0,
                                                     float* __restrict__ wsP,
                                                     float* __restrict__ wsSp,
                                                     const float* __restrict__ A0g,
                                                     float* __restrict__ Ainv0) {
  __shared__ __align__(16) float zAll[32][520];
  __shared__ __align__(16) float Mch[2][16][520];
  __shared__ __align__(16) float sFb[2][2][128];   // [buf][col j / j+1][row]
  __shared__ __align__(16) float sPv[2][2][256];   // [buf][row j / j+1][A-part 128 | I-part 128]
  const int tid = threadIdx.x;

  if (blockIdx.x > 0) {
    // ================= ps body: P rows kq*32..kq*32+31 ; S partial over c-quarter =================
    const int b = (blockIdx.x - 1) >> 2, kq = (blockIdx.x - 1) & 3;
    {
      const float4* x4 = (const float4*)(x + (size_t)b * EE * CC);
#pragma unroll
      for (int i = 0; i < 4; i++) {
        const int F = tid + 1024 * i, e = F >> 7, c4 = F & 127;
        ((float4*)zAll[e])[c4] = x4[F];
      }
    }
    const float4* M4 = (const float4*)M0;
    const int srow = tid >> 7, sc4 = tid & 127;
    const int kbase = kq * 32;
    float4 st0 = M4[(kbase + srow) * 128 + sc4];
    float4 st1 = M4[(kbase + 8 + srow) * 128 + sc4];
    int buf = 0;
    const int p = tid & 7;           // 8 threads per dot
    const int ep = (tid >> 3) & 15;  // episodes 2*ep, 2*ep+1  (0..31)
    const int kp = tid >> 7;         // k rows kp, kp+8
#pragma unroll 1
    for (int kc = 0; kc < 2; ++kc) {
      ((float4*)Mch[buf][srow])[sc4] = st0;
      ((float4*)Mch[buf][8 + srow])[sc4] = st1;
      __syncthreads();
      if (kc == 0) {
        st0 = M4[(kbase + 16 + srow) * 128 + sc4];
        st1 = M4[(kbase + 24 + srow) * 128 + sc4];
      }
      float s00 = 0, s01 = 0, s10 = 0, s11 = 0;
      const float* m0 = Mch[buf][kp];
      const float* m1 = Mch[buf][kp + 8];
      const float* z0 = zAll[2 * ep];
      const float* z1 = zAll[2 * ep + 1];
#pragma unroll
      for (int u = 0; u < 16; u++) {
        const int c = 4 * p + 32 * u;
        const float4 a0 = *(const float4*)(m0 + c);
        const float4 a1 = *(const float4*)(m1 + c);
        const float4 b0 = *(const float4*)(z0 + c);
        const float4 b1 = *(const float4*)(z1 + c);
        s00 += dot4(a0, b0); s01 += dot4(a0, b1);
        s10 += dot4(a1, b0); s11 += dot4(a1, b1);
      }
#pragma unroll
      for (int m = 1; m <= 4; m <<= 1) {
        s00 += __shfl_xor(s00, m, 64); s01 += __shfl_xor(s01, m, 64);
        s10 += __shfl_xor(s10, m, 64); s11 += __shfl_xor(s11, m, 64);
      }
      if (p == 0) {
        float* Pb = wsP + (size_t)b * KK * EE;
        Pb[(kbase + kc * 16 + kp) * EE + 2 * ep] = s00;
        Pb[(kbase + kc * 16 + kp) * EE + 2 * ep + 1] = s01;
        Pb[(kbase + kc * 16 + kp + 8) * EE + 2 * ep] = s10;
        Pb[(kbase + kc * 16 + kp + 8) * EE + 2 * ep + 1] = s11;
      }
      buf ^= 1;
    }
    // S partial = Z[:, cq] Z[:, cq]^T
    {
      const int e = tid >> 5, f = tid & 31;
      const float4* ze = ((const float4*)zAll[e]) + 32 * kq;
      const float4* zf = ((const float4*)zAll[f]) + 32 * kq;
      float a0 = 0, a1 = 0, a2 = 0, a3 = 0;
#pragma unroll 4
      for (int u = 0; u < 32; u++) {
        const float4 A = ze[u], Bq = zf[u];
        a0 += A.x * Bq.x; a1 += A.y * Bq.y; a2 += A.z * Bq.z; a3 += A.w * Bq.w;
      }
      wsSp[((size_t)b * 4 + kq) * 1024 + e * EE + f] = (a0 + a1) + (a2 + a3);
    }
  } else {
    // ======== inv0 body (block 0): 2-pivot register GJ, 64 super-iterations ========
    const int r = tid >> 3, q = tid & 7;
    float wreg[16], vreg[16];
    {
      const float4* a4 = (const float4*)(A0g + r * KK + 16 * q);
#pragma unroll
      for (int u = 0; u < 4; u++) {
        const float4 t4 = a4[u];
        wreg[4 * u] = t4.x; wreg[4 * u + 1] = t4.y; wreg[4 * u + 2] = t4.z; wreg[4 * u + 3] = t4.w;
      }
#pragma unroll
      for (int c = 0; c < 16; c++) vreg[c] = (16 * q + c == r) ? 1.0f : 0.0f;
    }
    // prologue: stage cols 0,1 and rows 0,1
    if (q == 0) { sFb[0][0][r] = wreg[0]; sFb[0][1][r] = wreg[1]; }
    if (r == 0) {
#pragma unroll
      for (int c = 0; c < 16; c++) { sPv[0][0][16 * q + c] = wreg[c]; sPv[0][0][128 + 16 * q + c] = vreg[c]; }
    }
    if (r == 1) {
#pragma unroll
      for (int c = 0; c < 16; c++) { sPv[0][1][16 * q + c] = wreg[c]; sPv[0][1][128 + 16 * q + c] = vreg[c]; }
    }
    __syncthreads();
#pragma unroll 1
    for (int jj = 0; jj < 64; ++jj) {
      const int j = 2 * jj, db = jj & 1, dn = db ^ 1;
      const float* c0 = sFb[db][0];
      const float* c1 = sFb[db][1];
      const float* rj = sPv[db][0];
      const float* rj1 = sPv[db][1];
      const float p00 = c0[j], p10 = c0[j + 1], p01 = c1[j], p11 = c1[j + 1];
      const float rp00 = 1.0f / p00;
      const float g = p10 * rp00;
      const float rp11 = 1.0f / (p11 - g * p01);
      const float alpha = (r == j) ? 0.0f : c0[r] * rp00;
      const float beta = (r == j + 1) ? 0.0f : (c1[r] - alpha * p01) * rp11;
      const float ca = alpha - beta * g, cb = beta;
      if (16 * q + 15 >= j) {  // A-part: only cols >= j are touched
        const float4* w0 = (const float4*)(rj + 16 * q);
        const float4* w1 = (const float4*)(rj1 + 16 * q);
#pragma unroll
        for (int u = 0; u < 4; u++) {
          const float4 a0 = w0[u], a1 = w1[u];
          wreg[4 * u]     -= ca * a0.x + cb * a1.x;
          wreg[4 * u + 1] -= ca * a0.y + cb * a1.y;
          wreg[4 * u + 2] -= ca * a0.z + cb * a1.z;
          wreg[4 * u + 3] -= ca * a0.w + cb * a1.w;
        }
      }
      if (16 * q <= j + 1) {  // I-part: rows j/j+1 nonzero only in cols <= j+1
        const float4* v0 = (const float4*)(rj + 128 + 16 * q);
        const float4* v1 = (const float4*)(rj1 + 128 + 16 * q);
#pragma unroll
        for (int u = 0; u < 4; u++) {
          const float4 a0 = v0[u], a1 = v1[u];
          vreg[4 * u]     -= ca * a0.x + cb * a1.x;
          vreg[4 * u + 1] -= ca * a0.y + cb * a1.y;
          vreg[4 * u + 2] -= ca * a0.z + cb * a1.z;
          vreg[4 * u + 3] -= ca * a0.w + cb * a1.w;
        }
      }
      if (jj + 1 < 64) {  // stage cols/rows j+2, j+3 (post-update values)
        const int j2 = j + 2, j3 = j + 3;
        float w2 = 0.0f, w3 = 0.0f;
#pragma unroll
        for (int c = 0; c < 16; c++) {
          if (c == (j2 & 15)) w2 = wreg[c];
          if (c == (j3 & 15)) w3 = wreg[c];
        }
        if (q == (j2 >> 4)) sFb[dn][0][r] = w2;
        if (q == (j3 >> 4)) sFb[dn][1][r] = w3;
        if (r == j2) {
#pragma unroll
          for (int c = 0; c < 16; c++) { sPv[dn][0][16 * q + c] = wreg[c]; sPv[dn][0][128 + 16 * q + c] = vreg[c]; }
        }
        if (r == j3) {
#pragma unroll
          for (int c = 0; c < 16; c++) { sPv[dn][1][16 * q + c] = wreg[c]; sPv[dn][1][128 + 16 * q + c] = vreg[c]; }
        }
      }
      __syncthreads();
    }
    {
      float dval = 0.0f;
#pragma unroll
      for (int c = 0; c < 16; c++) if (c == (r & 15)) dval = wreg[c];
      if (q == (r >> 4)) sFb[0][0][r] = dval;
    }
    __syncthreads();
    {
      const float sc = 1.0f / sFb[0][0][r];
      float4* o4 = (float4*)(Ainv0 + r * KK + 16 * q);
#pragma unroll
      for (int u = 0; u < 4; u++) {
        float4 o;
        o.x = vreg[4 * u] * sc; o.y = vreg[4 * u + 1] * sc;
        o.z = vreg[4 * u + 2] * sc; o.w = vreg[4 * u + 3] * sc;
        o4[u] = o;
      }
    }
  }
}

// ---------------- Kernel 3: scan + fused postA, 512 threads, one WG per batch ----------------
// (reverted to R4's verified 8-wave version: DS-pipe-bound phases, fewer waves behind
//  each barrier; postA fused with AinvP in areg and b128-friendly LDS layouts.)
__global__ __launch_bounds__(512) void scan_kernel(
    const float* __restrict__ Pg, const float* __restrict__ Sg,  // Sg = 4 partials per batch
    const float* __restrict__ scaleP, const float* __restrict__ Ainv0,
    float* __restrict__ wsKL, float* __restrict__ wsKLr, float* __restrict__ wsWt) {
  __shared__ __align__(16) float sPT[EE * PTS];    // P^T : [e][k]
  __shared__ __align__(16) float sGT[EE * LTR];    // G^T : [t][k]
  __shared__ __align__(16) float sEggT[EE * LTR];  // Egg^T : [t][k]
  __shared__ __align__(16) float uni2[EE * LTR];   // scan: Y^T [t][k] | postA: R1T + GamT
  __shared__ __align__(16) float uni3[KK * LKM];   // scan: G [k][t]  | postA: WrT [e][k]
  __shared__ __align__(16) float uni1[KK * LKM];   // scan: Y [k][j]  | postA: RhsT [e][k]
  __shared__ __align__(16) float sEk[KK * LKM];    // Egg: [k][s]
  __shared__ __align__(16) float sS[EE * L36];     // S (symmetric)
  __shared__ __align__(16) float sD[EE * L36];     // D : [s][r2]
  __shared__ __align__(16) float sW[160];
  __shared__ __align__(16) float sWU[160];
  __shared__ __align__(16) float sPu[160];
  __shared__ __align__(16) float sPm[160];
  __shared__ __align__(16) float sQ[160];
  __shared__ __align__(16) float sDz[EE];
  __shared__ __align__(16) float sDgw[EE];
  __shared__ __align__(16) float sQt[EE];
  __shared__ __align__(16) float sScal[16];

  float* sYT = uni2;
  float* sGk = uni3;
  float* sYk = uni1;

  const int tid = threadIdx.x, wv = tid >> 6, ln = tid & 63;
  const int mr = tid >> 2, mq = tid & 3;  // matvec: row mr, col-quarter mq
  const int b = blockIdx.x;

  float areg[32];
  {
    const float4* a4 = (const float4*)(Ainv0 + mr * KK + 32 * mq);
#pragma unroll
    for (int u = 0; u < 8; u++) {
      const float4 t4 = a4[u];
      areg[4 * u] = t4.x; areg[4 * u + 1] = t4.y; areg[4 * u + 2] = t4.z; areg[4 * u + 3] = t4.w;
    }
  }
  {
    const float* Pb = Pg + (size_t)b * KK * EE;
#pragma unroll
    for (int i = 0; i < 8; i++) {
      const int idx = tid + 512 * i;                  // idx = k*32 + e
      sPT[(idx & 31) * PTS + (idx >> 5)] = Pb[idx];   // transpose into [e][k]
    }
    const float* Sb = Sg + (size_t)b * 4096;
#pragma unroll
    for (int i = 0; i < 2; i++) {
      const int idx = tid + 512 * i;
      sS[(idx >> 5) * L36 + (idx & 31)] =
          Sb[idx] + Sb[idx + 1024] + Sb[idx + 2048] + Sb[idx + 3072];
    }
  }
  if (tid < 16) sScal[tid] = 0.0f;
  const float v0 = scaleP[0] + V0EPS;
  __syncthreads();
  {  // w0 = Ainv0 * P[:,0]
    const float* xb = sPT + 32 * mq;
    float s = 0;
#pragma unroll
    for (int c = 0; c < 32; c++) s += areg[c] * xb[c];
    s += __shfl_xor(s, 1, 64); s += __shfl_xor(s, 2, 64);
    if (mq == 0) sW[SEG(mr)] = s;
  }
  __syncthreads();

#pragma unroll 1
  for (int t = 0; t < EE; ++t) {
    const bool hn = (t + 1 < EE);
    // ---- PH1: Pm = Ainv w ; dgw = G^T w ; qt = Y^T w ; S2 ----
    {
      const float* xb = sW + 40 * mq;
      float s = 0;
#pragma unroll
      for (int c = 0; c < 16; c++) s += areg[c] * xb[c];
#pragma unroll
      for (int c = 0; c < 16; c++) s += areg[16 + c] * xb[20 + c];
      s += __shfl_xor(s, 1, 64); s += __shfl_xor(s, 2, 64);
      if (mq == 0) sPm[SEG(mr)] = s;
    }
    if (tid < 256) {
      const int s8 = tid >> 3, p3 = tid & 7;
      if (s8 < t) {
        const float* gr = sGT + s8 * LTR + 16 * p3;
        const float* wr_ = sW + 20 * p3;
        float s = 0;
#pragma unroll
        for (int kk = 0; kk < 16; kk++) s += gr[kk] * wr_[kk];
        s += __shfl_xor(s, 1, 64); s += __shfl_xor(s, 2, 64); s += __shfl_xor(s, 4, 64);
        if (p3 == 0) sDgw[s8] = s;
      } else if (s8 == 31) {  // s8==31 never used by dgw: S2 here
        const float* wp = sW + 20 * p3;
        float s = 0;
#pragma unroll
        for (int kk = 0; kk < 16; kk++) s += wp[kk] * wp[kk];
        s += __shfl_xor(s, 1, 64); s += __shfl_xor(s, 2, 64); s += __shfl_xor(s, 4, 64);
        if (p3 == 0) sScal[SC_S2] = s;
      }
    } else {
      const int j = (tid - 256) >> 3, p3 = tid & 7;
      if (j < t) {
        const float* yr = sYT + j * LTR + 16 * p3;
        const float* wr_ = sW + 20 * p3;
        float s = 0;
#pragma unroll
        for (int kk = 0; kk < 16; kk++) s += yr[kk] * wr_[kk];
        s += __shfl_xor(s, 1, 64); s += __shfl_xor(s, 2, 64); s += __shfl_xor(s, 4, 64);
        if (p3 == 0) sQt[j] = s;
      }
    }
    __syncthreads();
    // ---- PH2: wU ; D_t ; Egg_t ; sigma ; KL ; R22 ----
    if (tid < 256) {  // wU[k] = v0 w[k] - sum_{j<t} Y[k][j] qt[j]
      const int k = tid >> 1, h = tid & 1;
      const float* yk = sYk + k * LKM + 16 * h;
      const float* qb = sQt + 16 * h;
      float a = 0;
#pragma unroll
      for (int u = 0; u < 16; u++) {
        const int j = 16 * h + u;
        a += (j < t) ? yk[u] * qb[u] : 0.0f;
      }
      a += __shfl_xor(a, 1, 64);
      if (h == 0) sWU[SEG(k)] = v0 * sW[SEG(k)] - a;
    } else if (tid < 384) {  // Egg append (k-major recurrence)
      const int k = tid - 256;
      float a = sW[SEG(k)];
      const float* ek = sEk + k * LKM;
      const int nc = (t + 3) >> 2;
#pragma unroll 1
      for (int c4 = 0; c4 < nc; ++c4) {
        const float4 ev = *(const float4*)(ek + 4 * c4);
        const float4 dv = *(const float4*)(sDgw + 4 * c4);
        const int u0 = 4 * c4;
        a -= ((u0 + 0 < t) ? ev.x * dv.x : 0.0f) + ((u0 + 1 < t) ? ev.y * dv.y : 0.0f) +
             ((u0 + 2 < t) ? ev.z * dv.z : 0.0f) + ((u0 + 3 < t) ? ev.w * dv.w : 0.0f);
      }
      sEk[k * LKM + t] = a;
      sEggT[t * LTR + k] = a;
    } else if (tid < 448) {  // wave 6: lanes<32: D append ; lanes>=32: R22 = w.Pm
      if (ln < 32) {
        const int r2 = ln;
        float a = (r2 == t) ? 1.0f : 0.0f;
        for (int s2 = 0; s2 < t; ++s2) a -= sDgw[s2] * sD[s2 * L36 + r2];
        sD[t * L36 + r2] = a;
      } else {
        const int k0 = (ln - 32) * 4;
        const float4 wv4 = *(const float4*)(sW + SEG(k0));
        const float4 pm4 = *(const float4*)(sPm + SEG(k0));
        float a = dot4(wv4, pm4);
        a = wsum32(a);
        if (ln == 32) sScal[SC_R22] = a;
      }
    } else {  // wave 7: sigma ; KL
      const float s2v = sScal[SC_S2];
      float a = (ln < t) ? sQt[ln] * sQt[ln] : 0.0f;
      a = wsum64(a);
      if (ln == 0) {
        sScal[SC_SIG] = v0 * s2v - a + 1.0f;
        sScal[SC_KL] += s2v;
      }
    }
    __syncthreads();
    // ---- PH3: Pu = Ainv wU ; dz ; B1 ; B2 ; R12 ; G/Y appends ----
    {
      const float* xb = sWU + 40 * mq;
      float s = 0;
#pragma unroll
      for (int c = 0; c < 16; c++) s += areg[c] * xb[c];
#pragma unroll
      for (int c = 0; c < 16; c++) s += areg[16 + c] * xb[20 + c];
      s += __shfl_xor(s, 1, 64); s += __shfl_xor(s, 2, 64);
      if (mq == 0) sPu[SEG(mr)] = s;
    }
    if (tid < 256) {  // dz[s4] = D[s4,:].S[:,t+1] - Egg^T[s4,:].P[:,t+1]
      const int s4 = tid >> 3, p3 = tid & 7;
      if (hn && s4 <= t) {
        const float* er = sEggT + s4 * LTR + 16 * p3;
        const float* pr = sPT + (t + 1) * PTS + 16 * p3;
        float a = 0;
#pragma unroll
        for (int kk = 0; kk < 16; kk++) a -= er[kk] * pr[kk];
        const float4 dv = *(const float4*)(sD + s4 * L36 + 4 * p3);
        const float4 sv = *(const float4*)(sS + (t + 1) * L36 + 4 * p3);  // S symmetric
        a += dot4(dv, sv);
        a += __shfl_xor(a, 1, 64); a += __shfl_xor(a, 2, 64); a += __shfl_xor(a, 4, 64);
        if (p3 == 0) sDz[s4] = a;
      }
    } else if (tid < 320) {  // wave 4: B2 = Egg_t . P[:,t]
      float a = sEggT[t * LTR + ln] * sPT[t * PTS + ln] +
                sEggT[t * LTR + ln + 64] * sPT[t * PTS + ln + 64];
      a = wsum64(a);
      if (ln == 0) sScal[SC_B2] = a;
    } else if (tid < 384) {  // wave 5: lanes<32: B1 ; lanes>=32: R12 = wU.Pm
      if (ln < 32) {
        float a = sD[t * L36 + ln] * sS[t * L36 + ln];
        a = wsum32(a);
        if (ln == 0) sScal[SC_B1] = a;
      } else {
        const int k0 = (ln - 32) * 4;
        const float4 wu4 = *(const float4*)(sWU + SEG(k0));
        const float4 pm4 = *(const float4*)(sPm + SEG(k0));
        float a = dot4(wu4, pm4);
        a = wsum32(a);
        if (ln == 32) sScal[SC_R12] = a;
      }
    } else if (tid < 448) {  // wave 6: G/Y appends (both layouts)
      const float sig = sScal[SC_SIG];
      const float rsq = rsqrtf(sig);
#pragma unroll
      for (int u = 0; u < 2; u++) {
        const int k = ln + 64 * u;
        const float wu = sWU[SEG(k)];
        const float gv = wu / sig;
        const float yv = wu * rsq;
        sGT[t * LTR + k] = gv;
        sGk[k * LKM + t] = gv;
        sYT[t * LTR + k] = yv;
        sYk[k * LKM + t] = yv;
      }
    }
    __syncthreads();
    // ---- PH4: q_next ; R11 ----
    if (hn) {
      const float* gk = sGk + mr * LKM + 8 * mq;
      const float* dzb = sDz + 8 * mq;
      float a = 0;
#pragma unroll
      for (int u = 0; u < 8; u++) {
        const int s2 = 8 * mq + u;
        a += (s2 < t) ? gk[u] * dzb[u] : 0.0f;
      }
      a += __shfl_xor(a, 1, 64); a += __shfl_xor(a, 2, 64);
      if (mq == 0)
        sQ[SEG(mr)] = sPT[(t + 1) * PTS + mr] + a + (sWU[SEG(mr)] / sScal[SC_SIG]) * sDz[t];
    }
    if (wv == 0) {  // R11 = wU . Pu
      float a = sWU[SEG(ln)] * sPu[SEG(ln)] + sWU[SEG(ln + 64)] * sPu[SEG(ln + 64)];
      a = wsum64(a);
      if (ln == 0) sScal[SC_R11] = a;
    }
    __syncthreads();
    // ---- PH5: Ainv rank-2 update (per-thread scalar finalize) ; w_next ----
    {
      const float4 sc0 = *(const float4*)(sScal);      // S2, SIG, KL, B1
      const float4 sc1 = *(const float4*)(sScal + 4);  // B2, R11, R12, R22
      const float rs = 1.0f / sc0.y;
      const float beta = sc0.w - sc1.x - sc0.x;
      const float e11 = sc1.y * rs * rs;
      const float e12 = sc1.z * rs + 1.0f;
      const float e22 = sc1.w - beta;
      const float rd = 1.0f / (e11 * e22 - e12 * e12);
      const float t11 = e22 * rd, t12 = -e12 * rd, t22 = e11 * rd;
      const float u1r = sPu[SEG(mr)] * rs, u2r = sPm[SEG(mr)];
      const float* pub = sPu + 40 * mq;
      const float* pmb = sPm + 40 * mq;
#pragma unroll
      for (int c = 0; c < 16; c++) {
        const float u1c = pub[c] * rs;
        const float u2c = pmb[c];
        areg[c] -= u1r * (t11 * u1c + t12 * u2c) + u2r * (t12 * u1c + t22 * u2c);
      }
#pragma unroll
      for (int c = 0; c < 16; c++) {
        const float u1c = pub[20 + c] * rs;
        const float u2c = pmb[20 + c];
        areg[16 + c] -= u1r * (t11 * u1c + t12 * u2c) + u2r * (t12 * u1c + t22 * u2c);
      }
    }
    if (hn) {
      const float* xb = sQ + 40 * mq;
      float s = 0;
#pragma unroll
      for (int c = 0; c < 16; c++) s += areg[c] * xb[c];
#pragma unroll
      for (int c = 0; c < 16; c++) s += areg[16 + c] * xb[20 + c];
      s += __shfl_xor(s, 1, 64); s += __shfl_xor(s, 2, 64);
      if (mq == 0) sW[SEG(mr)] = s;
    }
    __syncthreads();
  }

  // ================= fused postA =================
  float* sR1T  = uni2;         // [32][36]  (over dead sYT)
  float* sGamT = uni2 + 1152;  // [32][36]
  float* sRhsT = uni1;         // [32][132] (over dead sYk)
  float* sWrT  = uni3;         // [32][132] (over sGk -- dead after PA1)
  if (tid == 0) wsKL[b] = sScal[SC_KL];

  // ---- PA0: R1T[e][s] = D[s,:].S[e,:] - EggT[s,:].PT[e,:] ----
#pragma unroll
  for (int h = 0; h < 2; ++h) {
    const int lin = tid + 512 * h, s = lin >> 5, e = lin & 31;
    const float4* er = (const float4*)(sEggT + s * LTR);
    const float4* pr = (const float4*)(sPT + e * PTS);
    float a = 0;
#pragma unroll 8
    for (int u = 0; u < 32; ++u) a -= dot4(er[u], pr[u]);
    const float4* dr = (const float4*)(sD + s * L36);
    const float4* sr = (const float4*)(sS + e * L36);
#pragma unroll
    for (int u = 0; u < 8; ++u) a += dot4(dr[u], sr[u]);
    sR1T[e * 36 + s] = a;
  }
  __syncthreads();
  // ---- PA1: RhsT[e][k] = PT[e][k] + sum_s G[k][s] R1T[e][s] ----
  {
    const int k = tid & 127, e4 = tid >> 7;
    float4 g0, g1, g2, g3, g4, g5, g6, g7;
    {
      const float4* gk = (const float4*)(sGk + k * LKM);
      g0 = gk[0]; g1 = gk[1]; g2 = gk[2]; g3 = gk[3];
      g4 = gk[4]; g5 = gk[5]; g6 = gk[6]; g7 = gk[7];
    }
#pragma unroll
    for (int u = 0; u < 8; ++u) {
      const int e = e4 * 8 + u;
      const float4* r1 = (const float4*)(sR1T + e * 36);
      float a = sPT[e * PTS + k];
      a += dot4(g0, r1[0]) + dot4(g1, r1[1]) + dot4(g2, r1[2]) + dot4(g3, r1[3]);
      a += dot4(g4, r1[4]) + dot4(g5, r1[5]) + dot4(g6, r1[6]) + dot4(g7, r1[7]);
      sRhsT[e * PTS + k] = a;
    }
  }
  __syncthreads();
  // ---- PA2: WrT[e][k] = AinvP . rhs[:,e]  (areg matvec, 32 episodes) ----
#pragma unroll 2
  for (int e = 0; e < EE; ++e) {
    const float* xb = sRhsT + e * PTS + 32 * mq;
    float s = 0;
#pragma unroll
    for (int c = 0; c < 32; c++) s += areg[c] * xb[c];
    s += __shfl_xor(s, 1, 64); s += __shfl_xor(s, 2, 64);
    if (mq == 0) sWrT[e * PTS + mr] = s;
  }
  __syncthreads();
  // ---- PA3: GamT[e][s] = sum_k G[k][s] Wr[k][e] = GT[s,:].WrT[e,:] ----
#pragma unroll
  for (int h = 0; h < 2; ++h) {
    const int lin = tid + 512 * h, s = lin >> 5, e = lin & 31;
    const float4* gr = (const float4*)(sGT + s * LTR);
    const float4* wr = (const float4*)(sWrT + e * PTS);
    float a = 0;
#pragma unroll 8
    for (int u = 0; u < 32; ++u) a += dot4(gr[u], wr[u]);
    sGamT[e * 36 + s] = a;
  }
  __syncthreads();
  // ---- PA4: Wc -> wsWt rows 0..127 ; Vc -> rows 128..159 ; KLr ----
  {
    const int k = tid & 127, e4 = tid >> 7;
    float4 E0, E1, E2, E3, E4, E5, E6, E7;
    {
      const float4* ek = (const float4*)(sEk + k * LKM);
      E0 = ek[0]; E1 = ek[1]; E2 = ek[2]; E3 = ek[3];
      E4 = ek[4]; E5 = ek[5]; E6 = ek[6]; E7 = ek[7];
    }
#pragma unroll
    for (int u = 0; u < 8; ++u) {
      const int e = e4 * 8 + u;
      const float4* gm = (const float4*)(sGamT + e * 36);
      float a = sWrT[e * PTS + k];
      a -= dot4(E0, gm[0]) + dot4(E1, gm[1]) + dot4(E2, gm[2]) + dot4(E3, gm[3]);
      a -= dot4(E4, gm[4]) + dot4(E5, gm[5]) + dot4(E6, gm[6]) + dot4(E7, gm[7]);
      wsWt[(size_t)b * 5120 + e * 160 + k] = a;
    }
  }
  {  // Vc[e][sp] = sum_f D[f][sp] * GamT[e][f]
    const int e = tid & 31, sp = tid >> 5;  // sp in 0..15, handle sp and sp+16
    float4 gm[8];
    {
      const float4* g4 = (const float4*)(sGamT + e * 36);
#pragma unroll
      for (int u = 0; u < 8; ++u) gm[u] = g4[u];
    }
#pragma unroll
    for (int h = 0; h < 2; ++h) {
      const int sp2 = sp + 16 * h;
      float a = 0;
#pragma unroll
      for (int u = 0; u < 8; ++u) {
        const float4 g = gm[u];
        a += sD[(4 * u + 0) * L36 + sp2] * g.x + sD[(4 * u + 1) * L36 + sp2] * g.y +
             sD[(4 * u + 2) * L36 + sp2] * g.z + sD[(4 * u + 3) * L36 + sp2] * g.w;
      }
      wsWt[(size_t)b * 5120 + e * 160 + 128 + sp2] = a;
    }
  }
  {  // KLr[e] = sum_k Wr[k][e]^2
    const int e = tid >> 4, p = tid & 15;
    const float4* wr = (const float4*)(sWrT + e * PTS + 8 * p);
    const float4 w0 = wr[0], w1 = wr[1];
    float a = dot4(w0, w0) + dot4(w1, w1);
    a += __shfl_xor(a, 1, 64); a += __shfl_xor(a, 2, 64);
    a += __shfl_xor(a, 4, 64); a += __shfl_xor(a, 8, 64);
    if (p == 0) wsKLr[b * EE + e] = a;
  }
}

// ---------------- Kernel 4: postB (256 WGs) + final (block 256) ----------------
__global__ __launch_bounds__(512) void postBF_kernel(
    const float* __restrict__ wsWt, const float* __restrict__ x,
    const float* __restrict__ M0, const float* __restrict__ znoise,
    const float* __restrict__ wsKL, const float* __restrict__ wsKLr,
    const float* __restrict__ lwsP, float* __restrict__ out) {
  __shared__ __align__(16) float sWtT[32 * LWT];   // Wt^T : [e][row], stride 176
  __shared__ __align__(16) float Mch[2 * 16 * 132];
  const int tid = threadIdx.x;

  if (blockIdx.x == 256) {
    // ======== final: total divergence ========
    float* sPp = sWtT;  // reuse
    float s = 0.0f;
    if (tid < 64) s += wsKL[tid];
    for (int i = tid; i < 2048; i += 512) s += wsKLr[i];
    sPp[tid] = s;
    __syncthreads();
    for (int off = 256; off > 0; off >>= 1) {
      if (tid < off) sPp[tid] += sPp[tid + off];
      __syncthreads();
    }
    if (tid == 0) {
      const float lws = lwsP[0];
      const float sw2 = expf(2.0f * lws);
      out[(size_t)BB * EE * CC] =
          0.5f * sPp[0] / (float)(EE * BB) + (float)KK * (sw2 - 1.0f - 2.0f * lws);
    }
    return;
  }

  const int b = blockIdx.x >> 2, cq = blockIdx.x & 3;
  {
    // wsWt is [b][e][160]: direct (no transpose) load
    const int e = tid >> 4, j = tid & 15;
    const float* Wg = wsWt + (size_t)b * 5120 + e * 160;
#pragma unroll
    for (int u = 0; u < 10; ++u) sWtT[e * LWT + j + 16 * u] = Wg[j + 16 * u];
  }
  const int srow = tid >> 5, sc4 = tid & 31;  // stage: 16 rows x 32 float4 (128 cols)
  const int e = tid & 31, cs = tid >> 5;      // compute: episode e, col-octet cs
  const float* xb = x + (size_t)b * EE * CC;
  const int cbase = cq * 128;
  float4 st = *(const float4*)(M0 + srow * CC + cbase + 4 * sc4);  // ch2=0 rows are all M0
  float acc[8];
#pragma unroll
  for (int u = 0; u < 8; u++) acc[u] = 0.0f;
  int buf = 0;
#pragma unroll 1
  for (int ch2 = 0; ch2 < 10; ++ch2) {
    *(float4*)(Mch + buf * 2112 + srow * 132 + 4 * sc4) = st;
    __syncthreads();
    if (ch2 + 1 < 10) {
      const int row = (ch2 + 1) * 16 + srow;
      st = (row < 128) ? *(const float4*)(M0 + row * CC + cbase + 4 * sc4)
                       : *(const float4*)(xb + (row - 128) * CC + cbase + 4 * sc4);
    }
    const float4* wt4 = (const float4*)(sWtT + e * LWT + ch2 * 16);
    const float4 wa = wt4[0], wb = wt4[1], wc = wt4[2], wd = wt4[3];
    const float wv16[16] = {wa.x, wa.y, wa.z, wa.w, wb.x, wb.y, wb.z, wb.w,
                            wc.x, wc.y, wc.z, wc.w, wd.x, wd.y, wd.z, wd.w};
#pragma unroll
    for (int kk = 0; kk < 16; ++kk) {
      const float* mrp = Mch + buf * 2112 + kk * 132 + cs * 8;
      const float4 m0 = *(const float4*)(mrp);
      const float4 m1 = *(const float4*)(mrp + 4);
      const float wk = wv16[kk];
      acc[0] += wk * m0.x; acc[1] += wk * m0.y; acc[2] += wk * m0.z; acc[3] += wk * m0.w;
      acc[4] += wk * m1.x; acc[5] += wk * m1.y; acc[6] += wk * m1.z; acc[7] += wk * m1.w;
    }
    buf ^= 1;
  }
  {
    const size_t ob = ((size_t)b * EE + e) * CC + cbase + cs * 8;
    const size_t nb = ((size_t)e * BB + b) * CC + cbase + cs * 8;
#pragma unroll
    for (int u = 0; u < 2; u++) {
      const float4 nz = *(const float4*)(znoise + nb + 4 * u);
      float4 o;
      o.x = acc[4 * u] + nz.x;     o.y = acc[4 * u + 1] + nz.y;
      o.z = acc[4 * u + 2] + nz.z; o.w = acc[4 * u + 3] + nz.w;
      *(float4*)(out + ob + 4 * u) = o;
    }
  }
}

extern "C" void kernel_launch(void* const* d_in, const int* in_sizes, int n_in,
                              void* d_out, int out_size, void* d_ws, size_t ws_size,
                              hipStream_t stream) {
  (void)in_sizes; (void)n_in; (void)out_size; (void)ws_size;
  const float* x = (const float*)d_in[0];        // [B,E,C]
  const float* M0 = (const float*)d_in[1];       // [K,C]
  const float* scaleP = (const float*)d_in[2];   // scalar
  const float* lwsP = (const float*)d_in[3];     // scalar
  const float* znoise = (const float*)d_in[4];   // [E,B,C]
  float* out = (float*)d_out;

  float* ws = (float*)d_ws;
  float* wsP = ws;                        // 262144
  float* wsSp = wsP + 262144;             // 262144 (64 x 4 partials x 1024)
  float* wsA0 = wsSp + 262144;            // 16384
  float* wsAinv0 = wsA0 + 16384;          // 16384
  float* wsKL = wsAinv0 + 16384;          // 64
  float* wsKLr = wsKL + 64;               // 2048
  float* wsWt = wsKLr + 2048;             // 327680 (64 x 32 x 160, [b][e][row])

  a0_kernel<<<512, 256, 0, stream>>>(M0, wsA0);
  psinv_kernel<<<257, 1024, 0, stream>>>(x, M0, wsP, wsSp, wsA0, wsAinv0);
  scan_kernel<<<BB, 512, 0, stream>>>(wsP, wsSp, scaleP, wsAinv0,
                                      wsKL, wsKLr, wsWt);
  postBF_kernel<<<257, 512, 0, stream>>>(wsWt, x, M0, znoise, wsKL, wsKLr, lwsP, out);
}

// Round 8
// 261.858 us; speedup vs baseline: 1.4522x; 1.0253x over previous
//
#include <hip/hip_runtime.h>

// (B,E,K,C) = (64,32,128,512), fp32.
#define BB 64
#define EE 32
#define KK 128
#define CC 512
#define V0EPS 1e-7f

#define LTR 132   // [32][132] padded stride
#define PTS 132   // scan: P^T / RhsT / WrT row stride
#define LKM 36    // scan: k-major row stride (G/Y/Egg)
#define L36 36    // scan: S/D row stride
#define LWT 176   // postB: Wt^T row stride
// segment-padded K-vector layout: element i lives at (i/16)*20 + (i%16)
#define SEG(i) ((((i) >> 4) * 20) + ((i) & 15))

// scan sScal slots (order matters: read as two float4s in PH5)
#define SC_S2  0
#define SC_SIG 1
#define SC_KL  2
#define SC_B1  3
#define SC_B2  4
#define SC_R11 5
#define SC_R12 6
#define SC_R22 7

__device__ __forceinline__ float wsum64(float v) {
#pragma unroll
  for (int m = 32; m >= 1; m >>= 1) v += __shfl_xor(v, m, 64);
  return v;
}

__device__ __forceinline__ float wsum32(float v) {  // reduce within aligned 32-lane half
#pragma unroll
  for (int m = 16; m >= 1; m >>= 1) v += __shfl_xor(v, m, 64);
  return v;
}

__device__ __forceinline__ float dot4(const float4 a, const float4 b) {
  return a.x * b.x + a.y * b.y + a.z * b.z + a.w * b.w;
}

// ---------------- Kernel 1: A0 = M0 M0^T + I (512 WGs: k x l-quarter) ----------------
__global__ __launch_bounds__(256) void a0_kernel(const float* __restrict__ M0,
                                                 float* __restrict__ wsA0) {
  __shared__ __align__(16) float sRow[CC];
  const int k = blockIdx.x >> 2, quarter = blockIdx.x & 3;
  for (int c = threadIdx.x; c < CC; c += 256) sRow[c] = M0[k * CC + c];
  __syncthreads();
  const int wv = threadIdx.x >> 6, ln = threadIdx.x & 63;
  const float4* zr = (const float4*)(sRow + 8 * ln);
  const float4 z0 = zr[0], z1 = zr[1];
  for (int li = 0; li < 8; ++li) {
    const int l = quarter * 32 + wv * 8 + li;
    const float4* rp = (const float4*)(M0 + l * CC + 8 * ln);
    const float4 a = rp[0], b = rp[1];
    float s = dot4(a, z0) + dot4(b, z1);
    s = wsum64(s);
    if (ln == 0) wsA0[k * KK + l] = s + (l == k ? 1.0f : 0.0f);
  }
}

// ------- Kernel 2: block 0 -> inv(A0) via 4-pivot GJ ; blocks 1..256 -> P/S partials -------
__global__ __launch_bounds__(1024) void psinv_kernel(const float* __restrict__ x,
                                                     const float* __restrict__ M0,
                                                     float* __restrict__ wsP,
                                                     float* __restrict__ wsSp,
                                                     const float* __restrict__ A0g,
                                                     float* __restrict__ Ainv0) {
  __shared__ __align__(16) float zAll[32][520];
  __shared__ __align__(16) float Mch[2][16][520];
  __shared__ __align__(16) float sFb[2][4][128];   // [buf][col j+i][row]
  __shared__ __align__(16) float sPv[2][4][256];   // [buf][row j+i][A-part 128 | I-part 128]
  const int tid = threadIdx.x;

  if (blockIdx.x > 0) {
    // ================= ps body: P rows kq*32..kq*32+31 ; S partial over c-quarter =================
    const int b = (blockIdx.x - 1) >> 2, kq = (blockIdx.x - 1) & 3;
    {
      const float4* x4 = (const float4*)(x + (size_t)b * EE * CC);
#pragma unroll
      for (int i = 0; i < 4; i++) {
        const int F = tid + 1024 * i, e = F >> 7, c4 = F & 127;
        ((float4*)zAll[e])[c4] = x4[F];
      }
    }
    const float4* M4 = (const float4*)M0;
    const int srow = tid >> 7, sc4 = tid & 127;
    const int kbase = kq * 32;
    float4 st0 = M4[(kbase + srow) * 128 + sc4];
    float4 st1 = M4[(kbase + 8 + srow) * 128 + sc4];
    int buf = 0;
    const int p = tid & 7;           // 8 threads per dot
    const int ep = (tid >> 3) & 15;  // episodes 2*ep, 2*ep+1  (0..31)
    const int kp = tid >> 7;         // k rows kp, kp+8
#pragma unroll 1
    for (int kc = 0; kc < 2; ++kc) {
      ((float4*)Mch[buf][srow])[sc4] = st0;
      ((float4*)Mch[buf][8 + srow])[sc4] = st1;
      __syncthreads();
      if (kc == 0) {
        st0 = M4[(kbase + 16 + srow) * 128 + sc4];
        st1 = M4[(kbase + 24 + srow) * 128 + sc4];
      }
      float s00 = 0, s01 = 0, s10 = 0, s11 = 0;
      const float* m0 = Mch[buf][kp];
      const float* m1 = Mch[buf][kp + 8];
      const float* z0 = zAll[2 * ep];
      const float* z1 = zAll[2 * ep + 1];
#pragma unroll
      for (int u = 0; u < 16; u++) {
        const int c = 4 * p + 32 * u;
        const float4 a0 = *(const float4*)(m0 + c);
        const float4 a1 = *(const float4*)(m1 + c);
        const float4 b0 = *(const float4*)(z0 + c);
        const float4 b1 = *(const float4*)(z1 + c);
        s00 += dot4(a0, b0); s01 += dot4(a0, b1);
        s10 += dot4(a1, b0); s11 += dot4(a1, b1);
      }
#pragma unroll
      for (int m = 1; m <= 4; m <<= 1) {
        s00 += __shfl_xor(s00, m, 64); s01 += __shfl_xor(s01, m, 64);
        s10 += __shfl_xor(s10, m, 64); s11 += __shfl_xor(s11, m, 64);
      }
      if (p == 0) {
        float* Pb = wsP + (size_t)b * KK * EE;
        Pb[(kbase + kc * 16 + kp) * EE + 2 * ep] = s00;
        Pb[(kbase + kc * 16 + kp) * EE + 2 * ep + 1] = s01;
        Pb[(kbase + kc * 16 + kp + 8) * EE + 2 * ep] = s10;
        Pb[(kbase + kc * 16 + kp + 8) * EE + 2 * ep + 1] = s11;
      }
      buf ^= 1;
    }
    // S partial = Z[:, cq] Z[:, cq]^T
    {
      const int e = tid >> 5, f = tid & 31;
      const float4* ze = ((const float4*)zAll[e]) + 32 * kq;
      const float4* zf = ((const float4*)zAll[f]) + 32 * kq;
      float a0 = 0, a1 = 0, a2 = 0, a3 = 0;
#pragma unroll 4
      for (int u = 0; u < 32; u++) {
        const float4 A = ze[u], Bq = zf[u];
        a0 += A.x * Bq.x; a1 += A.y * Bq.y; a2 += A.z * Bq.z; a3 += A.w * Bq.w;
      }
      wsSp[((size_t)b * 4 + kq) * 1024 + e * EE + f] = (a0 + a1) + (a2 + a3);
    }
  } else {
    // ======== inv0 body (block 0): 4-pivot register GJ, 32 super-iterations ========
    // Exact composition of 4 sequential eliminations through the 4x4 pivot block:
    // forward factors g10..g32 + Schur diagonals q11,q22,q33; per-row sequential
    // f0..f3 (f_i = 0 for the block's own row); back-substitute to original-row
    // coefficients c_i = f_i - sum_{m>i} c_m * g_{m,i}; row_r -= sum c_i row_{j+i}.
    const int r = tid >> 3, q = tid & 7;
    float wreg[16], vreg[16];
    {
      const float4* a4 = (const float4*)(A0g + r * KK + 16 * q);
#pragma unroll
      for (int u = 0; u < 4; u++) {
        const float4 t4 = a4[u];
        wreg[4 * u] = t4.x; wreg[4 * u + 1] = t4.y; wreg[4 * u + 2] = t4.z; wreg[4 * u + 3] = t4.w;
      }
#pragma unroll
      for (int c = 0; c < 16; c++) vreg[c] = (16 * q + c == r) ? 1.0f : 0.0f;
    }
    // prologue: stage cols 0..3 and rows 0..3
    if (q == 0) {
      sFb[0][0][r] = wreg[0]; sFb[0][1][r] = wreg[1];
      sFb[0][2][r] = wreg[2]; sFb[0][3][r] = wreg[3];
    }
    if (r < 4) {
#pragma unroll
      for (int c = 0; c < 16; c++) {
        sPv[0][r][16 * q + c] = wreg[c];
        sPv[0][r][128 + 16 * q + c] = vreg[c];
      }
    }
    __syncthreads();
#pragma unroll 1
    for (int jj = 0; jj < 32; ++jj) {
      const int j = 4 * jj, db = jj & 1, dn = db ^ 1;
      const float* c0 = sFb[db][0];
      const float* c1 = sFb[db][1];
      const float* c2 = sFb[db][2];
      const float* c3 = sFb[db][3];
      const float* r0 = sPv[db][0];
      const float* r1 = sPv[db][1];
      const float* r2 = sPv[db][2];
      const float* r3 = sPv[db][3];
      // pivot block p[m][i] = col_i[j+m]
      const float p00 = c0[j],     p01 = c1[j],     p02 = c2[j],     p03 = c3[j];
      const float p10 = c0[j + 1], p11 = c1[j + 1], p12 = c2[j + 1], p13 = c3[j + 1];
      const float p20 = c0[j + 2], p21 = c1[j + 2], p22 = c2[j + 2], p23 = c3[j + 2];
      const float p30 = c0[j + 3], p31 = c1[j + 3], p32 = c2[j + 3], p33 = c3[j + 3];
      const float rp00 = 1.0f / p00;
      const float g10 = p10 * rp00;
      const float q11 = p11 - g10 * p01, q12 = p12 - g10 * p02, q13 = p13 - g10 * p03;
      const float rq11 = 1.0f / q11;
      const float g20 = p20 * rp00;
      const float g21 = (p21 - g20 * p01) * rq11;
      const float q22 = p22 - g20 * p02 - g21 * q12;
      const float q23 = p23 - g20 * p03 - g21 * q13;
      const float rq22 = 1.0f / q22;
      const float g30 = p30 * rp00;
      const float g31 = (p31 - g30 * p01) * rq11;
      const float g32 = (p32 - g30 * p02 - g31 * q12) * rq22;
      const float q33 = p33 - g30 * p03 - g31 * q13 - g32 * q23;
      const float rq33 = 1.0f / q33;
      // per-row sequential factors
      const float f0 = (r == j) ? 0.0f : c0[r] * rp00;
      const float f1 = (r == j + 1) ? 0.0f : (c1[r] - f0 * p01) * rq11;
      const float f2 = (r == j + 2) ? 0.0f : (c2[r] - f0 * p02 - f1 * q12) * rq22;
      const float f3 = (r == j + 3) ? 0.0f : (c3[r] - f0 * p03 - f1 * q13 - f2 * q23) * rq33;
      // back-substitute to original-row coefficients
      const float cc3 = f3;
      const float cc2 = f2 - cc3 * g32;
      const float cc1 = f1 - cc2 * g21 - cc3 * g31;
      const float cc0 = f0 - cc1 * g10 - cc2 * g20 - cc3 * g30;
      if (16 * q + 15 >= j) {  // A-part: only cols >= j are touched
        const float4* w0 = (const float4*)(r0 + 16 * q);
        const float4* w1 = (const float4*)(r1 + 16 * q);
        const float4* w2 = (const float4*)(r2 + 16 * q);
        const float4* w3 = (const float4*)(r3 + 16 * q);
#pragma unroll
        for (int u = 0; u < 4; u++) {
          const float4 a0 = w0[u], a1 = w1[u], a2 = w2[u], a3 = w3[u];
          wreg[4 * u]     -= cc0 * a0.x + cc1 * a1.x + cc2 * a2.x + cc3 * a3.x;
          wreg[4 * u + 1] -= cc0 * a0.y + cc1 * a1.y + cc2 * a2.y + cc3 * a3.y;
          wreg[4 * u + 2] -= cc0 * a0.z + cc1 * a1.z + cc2 * a2.z + cc3 * a3.z;
          wreg[4 * u + 3] -= cc0 * a0.w + cc1 * a1.w + cc2 * a2.w + cc3 * a3.w;
        }
      }
      if (16 * q <= j + 3) {  // I-part: staged rows' I-support is cols <= j+3
        const float4* v0 = (const float4*)(r0 + 128 + 16 * q);
        const float4* v1 = (const float4*)(r1 + 128 + 16 * q);
        const float4* v2 = (const float4*)(r2 + 128 + 16 * q);
        const float4* v3 = (const float4*)(r3 + 128 + 16 * q);
#pragma unroll
        for (int u = 0; u < 4; u++) {
          const float4 a0 = v0[u], a1 = v1[u], a2 = v2[u], a3 = v3[u];
          vreg[4 * u]     -= cc0 * a0.x + cc1 * a1.x + cc2 * a2.x + cc3 * a3.x;
          vreg[4 * u + 1] -= cc0 * a0.y + cc1 * a1.y + cc2 * a2.y + cc3 * a3.y;
          vreg[4 * u + 2] -= cc0 * a0.z + cc1 * a1.z + cc2 * a2.z + cc3 * a3.z;
          vreg[4 * u + 3] -= cc0 * a0.w + cc1 * a1.w + cc2 * a2.w + cc3 * a3.w;
        }
      }
      if (jj + 1 < 32) {  // stage cols/rows j+4..j+7 (post-update values)
#pragma unroll
        for (int i = 0; i < 4; ++i) {
          const int j2 = j + 4 + i;
          float wv_ = 0.0f;
#pragma unroll
          for (int c = 0; c < 16; c++) if (c == (j2 & 15)) wv_ = wreg[c];
          if (q == (j2 >> 4)) sFb[dn][i][r] = wv_;
          if (r == j2) {
#pragma unroll
            for (int c = 0; c < 16; c++) {
              sPv[dn][i][16 * q + c] = wreg[c];
              sPv[dn][i][128 + 16 * q + c] = vreg[c];
            }
          }
        }
      }
      __syncthreads();
    }
    {
      float dval = 0.0f;
#pragma unroll
      for (int c = 0; c < 16; c++) if (c == (r & 15)) dval = wreg[c];
      if (q == (r >> 4)) sFb[0][0][r] = dval;
    }
    __syncthreads();
    {
      const float sc = 1.0f / sFb[0][0][r];
      float4* o4 = (float4*)(Ainv0 + r * KK + 16 * q);
#pragma unroll
      for (int u = 0; u < 4; u++) {
        float4 o;
        o.x = vreg[4 * u] * sc; o.y = vreg[4 * u + 1] * sc;
        o.z = vreg[4 * u + 2] * sc; o.w = vreg[4 * u + 3] * sc;
        o4[u] = o;
      }
    }
  }
}

// ---------------- Kernel 3: scan + fused postA, 512 threads, one WG per batch ----------------
// (R4's verified 8-wave version: DS-pipe-bound phases, fewer waves behind each barrier;
//  postA fused with AinvP in areg and b128-friendly LDS layouts.)
__global__ __launch_bounds__(512) void scan_kernel(
    const float* __restrict__ Pg, const float* __restrict__ Sg,  // Sg = 4 partials per batch
    const float* __restrict__ scaleP, const float* __restrict__ Ainv0,
    float* __restrict__ wsKL, float* __restrict__ wsKLr, float* __restrict__ wsWt) {
  __shared__ __align__(16) float sPT[EE * PTS];    // P^T : [e][k]
  __shared__ __align__(16) float sGT[EE * LTR];    // G^T : [t][k]
  __shared__ __align__(16) float sEggT[EE * LTR];  // Egg^T : [t][k]
  __shared__ __align__(16) float uni2[EE * LTR];   // scan: Y^T [t][k] | postA: R1T + GamT
  __shared__ __align__(16) float uni3[KK * LKM];   // scan: G [k][t]  | postA: WrT [e][k]
  __shared__ __align__(16) float uni1[KK * LKM];   // scan: Y [k][j]  | postA: RhsT [e][k]
  __shared__ __align__(16) float sEk[KK * LKM];    // Egg: [k][s]
  __shared__ __align__(16) float sS[EE * L36];     // S (symmetric)
  __shared__ __align__(16) float sD[EE * L36];     // D : [s][r2]
  __shared__ __align__(16) float sW[160];
  __shared__ __align__(16) float sWU[160];
  __shared__ __align__(16) float sPu[160];
  __shared__ __align__(16) float sPm[160];
  __shared__ __align__(16) float sQ[160];
  __shared__ __align__(16) float sDz[EE];
  __shared__ __align__(16) float sDgw[EE];
  __shared__ __align__(16) float sQt[EE];
  __shared__ __align__(16) float sScal[16];

  float* sYT = uni2;
  float* sGk = uni3;
  float* sYk = uni1;

  const int tid = threadIdx.x, wv = tid >> 6, ln = tid & 63;
  const int mr = tid >> 2, mq = tid & 3;  // matvec: row mr, col-quarter mq
  const int b = blockIdx.x;

  float areg[32];
  {
    const float4* a4 = (const float4*)(Ainv0 + mr * KK + 32 * mq);
#pragma unroll
    for (int u = 0; u < 8; u++) {
      const float4 t4 = a4[u];
      areg[4 * u] = t4.x; areg[4 * u + 1] = t4.y; areg[4 * u + 2] = t4.z; areg[4 * u + 3] = t4.w;
    }
  }
  {
    const float* Pb = Pg + (size_t)b * KK * EE;
#pragma unroll
    for (int i = 0; i < 8; i++) {
      const int idx = tid + 512 * i;                  // idx = k*32 + e
      sPT[(idx & 31) * PTS + (idx >> 5)] = Pb[idx];   // transpose into [e][k]
    }
    const float* Sb = Sg + (size_t)b * 4096;
#pragma unroll
    for (int i = 0; i < 2; i++) {
      const int idx = tid + 512 * i;
      sS[(idx >> 5) * L36 + (idx & 31)] =
          Sb[idx] + Sb[idx + 1024] + Sb[idx + 2048] + Sb[idx + 3072];
    }
  }
  if (tid < 16) sScal[tid] = 0.0f;
  const float v0 = scaleP[0] + V0EPS;
  __syncthreads();
  {  // w0 = Ainv0 * P[:,0]
    const float* xb = sPT + 32 * mq;
    float s = 0;
#pragma unroll
    for (int c = 0; c < 32; c++) s += areg[c] * xb[c];
    s += __shfl_xor(s, 1, 64); s += __shfl_xor(s, 2, 64);
    if (mq == 0) sW[SEG(mr)] = s;
  }
  __syncthreads();

#pragma unroll 1
  for (int t = 0; t < EE; ++t) {
    const bool hn = (t + 1 < EE);
    // ---- PH1: Pm = Ainv w ; dgw = G^T w ; qt = Y^T w ; S2 ----
    {
      const float* xb = sW + 40 * mq;
      float s = 0;
#pragma unroll
      for (int c = 0; c < 16; c++) s += areg[c] * xb[c];
#pragma unroll
      for (int c = 0; c < 16; c++) s += areg[16 + c] * xb[20 + c];
      s += __shfl_xor(s, 1, 64); s += __shfl_xor(s, 2, 64);
      if (mq == 0) sPm[SEG(mr)] = s;
    }
    if (tid < 256) {
      const int s8 = tid >> 3, p3 = tid & 7;
      if (s8 < t) {
        const float* gr = sGT + s8 * LTR + 16 * p3;
        const float* wr_ = sW + 20 * p3;
        float s = 0;
#pragma unroll
        for (int kk = 0; kk < 16; kk++) s += gr[kk] * wr_[kk];
        s += __shfl_xor(s, 1, 64); s += __shfl_xor(s, 2, 64); s += __shfl_xor(s, 4, 64);
        if (p3 == 0) sDgw[s8] = s;
      } else if (s8 == 31) {  // s8==31 never used by dgw: S2 here
        const float* wp = sW + 20 * p3;
        float s = 0;
#pragma unroll
        for (int kk = 0; kk < 16; kk++) s += wp[kk] * wp[kk];
        s += __shfl_xor(s, 1, 64); s += __shfl_xor(s, 2, 64); s += __shfl_xor(s, 4, 64);
        if (p3 == 0) sScal[SC_S2] = s;
      }
    } else {
      const int j = (tid - 256) >> 3, p3 = tid & 7;
      if (j < t) {
        const float* yr = sYT + j * LTR + 16 * p3;
        const float* wr_ = sW + 20 * p3;
        float s = 0;
#pragma unroll
        for (int kk = 0; kk < 16; kk++) s += yr[kk] * wr_[kk];
        s += __shfl_xor(s, 1, 64); s += __shfl_xor(s, 2, 64); s += __shfl_xor(s, 4, 64);
        if (p3 == 0) sQt[j] = s;
      }
    }
    __syncthreads();
    // ---- PH2: wU ; D_t ; Egg_t ; sigma ; KL ; R22 ----
    if (tid < 256) {  // wU[k] = v0 w[k] - sum_{j<t} Y[k][j] qt[j]
      const int k = tid >> 1, h = tid & 1;
      const float* yk = sYk + k * LKM + 16 * h;
      const float* qb = sQt + 16 * h;
      float a = 0;
#pragma unroll
      for (int u = 0; u < 16; u++) {
        const int j = 16 * h + u;
        a += (j < t) ? yk[u] * qb[u] : 0.0f;
      }
      a += __shfl_xor(a, 1, 64);
      if (h == 0) sWU[SEG(k)] = v0 * sW[SEG(k)] - a;
    } else if (tid < 384) {  // Egg append (k-major recurrence)
      const int k = tid - 256;
      float a = sW[SEG(k)];
      const float* ek = sEk + k * LKM;
      const int nc = (t + 3) >> 2;
#pragma unroll 1
      for (int c4 = 0; c4 < nc; ++c4) {
        const float4 ev = *(const float4*)(ek + 4 * c4);
        const float4 dv = *(const float4*)(sDgw + 4 * c4);
        const int u0 = 4 * c4;
        a -= ((u0 + 0 < t) ? ev.x * dv.x : 0.0f) + ((u0 + 1 < t) ? ev.y * dv.y : 0.0f) +
             ((u0 + 2 < t) ? ev.z * dv.z : 0.0f) + ((u0 + 3 < t) ? ev.w * dv.w : 0.0f);
      }
      sEk[k * LKM + t] = a;
      sEggT[t * LTR + k] = a;
    } else if (tid < 448) {  // wave 6: lanes<32: D append ; lanes>=32: R22 = w.Pm
      if (ln < 32) {
        const int r2 = ln;
        float a = (r2 == t) ? 1.0f : 0.0f;
        for (int s2 = 0; s2 < t; ++s2) a -= sDgw[s2] * sD[s2 * L36 + r2];
        sD[t * L36 + r2] = a;
      } else {
        const int k0 = (ln - 32) * 4;
        const float4 wv4 = *(const float4*)(sW + SEG(k0));
        const float4 pm4 = *(const float4*)(sPm + SEG(k0));
        float a = dot4(wv4, pm4);
        a = wsum32(a);
        if (ln == 32) sScal[SC_R22] = a;
      }
    } else {  // wave 7: sigma ; KL
      const float s2v = sScal[SC_S2];
      float a = (ln < t) ? sQt[ln] * sQt[ln] : 0.0f;
      a = wsum64(a);
      if (ln == 0) {
        sScal[SC_SIG] = v0 * s2v - a + 1.0f;
        sScal[SC_KL] += s2v;
      }
    }
    __syncthreads();
    // ---- PH3: Pu = Ainv wU ; dz ; B1 ; B2 ; R12 ; G/Y appends ----
    {
      const float* xb = sWU + 40 * mq;
      float s = 0;
#pragma unroll
      for (int c = 0; c < 16; c++) s += areg[c] * xb[c];
#pragma unroll
      for (int c = 0; c < 16; c++) s += areg[16 + c] * xb[20 + c];
      s += __shfl_xor(s, 1, 64); s += __shfl_xor(s, 2, 64);
      if (mq == 0) sPu[SEG(mr)] = s;
    }
    if (tid < 256) {  // dz[s4] = D[s4,:].S[:,t+1] - Egg^T[s4,:].P[:,t+1]
      const int s4 = tid >> 3, p3 = tid & 7;
      if (hn && s4 <= t) {
        const float* er = sEggT + s4 * LTR + 16 * p3;
        const float* pr = sPT + (t + 1) * PTS + 16 * p3;
        float a = 0;
#pragma unroll
        for (int kk = 0; kk < 16; kk++) a -= er[kk] * pr[kk];
        const float4 dv = *(const float4*)(sD + s4 * L36 + 4 * p3);
        const float4 sv = *(const float4*)(sS + (t + 1) * L36 + 4 * p3);  // S symmetric
        a += dot4(dv, sv);
        a += __shfl_xor(a, 1, 64); a += __shfl_xor(a, 2, 64); a += __shfl_xor(a, 4, 64);
        if (p3 == 0) sDz[s4] = a;
      }
    } else if (tid < 320) {  // wave 4: B2 = Egg_t . P[:,t]
      float a = sEggT[t * LTR + ln] * sPT[t * PTS + ln] +
                sEggT[t * LTR + ln + 64] * sPT[t * PTS + ln + 64];
      a = wsum64(a);
      if (ln == 0) sScal[SC_B2] = a;
    } else if (tid < 384) {  // wave 5: lanes<32: B1 ; lanes>=32: R12 = wU.Pm
      if (ln < 32) {
        float a = sD[t * L36 + ln] * sS[t * L36 + ln];
        a = wsum32(a);
        if (ln == 0) sScal[SC_B1] = a;
      } else {
        const int k0 = (ln - 32) * 4;
        const float4 wu4 = *(const float4*)(sWU + SEG(k0));
        const float4 pm4 = *(const float4*)(sPm + SEG(k0));
        float a = dot4(wu4, pm4);
        a = wsum32(a);
        if (ln == 32) sScal[SC_R12] = a;
      }
    } else if (tid < 448) {  // wave 6: G/Y appends (both layouts)
      const float sig = sScal[SC_SIG];
      const float rsq = rsqrtf(sig);
#pragma unroll
      for (int u = 0; u < 2; u++) {
        const int k = ln + 64 * u;
        const float wu = sWU[SEG(k)];
        const float gv = wu / sig;
        const float yv = wu * rsq;
        sGT[t * LTR + k] = gv;
        sGk[k * LKM + t] = gv;
        sYT[t * LTR + k] = yv;
        sYk[k * LKM + t] = yv;
      }
    }
    __syncthreads();
    // ---- PH4: q_next ; R11 ----
    if (hn) {
      const float* gk = sGk + mr * LKM + 8 * mq;
      const float* dzb = sDz + 8 * mq;
      float a = 0;
#pragma unroll
      for (int u = 0; u < 8; u++) {
        const int s2 = 8 * mq + u;
        a += (s2 < t) ? gk[u] * dzb[u] : 0.0f;
      }
      a += __shfl_xor(a, 1, 64); a += __shfl_xor(a, 2, 64);
      if (mq == 0)
        sQ[SEG(mr)] = sPT[(t + 1) * PTS + mr] + a + (sWU[SEG(mr)] / sScal[SC_SIG]) * sDz[t];
    }
    if (wv == 0) {  // R11 = wU . Pu
      float a = sWU[SEG(ln)] * sPu[SEG(ln)] + sWU[SEG(ln + 64)] * sPu[SEG(ln + 64)];
      a = wsum64(a);
      if (ln == 0) sScal[SC_R11] = a;
    }
    __syncthreads();
    // ---- PH5: Ainv rank-2 update (per-thread scalar finalize) ; w_next ----
    {
      const float4 sc0 = *(const float4*)(sScal);      // S2, SIG, KL, B1
      const float4 sc1 = *(const float4*)(sScal + 4);  // B2, R11, R12, R22
      const float rs = 1.0f / sc0.y;
      const float beta = sc0.w - sc1.x - sc0.x;
      const float e11 = sc1.y * rs * rs;
      const float e12 = sc1.z * rs + 1.0f;
      const float e22 = sc1.w - beta;
      const float rd = 1.0f / (e11 * e22 - e12 * e12);
      const float t11 = e22 * rd, t12 = -e12 * rd, t22 = e11 * rd;
      const float u1r = sPu[SEG(mr)] * rs, u2r = sPm[SEG(mr)];
      const float* pub = sPu + 40 * mq;
      const float* pmb = sPm + 40 * mq;
#pragma unroll
      for (int c = 0; c < 16; c++) {
        const float u1c = pub[c] * rs;
        const float u2c = pmb[c];
        areg[c] -= u1r * (t11 * u1c + t12 * u2c) + u2r * (t12 * u1c + t22 * u2c);
      }
#pragma unroll
      for (int c = 0; c < 16; c++) {
        const float u1c = pub[20 + c] * rs;
        const float u2c = pmb[20 + c];
        areg[16 + c] -= u1r * (t11 * u1c + t12 * u2c) + u2r * (t12 * u1c + t22 * u2c);
      }
    }
    if (hn) {
      const float* xb = sQ + 40 * mq;
      float s = 0;
#pragma unroll
      for (int c = 0; c < 16; c++) s += areg[c] * xb[c];
#pragma unroll
      for (int c = 0; c < 16; c++) s += areg[16 + c] * xb[20 + c];
      s += __shfl_xor(s, 1, 64); s += __shfl_xor(s, 2, 64);
      if (mq == 0) sW[SEG(mr)] = s;
    }
    __syncthreads();
  }

  // ================= fused postA =================
  float* sR1T  = uni2;         // [32][36]  (over dead sYT)
  float* sGamT = uni2 + 1152;  // [32][36]
  float* sRhsT = uni1;         // [32][132] (over dead sYk)
  float* sWrT  = uni3;         // [32][132] (over sGk -- dead after PA1)
  if (tid == 0) wsKL[b] = sScal[SC_KL];

  // ---- PA0: R1T[e][s] = D[s,:].S[e,:] - EggT[s,:].PT[e,:] ----
#pragma unroll
  for (int h = 0; h < 2; ++h) {
    const int lin = tid + 512 * h, s = lin >> 5, e = lin & 31;
    const float4* er = (const float4*)(sEggT + s * LTR);
    const float4* pr = (const float4*)(sPT + e * PTS);
    float a = 0;
#pragma unroll 8
    for (int u = 0; u < 32; ++u) a -= dot4(er[u], pr[u]);
    const float4* dr = (const float4*)(sD + s * L36);
    const float4* sr = (const float4*)(sS + e * L36);
#pragma unroll
    for (int u = 0; u < 8; ++u) a += dot4(dr[u], sr[u]);
    sR1T[e * 36 + s] = a;
  }
  __syncthreads();
  // ---- PA1: RhsT[e][k] = PT[e][k] + sum_s G[k][s] R1T[e][s] ----
  {
    const int k = tid & 127, e4 = tid >> 7;
    float4 g0, g1, g2, g3, g4, g5, g6, g7;
    {
      const float4* gk = (const float4*)(sGk + k * LKM);
      g0 = gk[0]; g1 = gk[1]; g2 = gk[2]; g3 = gk[3];
      g4 = gk[4]; g5 = gk[5]; g6 = gk[6]; g7 = gk[7];
    }
#pragma unroll
    for (int u = 0; u < 8; ++u) {
      const int e = e4 * 8 + u;
      const float4* r1 = (const float4*)(sR1T + e * 36);
      float a = sPT[e * PTS + k];
      a += dot4(g0, r1[0]) + dot4(g1, r1[1]) + dot4(g2, r1[2]) + dot4(g3, r1[3]);
      a += dot4(g4, r1[4]) + dot4(g5, r1[5]) + dot4(g6, r1[6]) + dot4(g7, r1[7]);
      sRhsT[e * PTS + k] = a;
    }
  }
  __syncthreads();
  // ---- PA2: WrT[e][k] = AinvP . rhs[:,e]  (areg matvec, 32 episodes) ----
#pragma unroll 2
  for (int e = 0; e < EE; ++e) {
    const float* xb = sRhsT + e * PTS + 32 * mq;
    float s = 0;
#pragma unroll
    for (int c = 0; c < 32; c++) s += areg[c] * xb[c];
    s += __shfl_xor(s, 1, 64); s += __shfl_xor(s, 2, 64);
    if (mq == 0) sWrT[e * PTS + mr] = s;
  }
  __syncthreads();
  // ---- PA3: GamT[e][s] = sum_k G[k][s] Wr[k][e] = GT[s,:].WrT[e,:] ----
#pragma unroll
  for (int h = 0; h < 2; ++h) {
    const int lin = tid + 512 * h, s = lin >> 5, e = lin & 31;
    const float4* gr = (const float4*)(sGT + s * LTR);
    const float4* wr = (const float4*)(sWrT + e * PTS);
    float a = 0;
#pragma unroll 8
    for (int u = 0; u < 32; ++u) a += dot4(gr[u], wr[u]);
    sGamT[e * 36 + s] = a;
  }
  __syncthreads();
  // ---- PA4: Wc -> wsWt rows 0..127 ; Vc -> rows 128..159 ; KLr ----
  {
    const int k = tid & 127, e4 = tid >> 7;
    float4 E0, E1, E2, E3, E4, E5, E6, E7;
    {
      const float4* ek = (const float4*)(sEk + k * LKM);
      E0 = ek[0]; E1 = ek[1]; E2 = ek[2]; E3 = ek[3];
      E4 = ek[4]; E5 = ek[5]; E6 = ek[6]; E7 = ek[7];
    }
#pragma unroll
    for (int u = 0; u < 8; ++u) {
      const int e = e4 * 8 + u;
      const float4* gm = (const float4*)(sGamT + e * 36);
      float a = sWrT[e * PTS + k];
      a -= dot4(E0, gm[0]) + dot4(E1, gm[1]) + dot4(E2, gm[2]) + dot4(E3, gm[3]);
      a -= dot4(E4, gm[4]) + dot4(E5, gm[5]) + dot4(E6, gm[6]) + dot4(E7, gm[7]);
      wsWt[(size_t)b * 5120 + e * 160 + k] = a;
    }
  }
  {  // Vc[e][sp] = sum_f D[f][sp] * GamT[e][f]
    const int e = tid & 31, sp = tid >> 5;  // sp in 0..15, handle sp and sp+16
    float4 gm[8];
    {
      const float4* g4 = (const float4*)(sGamT + e * 36);
#pragma unroll
      for (int u = 0; u < 8; ++u) gm[u] = g4[u];
    }
#pragma unroll
    for (int h = 0; h < 2; ++h) {
      const int sp2 = sp + 16 * h;
      float a = 0;
#pragma unroll
      for (int u = 0; u < 8; ++u) {
        const float4 g = gm[u];
        a += sD[(4 * u + 0) * L36 + sp2] * g.x + sD[(4 * u + 1) * L36 + sp2] * g.y +
             sD[(4 * u + 2) * L36 + sp2] * g.z + sD[(4 * u + 3) * L36 + sp2] * g.w;
      }
      wsWt[(size_t)b * 5120 + e * 160 + 128 + sp2] = a;
    }
  }
  {  // KLr[e] = sum_k Wr[k][e]^2
    const int e = tid >> 4, p = tid & 15;
    const float4* wr = (const float4*)(sWrT + e * PTS + 8 * p);
    const float4 w0 = wr[0], w1 = wr[1];
    float a = dot4(w0, w0) + dot4(w1, w1);
    a += __shfl_xor(a, 1, 64); a += __shfl_xor(a, 2, 64);
    a += __shfl_xor(a, 4, 64); a += __shfl_xor(a, 8, 64);
    if (p == 0) wsKLr[b * EE + e] = a;
  }
}

// ---------------- Kernel 4: postB (256 WGs) + final (block 256) ----------------
__global__ __launch_bounds__(512) void postBF_kernel(
    const float* __restrict__ wsWt, const float* __restrict__ x,
    const float* __restrict__ M0, const float* __restrict__ znoise,
    const float* __restrict__ wsKL, const float* __restrict__ wsKLr,
    const float* __restrict__ lwsP, float* __restrict__ out) {
  __shared__ __align__(16) float sWtT[32 * LWT];   // Wt^T : [e][row], stride 176
  __shared__ __align__(16) float Mch[2 * 16 * 132];
  const int tid = threadIdx.x;

  if (blockIdx.x == 256) {
    // ======== final: total divergence ========
    float* sPp = sWtT;  // reuse
    float s = 0.0f;
    if (tid < 64) s += wsKL[tid];
    for (int i = tid; i < 2048; i += 512) s += wsKLr[i];
    sPp[tid] = s;
    __syncthreads();
    for (int off = 256; off > 0; off >>= 1) {
      if (tid < off) sPp[tid] += sPp[tid + off];
      __syncthreads();
    }
    if (tid == 0) {
      const float lws = lwsP[0];
      const float sw2 = expf(2.0f * lws);
      out[(size_t)BB * EE * CC] =
          0.5f * sPp[0] / (float)(EE * BB) + (float)KK * (sw2 - 1.0f - 2.0f * lws);
    }
    return;
  }

  const int b = blockIdx.x >> 2, cq = blockIdx.x & 3;
  {
    // wsWt is [b][e][160]: direct (no transpose) load
    const int e = tid >> 4, j = tid & 15;
    const float* Wg = wsWt + (size_t)b * 5120 + e * 160;
#pragma unroll
    for (int u = 0; u < 10; ++u) sWtT[e * LWT + j + 16 * u] = Wg[j + 16 * u];
  }
  const int srow = tid >> 5, sc4 = tid & 31;  // stage: 16 rows x 32 float4 (128 cols)
  const int e = tid & 31, cs = tid >> 5;      // compute: episode e, col-octet cs
  const float* xb = x + (size_t)b * EE * CC;
  const int cbase = cq * 128;
  float4 st = *(const float4*)(M0 + srow * CC + cbase + 4 * sc4);  // ch2=0 rows are all M0
  float acc[8];
#pragma unroll
  for (int u = 0; u < 8; u++) acc[u] = 0.0f;
  int buf = 0;
#pragma unroll 1
  for (int ch2 = 0; ch2 < 10; ++ch2) {
    *(float4*)(Mch + buf * 2112 + srow * 132 + 4 * sc4) = st;
    __syncthreads();
    if (ch2 + 1 < 10) {
      const int row = (ch2 + 1) * 16 + srow;
      st = (row < 128) ? *(const float4*)(M0 + row * CC + cbase + 4 * sc4)
                       : *(const float4*)(xb + (row - 128) * CC + cbase + 4 * sc4);
    }
    const float4* wt4 = (const float4*)(sWtT + e * LWT + ch2 * 16);
    const float4 wa = wt4[0], wb = wt4[1], wc = wt4[2], wd = wt4[3];
    const float wv16[16] = {wa.x, wa.y, wa.z, wa.w, wb.x, wb.y, wb.z, wb.w,
                            wc.x, wc.y, wc.z, wc.w, wd.x, wd.y, wd.z, wd.w};
#pragma unroll
    for (int kk = 0; kk < 16; ++kk) {
      const float* mrp = Mch + buf * 2112 + kk * 132 + cs * 8;
      const float4 m0 = *(const float4*)(mrp);
      const float4 m1 = *(const float4*)(mrp + 4);
      const float wk = wv16[kk];
      acc[0] += wk * m0.x; acc[1] += wk * m0.y; acc[2] += wk * m0.z; acc[3] += wk * m0.w;
      acc[4] += wk * m1.x; acc[5] += wk * m1.y; acc[6] += wk * m1.z; acc[7] += wk * m1.w;
    }
    buf ^= 1;
  }
  {
    const size_t ob = ((size_t)b * EE + e) * CC + cbase + cs * 8;
    const size_t nb = ((size_t)e * BB + b) * CC + cbase + cs * 8;
#pragma unroll
    for (int u = 0; u < 2; u++) {
      const float4 nz = *(const float4*)(znoise + nb + 4 * u);
      float4 o;
      o.x = acc[4 * u] + nz.x;     o.y = acc[4 * u + 1] + nz.y;
      o.z = acc[4 * u + 2] + nz.z; o.w = acc[4 * u + 3] + nz.w;
      *(float4*)(out + ob + 4 * u) = o;
    }
  }
}

extern "C" void kernel_launch(void* const* d_in, const int* in_sizes, int n_in,
                              void* d_out, int out_size, void* d_ws, size_t ws_size,
                              hipStream_t stream) {
  (void)in_sizes; (void)n_in; (void)out_size; (void)ws_size;
  const float* x = (const float*)d_in[0];        // [B,E,C]
  const float* M0 = (const float*)d_in[1];       // [K,C]
  const float* scaleP = (const float*)d_in[2];   // scalar
  const float* lwsP = (const float*)d_in[3];     // scalar
  const float* znoise = (const float*)d_in[4];   // [E,B,C]
  float* out = (float*)d_out;

  float* ws = (float*)d_ws;
  float* wsP = ws;                        // 262144
  float* wsSp = wsP + 262144;             // 262144 (64 x 4 partials x 1024)
  float* wsA0 = wsSp + 262144;            // 16384
  float* wsAinv0 = wsA0 + 16384;          // 16384
  float* wsKL = wsAinv0 + 16384;          // 64
  float* wsKLr = wsKL + 64;               // 2048
  float* wsWt = wsKLr + 2048;             // 327680 (64 x 32 x 160, [b][e][row])

  a0_kernel<<<512, 256, 0, stream>>>(M0, wsA0);
  psinv_kernel<<<257, 1024, 0, stream>>>(x, M0, wsP, wsSp, wsA0, wsAinv0);
  scan_kernel<<<BB, 512, 0, stream>>>(wsP, wsSp, scaleP, wsAinv0,
                                      wsKL, wsKLr, wsWt);
  postBF_kernel<<<257, 512, 0, stream>>>(wsWt, x, M0, znoise, wsKL, wsKLr, lwsP, out);
}